// Round 6
// baseline (583.135 us; speedup 1.0000x reference)
//
#include <hip/hip_runtime.h>
#include <hip/hip_bf16.h>

#define B_    256
#define L_    512
#define DV    21
#define NROW  5376       // B_*DV
#define NP    32
#define PP    16
#define PRED_ 96

// ---------------- workspace layout (float indices) ----------------
static const size_t OFF_XT    = 0;          // 5376x512 f32
static const size_t OFF_ZA    = 2752512;    // z_dct -> z -> t -> z2 -> Hcat/BcatT (aliased over time)
static const size_t OFF_Z1    = 5505024;
static const size_t OFF_ZCP   = 8257536;    // zc_pre -> z2f (in-place)
static const size_t OFF_D2    = 11010048;   // 512x512
static const size_t OFF_D3    = 11272192;
static const size_t OFF_M     = 11534336;   // 512x96 folded linres
static const size_t OFF_TN    = 11583488;   // 32x16x16
static const size_t OFF_TB    = 11591680;   // 32x16
static const size_t OFF_C     = 11592192;   // 96 (pad 128)
static const size_t OFF_EN    = 11592320;   // 5376
static const size_t OFF_NORM  = 11597696;
static const size_t OFF_ATT   = 11603072;
static const size_t OFF_ATT1  = 11608448;   // also aliases dvec (512) before k_attfin writes att1
static const size_t OFF_STAT  = 11613824;   // 256: [0..41]dct [42..105]patch [106..169]dep [200],[201]=thr order stats
static const size_t OFF_ABD   = 11614080;   // 64
static const size_t OFF_ABP   = 11614144;   // 64
static const size_t OFF_ABDEP = 11614208;   // 64
static const size_t OFF_FLAG  = 11614272;   // int mode flag (1=f32 inputs, 0=bf16)
static const size_t OFF_STG   = 11614336;   // staged f32 weights (854480)
// total 12468816 floats = 49.9 MB
// aliases inside OFF_ZA region (live only after z2f):
//   Hcat  = OFF_ZA            (5376 x 256)
//   BcatT = OFF_ZA + 1500000  (256 x 512)

// staged-weight offsets (relative to OFF_STG)
static const int S_WDCT=0, S_BDCT=24, S_WE=48, S_BE=4144, S_WL=4400, S_BL=790832,
  S_WD=790928, S_BDRES=795024, S_WDC=795040, S_BDC=795552, S_WDC1=795584, S_BDC1=795680,
  S_GD=795712, S_BDN=795736, S_GP=795760, S_BP=795792, S_GDEP=795824, S_BDEP=795856,
  S_THR=795888, S_WM1=795892, S_BM1=845044, S_WM2=845140, S_BM2=854356,
  S_ADWW=854452, S_ADWB=854460, S_ACW=854464, S_ACB=854468, S_AG=854472, S_AB2=854476;

struct Ptrs { const void* p[30]; };

__device__ __forceinline__ float bf2f(unsigned short h){
  unsigned u = ((unsigned)h) << 16;
  return __uint_as_float(u);
}
__device__ __forceinline__ float gelu_f(float x){ return 0.5f*x*(1.0f+erff(x*0.70710678118654752440f)); }

// ---------------- init: zero stats/c/M + detect input dtype ----------------
// block 0: stat + c + flag.  blocks 1..192: zero M (49152 floats).
__global__ void k_init(const unsigned* __restrict__ gones, float* __restrict__ stat,
                       float* __restrict__ c, float* __restrict__ M, int* __restrict__ flag){
  if (blockIdx.x == 0){
    stat[threadIdx.x] = 0.0f;
    if (threadIdx.x < 128) c[threadIdx.x] = 0.0f;
    if (threadIdx.x == 0) *flag = (gones[0] == 0x3F800000u) ? 1 : 0;
  } else {
    M[(blockIdx.x-1)*256 + threadIdx.x] = 0.0f;
  }
}

// ---------------- stage all weights (inputs 1..29) to f32 ----------------
__global__ __launch_bounds__(256) void k_stage(Ptrs ptrs, float* __restrict__ dst, const int* __restrict__ flag){
  const int cnt[29] = {21,21,4096,256,786432,96,4096,16,512,32,96,32,21,21,32,32,32,32,1,49152,96,9216,96,5,1,1,1,1,1};
  const int off[29] = {S_WDCT,S_BDCT,S_WE,S_BE,S_WL,S_BL,S_WD,S_BDRES,S_WDC,S_BDC,S_WDC1,S_BDC1,
                       S_GD,S_BDN,S_GP,S_BP,S_GDEP,S_BDEP,S_THR,S_WM1,S_BM1,S_WM2,S_BM2,
                       S_ADWW,S_ADWB,S_ACW,S_ACB,S_AG,S_AB2};
  int mode = *flag;
  int gid = blockIdx.x*256 + threadIdx.x;
  int a = -1, loc = 0, base = 0;
  #pragma unroll
  for (int i = 0; i < 29; i++){
    if (a < 0 && gid < base + cnt[i]){ a = i; loc = gid - base; }
    base += cnt[i];
  }
  if (a < 0) return;
  const void* s = ptrs.p[a+1];
  float v = mode ? ((const float*)s)[loc] : bf2f(((const unsigned short*)s)[loc]);
  dst[off[a] + loc] = v;
}

// ---------------- transpose x (B,L,D) -> xt (B*D, L) f32, dual dtype ----------------
__global__ __launch_bounds__(256) void k_transpose(const void* __restrict__ x, float* __restrict__ xt,
                                                   const int* __restrict__ flag){
  __shared__ float xs[L_*DV];
  int mode = *flag;
  int b = blockIdx.x;
  if (mode){
    const float* xp = (const float*)x + (size_t)b*(L_*DV);
    for (int i = threadIdx.x; i < L_*DV; i += 256) xs[i] = xp[i];
  } else {
    const unsigned short* xp = (const unsigned short*)x + (size_t)b*(L_*DV);
    for (int i = threadIdx.x; i < L_*DV; i += 256) xs[i] = bf2f(xp[i]);
  }
  __syncthreads();
  float* op = xt + (size_t)b*(L_*DV);
  for (int i = threadIdx.x; i < L_*DV; i += 256){
    int l = i & 511, d = i >> 9;
    op[i] = xs[l*DV + d];
  }
}

// ---------------- DCT matrices (exact integer range reduction) ----------------
__global__ __launch_bounds__(256) void k_dctmats(float* __restrict__ D2, float* __restrict__ D3){
  int i = blockIdx.x*256 + threadIdx.x;
  int kk = i >> 9, m = i & 511;
  const float PIo = 3.14159265358979323846f / 1024.0f;
  int a = ((2*m+1)*kk) & 2047;
  D2[i] = 2.0f * cosf(PIo * (float)a);
  int l = kk, k = m;
  int a2 = ((2*l+1)*k) & 2047;
  float w0 = (k==0) ? 0.5f : 1.0f;
  D3[i] = cosf(PIo * (float)a2) * w0 * (1.0f/512.0f);
}

// ---------------- dvec[m] = sum_k 2cos(pi(2m+1)k/1024) * s_ortho[k] * a_dw_w[k] ----------------
// (a_dw_b cancels exactly through the BatchNorm over att -> skipped)
__global__ void k_dvec(const float* __restrict__ S, float* __restrict__ dvec){
  int m = blockIdx.x*256 + threadIdx.x;   // 0..511
  const float PIo = 3.14159265358979323846f / 1024.0f;
  const float rs = 22.627416997969522f;   // sqrt(512)
  float s = 0.f;
  #pragma unroll
  for (int k = 0; k < 5; k++){
    float sk = ((k == 0) ? 0.5f : 0.70710678118654752440f) / rs;
    int a = ((2*m+1)*k) & 2047;
    s += 2.0f * cosf(PIo * (float)a) * sk * S[S_ADWW + k];
  }
  dvec[m] = s;
}

// ---------------- fold M = We@Wl blocks: K-split, 1536 blocks, atomic partials ----------------
__global__ __launch_bounds__(256) void k_foldM(const float* __restrict__ S, float* __restrict__ M){
  const float* We = S + S_WE;  const float* Wl = S + S_WL;
  int gid = blockIdx.x*256 + threadIdx.x;   // 0..49151 = (l,p)
  int l = gid/96, p = gid - l*96;
  int n = l>>4, q = l&15;
  int j0 = blockIdx.y*32;
  float acc = 0.f;
  #pragma unroll 8
  for (int j = j0; j < j0+32; j++) acc += We[q*256+j] * Wl[(size_t)(n*256+j)*96 + p];
  atomicAdd(&M[gid], acc);
}

// ---------------- fold c[p] = bl[p] + sum_J be[J&255]*Wl[J*96+p], 128 blocks ----------------
__global__ __launch_bounds__(256) void k_foldC(const float* __restrict__ S, float* __restrict__ c){
  const float* be = S + S_BE;  const float* Wl = S + S_WL;  const float* bl = S + S_BL;
  int t = threadIdx.x;
  int rp = t >> 7, p = t & 127;      // 2 J-rows in flight per iteration
  if (p >= 96) return;
  float acc = 0.f;
  int J0 = blockIdx.x*64;
  for (int j = 0; j < 64; j += 2){
    int J = J0 + j + rp;
    acc += be[J & 255] * Wl[(size_t)J*96 + p];
  }
  if (blockIdx.x == 0 && rp == 0) acc += bl[p];
  atomicAdd(&c[p], acc);
}

// ---------------- fold Tn/tb per n: all operands staged to LDS first ----------------
__global__ __launch_bounds__(256) void k_foldTn(const float* __restrict__ S,
    float* __restrict__ Tn, float* __restrict__ tb){
  __shared__ float WeS[4096];
  __shared__ float WdS[4096];
  __shared__ float wdcS[16];
  __shared__ float beS[256];
  __shared__ float bdresS[16];
  int n = blockIdx.x, tid = threadIdx.x;
  for (int i = tid; i < 4096; i += 256){ WeS[i] = S[S_WE+i]; WdS[i] = S[S_WD+i]; }
  beS[tid & 255] = S[S_BE + (tid & 255)];
  if (tid < 16){ wdcS[tid] = S[S_WDC + n*16 + tid]; bdresS[tid] = S[S_BDRES + tid]; }
  __syncthreads();
  int q2 = tid>>4, q = tid&15;
  float R = 0.f;
  for (int j = 0; j < 256; j++) R += WeS[q2*256+j] * WdS[j*16+q];
  float G = 0.f;
  #pragma unroll
  for (int p = 0; p < 16; p++) G += WeS[q2*256 + q*16 + p] * wdcS[p];
  Tn[n*256 + q2*16 + q] = R + G;
  if (tid < 16){
    float rb = bdresS[tid];
    for (int j = 0; j < 256; j++) rb += beS[j] * WdS[j*16+tid];
    float gb = S[S_BDC + n];
    #pragma unroll
    for (int p = 0; p < 16; p++) gb += beS[tid*16+p] * wdcS[p];
    tb[n*16+tid] = rb + gb;
  }
}

// ---------------- tiled f32 GEMM: C[r,col] = sum_m A'[r,m]*Bm[col*512+m] ----------------
// MODE 0: plain.  MODE 1: A' = alpha_d*A+beta_d, epilogue += xt*w_dct+b_dct.
// MODE 3: blockIdx.x<2 -> A' = att*A + (1-att)*A2 ; else A' = xt.  (MLP/zres fused GEMM)
template<int MODE>
__global__ __launch_bounds__(256) void k_gemm(
    const float* __restrict__ A, const float* __restrict__ A2,
    const float* __restrict__ Bm, float* __restrict__ C,
    const float* __restrict__ ab, const float* __restrict__ xt,
    const float* __restrict__ wdct, const float* __restrict__ bdct, int Cstride){
  __shared__ float As[16][68];   // pad 68 keeps 16B alignment for float4 reads
  __shared__ float Bs[16][68];
  int tid = threadIdx.x;
  int tx = tid & 15, ty = tid >> 4;
  int rowBase = blockIdx.y * 64;
  int colBase = blockIdx.x * 64;
  int lr = tid >> 2;
  int lk = (tid & 3) << 2;
  float alpha = 1.f, beta = 0.f;
  bool mixA = false;
  if (MODE == 1){ int d = (rowBase + lr) % DV; alpha = ab[2*d]; beta = ab[2*d+1]; }
  if (MODE == 3){ mixA = (blockIdx.x < 2); if (mixA) alpha = ab[rowBase + lr]; }
  float acc[4][4] = {};
  for (int k0 = 0; k0 < 512; k0 += 16){
    float4 av;
    if (MODE == 3 && !mixA) av = *(const float4*)(xt + (size_t)(rowBase+lr)*512 + k0 + lk);
    else                    av = *(const float4*)(A  + (size_t)(rowBase+lr)*512 + k0 + lk);
    if (MODE == 1){ av.x = alpha*av.x+beta; av.y = alpha*av.y+beta; av.z = alpha*av.z+beta; av.w = alpha*av.w+beta; }
    if (MODE == 3 && mixA){
      float4 a2 = *(const float4*)(A2 + (size_t)(rowBase+lr)*512 + k0 + lk);
      float om = 1.0f - alpha;
      av.x = alpha*av.x + om*a2.x; av.y = alpha*av.y + om*a2.y;
      av.z = alpha*av.z + om*a2.z; av.w = alpha*av.w + om*a2.w;
    }
    As[lk+0][lr] = av.x; As[lk+1][lr] = av.y; As[lk+2][lr] = av.z; As[lk+3][lr] = av.w;
    float4 bv = *(const float4*)(Bm + (size_t)(colBase+lr)*512 + k0 + lk);
    Bs[lk+0][lr] = bv.x; Bs[lk+1][lr] = bv.y; Bs[lk+2][lr] = bv.z; Bs[lk+3][lr] = bv.w;
    __syncthreads();
    #pragma unroll
    for (int kk = 0; kk < 16; kk++){
      float4 a4 = *(const float4*)&As[kk][ty*4];
      float4 b4 = *(const float4*)&Bs[kk][tx*4];
      acc[0][0] += a4.x*b4.x; acc[0][1] += a4.x*b4.y; acc[0][2] += a4.x*b4.z; acc[0][3] += a4.x*b4.w;
      acc[1][0] += a4.y*b4.x; acc[1][1] += a4.y*b4.y; acc[1][2] += a4.y*b4.z; acc[1][3] += a4.y*b4.w;
      acc[2][0] += a4.z*b4.x; acc[2][1] += a4.z*b4.y; acc[2][2] += a4.z*b4.z; acc[2][3] += a4.z*b4.w;
      acc[3][0] += a4.w*b4.x; acc[3][1] += a4.w*b4.y; acc[3][2] += a4.w*b4.z; acc[3][3] += a4.w*b4.w;
    }
    __syncthreads();
  }
  #pragma unroll
  for (int i = 0; i < 4; i++){
    int r = rowBase + ty*4 + i;
    #pragma unroll
    for (int j = 0; j < 4; j++){
      int cc = colBase + tx*4 + j;
      float v = acc[i][j];
      if (MODE == 1){
        int d = r % DV;
        v += xt[(size_t)r*512 + cc] * wdct[d] + bdct[d];
      }
      C[(size_t)r*Cstride + cc] = v;
    }
  }
}

// ---------------- energy per row ----------------
__global__ __launch_bounds__(256) void k_energy(const float* __restrict__ z, float* __restrict__ e){
  int tid = threadIdx.x;
  int r = blockIdx.x*4 + (tid>>6);
  int lane = tid & 63;
  const float* p = z + (size_t)r*512;
  float s = 0.f;
  #pragma unroll
  for (int w = 0; w < 8; w++){ float v = p[lane + w*64]; s += v*v; }
  for (int off = 32; off; off >>= 1) s += __shfl_down(s, off);
  if (lane == 0) e[r] = s;
}

// ---------------- median per batch row + norm_e ----------------
__global__ __launch_bounds__(256) void k_med(const float* __restrict__ e, float* __restrict__ norm){
  int b = threadIdx.x;
  float v[DV];
  for (int d = 0; d < DV; d++) v[d] = e[b*DV + d];
  float med = 0.f;
  for (int i = 0; i < DV; i++){
    int rk = 0;
    for (int j = 0; j < DV; j++) rk += (v[j] < v[i]) || (v[j] == v[i] && j < i);
    if (rk == 10) med = v[i];
  }
  float den = med + 1e-6f;
  for (int d = 0; d < DV; d++) norm[b*DV + d] = v[d] / den;
}

// ---------------- distributed rank-count quantile: 16 candidates/block, 16-way scan ----------------
__global__ __launch_bounds__(256) void k_rank(const float* __restrict__ norm,
    const float* __restrict__ thrv, float* __restrict__ stat){
  int tid = threadIdx.x;
  int cand = tid >> 4, part = tid & 15;
  int idx = blockIdx.x*16 + cand;
  float val = norm[idx];
  int cnt = 0;
  int j0 = part*336;
  for (int j = j0; j < j0 + 336; ++j){
    float v = norm[j];
    cnt += (v < val) || (v == val && j < idx);
  }
  __shared__ int sc[16][17];
  sc[cand][part] = cnt;
  __syncthreads();
  if (part == 0){
    int rank = 0;
    #pragma unroll
    for (int i = 0; i < 16; i++) rank += sc[cand][i];
    float q = thrv[0];
    float pos = q * 5375.0f;
    int i0 = (int)floorf(pos);
    int i1 = (i0 + 1 > 5375) ? 5375 : i0 + 1;
    if (rank == i0) stat[200] = val;
    if (rank == i1) stat[201] = val;
  }
}

// ---------------- mask + scale + gelu + BN stats (in-place over zA) ----------------
__global__ __launch_bounds__(256) void k_maskgelu(float* __restrict__ zA, const float* __restrict__ norm,
    const float* __restrict__ stat, const float* __restrict__ thrv,
    const float* __restrict__ wdct, const float* __restrict__ bdct,
    float* __restrict__ dstats){
  int r = blockIdx.x, tid = threadIdx.x;
  int d = r % DV;
  float q = thrv[0];
  float pos = q * 5375.0f; float f = pos - floorf(pos);
  float thr = stat[200] + (stat[201] - stat[200]) * f;
  float mask = norm[r] > thr ? 1.0f : 0.0f;
  float w = wdct[d], b = bdct[d];
  float s = 0.f, s2 = 0.f;
  for (int i = tid; i < 512; i += 256){
    float v = zA[(size_t)r*512 + i] * mask * w + b;
    float g = gelu_f(v);
    zA[(size_t)r*512 + i] = g;
    s += g; s2 += g*g;
  }
  for (int off = 32; off; off >>= 1){ s += __shfl_down(s, off); s2 += __shfl_down(s2, off); }
  __shared__ float wsum[4][2];
  int wv = tid >> 6;
  if ((tid & 63) == 0){ wsum[wv][0] = s; wsum[wv][1] = s2; }
  __syncthreads();
  if (tid == 0){
    float S  = wsum[0][0]+wsum[1][0]+wsum[2][0]+wsum[3][0];
    float S2 = wsum[0][1]+wsum[1][1]+wsum[2][1]+wsum[3][1];
    atomicAdd(&dstats[2*d], S); atomicAdd(&dstats[2*d+1], S2);
  }
}

// ---------------- BN finalize: stats -> alpha,beta per channel ----------------
__global__ void k_bnfin(const float* __restrict__ stats, const float* __restrict__ g,
                        const float* __restrict__ b, int nchan, float count, float* __restrict__ ab){
  int c = threadIdx.x;
  if (c < nchan){
    float mean = stats[2*c] / count;
    float var  = stats[2*c+1] / count - mean*mean;
    float al = g[c] * rsqrtf(var + 1e-5f);
    float be = b[c] - mean * al;
    ab[2*c] = al; ab[2*c+1] = be;
  }
}

// ---------------- patch branch: t = zd+res; barrier-free, Tn in registers, x via shuffle ----------------
__global__ __launch_bounds__(256) void k_patch(const float* __restrict__ xt, const float* __restrict__ Tn,
    const float* __restrict__ tb, float* __restrict__ t, float* __restrict__ pstats){
  int blk = blockIdx.x, tid = threadIdx.x;
  int n0 = tid >> 4, qq = tid & 15;
  int n1 = n0 + 16;
  float T0[16], T1[16];
  #pragma unroll
  for (int q2 = 0; q2 < 16; q2++){
    T0[q2] = Tn[n0*256 + q2*16 + qq];
    T1[q2] = Tn[n1*256 + q2*16 + qq];
  }
  float tb0 = tb[n0*16 + qq], tb1 = tb[n1*16 + qq];
  float s0 = 0.f, q0 = 0.f, s1 = 0.f, q1 = 0.f;
  for (int rr = 0; rr < 8; rr++){
    int r = blk*8 + rr;
    float x0 = xt[(size_t)r*512 + tid];
    float x1 = xt[(size_t)r*512 + tid + 256];
    float a0 = tb0, a1 = tb1;
    #pragma unroll
    for (int q2 = 0; q2 < 16; q2++){
      a0 += __shfl(x0, q2, 16) * T0[q2];
      a1 += __shfl(x1, q2, 16) * T1[q2];
    }
    t[(size_t)r*512 + tid] = a0;       s0 += a0; q0 += a0*a0;
    t[(size_t)r*512 + tid + 256] = a1; s1 += a1; q1 += a1*a1;
  }
  #pragma unroll
  for (int off = 1; off < 16; off <<= 1){
    s0 += __shfl_xor(s0, off); q0 += __shfl_xor(q0, off);
    s1 += __shfl_xor(s1, off); q1 += __shfl_xor(q1, off);
  }
  if (qq == 0){
    atomicAdd(&pstats[2*n0], s0); atomicAdd(&pstats[2*n0+1], q0);
    atomicAdd(&pstats[2*n1], s1); atomicAdd(&pstats[2*n1+1], q1);
  }
}

// ---------------- z2 = gelu(bn(t)) [in-place]; zc_pre = conv3(z2); barrier-free via shuffles ----------------
__global__ __launch_bounds__(256) void k_z2(float* __restrict__ t, float* __restrict__ zcp,
    const float* __restrict__ abp, const float* __restrict__ wdc1,
    const float* __restrict__ bdc1, float* __restrict__ depstats){
  int blk = blockIdx.x, tid = threadIdx.x;
  int n0 = tid >> 4, qq = tid & 15;
  int n1 = n0 + 16;
  float al0 = abp[2*n0], be0 = abp[2*n0+1], al1 = abp[2*n1], be1 = abp[2*n1+1];
  float w00 = wdc1[n0*3], w01 = wdc1[n0*3+1], w02 = wdc1[n0*3+2], bb0 = bdc1[n0];
  float w10 = wdc1[n1*3], w11 = wdc1[n1*3+1], w12 = wdc1[n1*3+2], bb1 = bdc1[n1];
  float s0 = 0.f, q0 = 0.f, s1 = 0.f, q1 = 0.f;
  for (int rr = 0; rr < 8; rr++){
    int r = blk*8 + rr;
    float v0 = t[(size_t)r*512 + tid];
    float v1 = t[(size_t)r*512 + tid + 256];
    float z0  = gelu_f(al0*v0 + be0);
    float z1v = gelu_f(al1*v1 + be1);
    float l0 = __shfl_up(z0, 1, 16);    if (qq == 0)  l0 = 0.f;
    float r0 = __shfl_down(z0, 1, 16);  if (qq == 15) r0 = 0.f;
    float l1 = __shfl_up(z1v, 1, 16);   if (qq == 0)  l1 = 0.f;
    float r1 = __shfl_down(z1v, 1, 16); if (qq == 15) r1 = 0.f;
    float cv0 = w00*l0 + w01*z0  + w02*r0 + bb0;
    float cv1 = w10*l1 + w11*z1v + w12*r1 + bb1;
    zcp[(size_t)r*512 + tid] = cv0;       t[(size_t)r*512 + tid] = z0;
    zcp[(size_t)r*512 + tid + 256] = cv1; t[(size_t)r*512 + tid + 256] = z1v;
    s0 += cv0; q0 += cv0*cv0; s1 += cv1; q1 += cv1*cv1;
  }
  #pragma unroll
  for (int off = 1; off < 16; off <<= 1){
    s0 += __shfl_xor(s0, off); q0 += __shfl_xor(q0, off);
    s1 += __shfl_xor(s1, off); q1 += __shfl_xor(q1, off);
  }
  if (qq == 0){
    atomicAdd(&depstats[2*n0], s0); atomicAdd(&depstats[2*n0+1], q0);
    atomicAdd(&depstats[2*n1], s1); atomicAdd(&depstats[2*n1+1], q1);
  }
}

// ---------------- z2f = gelu(bn(zcp)) + z2  (in-place over zcp) ----------------
__global__ __launch_bounds__(256) void k_z2f(float* __restrict__ zcp, const float* __restrict__ z2,
    const float* __restrict__ ab){
  int idx = blockIdx.x*256 + threadIdx.x;
  int n = (idx >> 4) & 31;
  zcp[idx] = gelu_f(ab[2*n]*zcp[idx] + ab[2*n+1]) + z2[idx];
}

// ---------------- attention scalar per row: att[r] = sum_m z1*z2f*dvec  (no atomics) ----------------
__global__ __launch_bounds__(256) void k_att(const float* __restrict__ z1, const float* __restrict__ z2f,
    const float* __restrict__ dvec, float* __restrict__ att){
  int tid = threadIdx.x;
  int r = blockIdx.x*4 + (tid >> 6);
  int lane = tid & 63;
  const float* p1 = z1  + (size_t)r*512;
  const float* p2 = z2f + (size_t)r*512;
  float s = 0.f;
  #pragma unroll
  for (int w = 0; w < 8; w++){
    int m = lane + w*64;
    s += p1[m] * p2[m] * dvec[m];
  }
  for (int off = 32; off; off >>= 1) s += __shfl_down(s, off);
  if (lane == 0) att[r] = s;
}

// ---------------- att reduce + BN + gelu + softmax over d (single block) ----------------
__global__ __launch_bounds__(256) void k_attfin(const float* __restrict__ att, const float* __restrict__ S,
                                                float* __restrict__ att1){
  __shared__ float ws[4][2];
  int tid = threadIdx.x;
  float s = 0.f, s2 = 0.f;
  for (int i = tid; i < NROW; i += 256){ float a = att[i]; s += a; s2 += a*a; }
  for (int off = 32; off; off >>= 1){ s += __shfl_down(s, off); s2 += __shfl_down(s2, off); }
  if ((tid & 63) == 0){ ws[tid>>6][0] = s; ws[tid>>6][1] = s2; }
  __syncthreads();
  float S1 = ws[0][0]+ws[1][0]+ws[2][0]+ws[3][0];
  float S2 = ws[0][1]+ws[1][1]+ws[2][1]+ws[3][1];
  float mean = S1 / 5376.0f;
  float var  = S2 / 5376.0f - mean*mean;
  float al = S[S_AG] * rsqrtf(var + 1e-5f);
  float bb = S[S_AB2];
  float cw = S[S_ACW], cb2 = S[S_ACB];
  int b = tid;
  float v[DV]; float mx = -1e30f;
  for (int d = 0; d < DV; d++){
    float a = att[b*DV + d];
    a = gelu_f(al*(a - mean) + bb);
    a = a*cw + cb2;
    v[d] = a; mx = fmaxf(mx, a);
  }
  float ss = 0.f;
  for (int d = 0; d < DV; d++){ v[d] = expf(v[d] - mx); ss += v[d]; }
  float inv = 1.0f / ss;
  for (int d = 0; d < DV; d++) att1[b*DV + d] = v[d] * inv;
}

// ---------------- build BcatT (256x512): rows 0..95 Wm1^T, 128..223 M^T, rest 0 ----------------
__global__ __launch_bounds__(256) void k_bcat(const float* __restrict__ Wm1, const float* __restrict__ M,
                                              float* __restrict__ BcatT){
  int i = blockIdx.x*256 + threadIdx.x;   // 131072
  int c = i >> 9, m = i & 511;
  float v = 0.f;
  if (c < 96) v = Wm1[m*96 + c];
  else if (c >= 128 && c < 224) v = M[m*96 + (c - 128)];
  BcatT[i] = v;
}

// ---------------- out = Zres + c + gelu(H + bm1) @ Wm2 + bm2, 16 rows/block ----------------
__global__ __launch_bounds__(256) void k_out(const float* __restrict__ Hcat, const float* __restrict__ c,
    const float* __restrict__ S, void* __restrict__ outv, const int* __restrict__ flag){
  const float* bm1 = S + S_BM1;
  const float* Wm2 = S + S_WM2;
  const float* bm2 = S + S_BM2;
  __shared__ float W2s[96*96];
  __shared__ float Hs[16][100];
  int blk = blockIdx.x, tid = threadIdx.x;
  int r0 = blk*16;
  for (int i = tid; i < 96*96; i += 256) W2s[i] = Wm2[i];
  for (int i = tid; i < 16*96; i += 256){
    int rr = i / 96, col = i - rr*96;
    Hs[rr][col] = gelu_f(Hcat[(size_t)(r0+rr)*256 + col] + bm1[col]);
  }
  __syncthreads();
  int rr = tid >> 4, c0 = (tid & 15)*6;
  float acc[6] = {};
  for (int k = 0; k < 96; k++){
    float h = Hs[rr][k];
    #pragma unroll
    for (int j = 0; j < 6; j++) acc[j] += h * W2s[k*96 + c0 + j];
  }
  int r = r0 + rr;
  int b = r / DV, d = r - b*DV;
  int mode = *flag;
  #pragma unroll
  for (int j = 0; j < 6; j++){
    int p = c0 + j;
    float val = Hcat[(size_t)r*256 + 128 + p] + c[p] + acc[j] + bm2[p];
    size_t oi = ((size_t)b*96 + p)*DV + d;
    if (mode) ((float*)outv)[oi] = val;
    else ((__hip_bfloat16*)outv)[oi] = __float2bfloat16(val);
  }
}

extern "C" void kernel_launch(void* const* d_in, const int* in_sizes, int n_in,
                              void* d_out, int out_size, void* d_ws, size_t ws_size,
                              hipStream_t stream) {
  float* w = (float*)d_ws;
  float* xt   = w + OFF_XT;
  float* zA   = w + OFF_ZA;
  float* z1   = w + OFF_Z1;
  float* zcp  = w + OFF_ZCP;
  float* D2   = w + OFF_D2;
  float* D3   = w + OFF_D3;
  float* Mb   = w + OFF_M;
  float* Tn   = w + OFF_TN;
  float* tb   = w + OFF_TB;
  float* cb   = w + OFF_C;
  float* en   = w + OFF_EN;
  float* nrm  = w + OFF_NORM;
  float* att  = w + OFF_ATT;
  float* att1 = w + OFF_ATT1;
  float* dvec = w + OFF_ATT1;     // alias: dvec dead before att1 is written
  float* stat = w + OFF_STAT;
  float* abd  = w + OFF_ABD;
  float* abp  = w + OFF_ABP;
  float* abdep= w + OFF_ABDEP;
  int*   flag = (int*)(w + OFF_FLAG);
  float* S    = w + OFF_STG;
  float* Hcat = zA;               // 5376x256, alias (zA dead after z2f)
  float* BcatT= zA + 1500000;     // 256x512, alias

  Ptrs ptrs;
  for (int i = 0; i < 30; i++) ptrs.p[i] = d_in[i];

  k_init<<<193, 256, 0, stream>>>((const unsigned*)d_in[13], stat, cb, Mb, flag);
  k_stage<<<3338, 256, 0, stream>>>(ptrs, S, flag);
  k_transpose<<<B_, 256, 0, stream>>>(d_in[0], xt, flag);
  k_dctmats<<<1024, 256, 0, stream>>>(D2, D3);
  k_dvec<<<2, 256, 0, stream>>>(S, dvec);
  k_foldM<<<dim3(192, 8), 256, 0, stream>>>(S, Mb);
  k_foldC<<<128, 256, 0, stream>>>(S, cb);
  k_foldTn<<<32, 256, 0, stream>>>(S, Tn, tb);

  k_gemm<0><<<dim3(8,84), 256, 0, stream>>>(xt, nullptr, D2, zA, nullptr, nullptr, nullptr, nullptr, 512);
  k_energy<<<NROW/4, 256, 0, stream>>>(zA, en);
  k_med<<<1, 256, 0, stream>>>(en, nrm);
  k_rank<<<336, 256, 0, stream>>>(nrm, S+S_THR, stat);
  k_maskgelu<<<NROW, 256, 0, stream>>>(zA, nrm, stat, S+S_THR, S+S_WDCT, S+S_BDCT, stat + 0);
  k_bnfin<<<1, 64, 0, stream>>>(stat + 0, S+S_GD, S+S_BDN, DV, 131072.0f, abd);
  k_gemm<1><<<dim3(8,84), 256, 0, stream>>>(zA, nullptr, D3, z1, abd, xt, S+S_WDCT, S+S_BDCT, 512);

  k_patch<<<NROW/8, 256, 0, stream>>>(xt, Tn, tb, zA, stat + 42);
  k_bnfin<<<1, 64, 0, stream>>>(stat + 42, S+S_GP, S+S_BP, NP, 86016.0f, abp);
  k_z2<<<NROW/8, 256, 0, stream>>>(zA, zcp, abp, S+S_WDC1, S+S_BDC1, stat + 106);
  k_bnfin<<<1, 64, 0, stream>>>(stat + 106, S+S_GDEP, S+S_BDEP, NP, 86016.0f, abdep);
  k_z2f<<<NROW*2, 256, 0, stream>>>(zcp, zA, abdep);

  k_att<<<NROW/4, 256, 0, stream>>>(z1, zcp, dvec, att);
  k_attfin<<<1, 256, 0, stream>>>(att, S, att1);

  k_bcat<<<512, 256, 0, stream>>>(S+S_WM1, Mb, BcatT);
  k_gemm<3><<<dim3(4,84), 256, 0, stream>>>(z1, zcp, BcatT, Hcat, att1, xt, nullptr, nullptr, 256);
  k_out<<<NROW/16, 256, 0, stream>>>(Hcat, cb, S, d_out, flag);
}

// Round 7
// 395.690 us; speedup vs baseline: 1.4737x; 1.4737x over previous
//
#include <hip/hip_runtime.h>
#include <hip/hip_bf16.h>

#define B_    256
#define L_    512
#define DV    21
#define NROW  5376       // B_*DV
#define NP    32
#define PP    16
#define PRED_ 96

// ---------------- workspace layout (float indices) ----------------
static const size_t OFF_XT    = 0;          // 5376x512 f32
static const size_t OFF_ZA    = 2752512;    // z_dct -> z -> t -> z2 -> Hcat/BcatT (aliased over time)
static const size_t OFF_Z1    = 5505024;
static const size_t OFF_ZCP   = 8257536;    // zc_pre -> z2f (in-place)
static const size_t OFF_D2    = 11010048;   // 512x512 ; dead after k_gemm<0> -> reused for dct+patch stat partials
static const size_t OFF_D3    = 11272192;   // 512x512 ; dead after k_gemm<1> -> reused for depth stat partials
static const size_t OFF_M     = 11534336;   // 512x96 folded linres
static const size_t OFF_TN    = 11583488;   // 32x16x16
static const size_t OFF_TB    = 11591680;   // 32x16
static const size_t OFF_C     = 11592192;   // 96 (pad 128)
static const size_t OFF_EN    = 11592320;   // 5376
static const size_t OFF_NORM  = 11597696;
static const size_t OFF_ATT   = 11603072;
static const size_t OFF_ATT1  = 11608448;   // also aliases dvec (512) before k_attfin writes att1
static const size_t OFF_STAT  = 11613824;   // 256: [200],[201]=quantile order stats
static const size_t OFF_ABD   = 11614080;   // 64
static const size_t OFF_ABP   = 11614144;   // 64
static const size_t OFF_ABDEP = 11614208;   // 64
static const size_t OFF_FLAG  = 11614272;   // int mode flag (1=f32 inputs, 0=bf16)
static const size_t OFF_STG   = 11614336;   // staged f32 weights (854480)
// total 12468816 floats = 49.9 MB
// aliases inside OFF_ZA region (live only after z2f):
//   Hcat  = OFF_ZA            (5376 x 256)
//   BcatT = OFF_ZA + 1500000  (256 x 512)

// staged-weight offsets (relative to OFF_STG)
static const int S_WDCT=0, S_BDCT=24, S_WE=48, S_BE=4144, S_WL=4400, S_BL=790832,
  S_WD=790928, S_BDRES=795024, S_WDC=795040, S_BDC=795552, S_WDC1=795584, S_BDC1=795680,
  S_GD=795712, S_BDN=795736, S_GP=795760, S_BP=795792, S_GDEP=795824, S_BDEP=795856,
  S_THR=795888, S_WM1=795892, S_BM1=845044, S_WM2=845140, S_BM2=854356,
  S_ADWW=854452, S_ADWB=854460, S_ACW=854464, S_ACB=854468, S_AG=854472, S_AB2=854476;

struct Ptrs { const void* p[30]; };

__device__ __forceinline__ float bf2f(unsigned short h){
  unsigned u = ((unsigned)h) << 16;
  return __uint_as_float(u);
}
__device__ __forceinline__ float gelu_f(float x){ return 0.5f*x*(1.0f+erff(x*0.70710678118654752440f)); }

// ---------------- init: zero stats/c/M + detect input dtype ----------------
__global__ void k_init(const unsigned* __restrict__ gones, float* __restrict__ stat,
                       float* __restrict__ c, float* __restrict__ M, int* __restrict__ flag){
  if (blockIdx.x == 0){
    stat[threadIdx.x] = 0.0f;
    if (threadIdx.x < 128) c[threadIdx.x] = 0.0f;
    if (threadIdx.x == 0) *flag = (gones[0] == 0x3F800000u) ? 1 : 0;
  } else {
    M[(blockIdx.x-1)*256 + threadIdx.x] = 0.0f;
  }
}

// ---------------- stage all weights (inputs 1..29) to f32 ----------------
__global__ __launch_bounds__(256) void k_stage(Ptrs ptrs, float* __restrict__ dst, const int* __restrict__ flag){
  const int cnt[29] = {21,21,4096,256,786432,96,4096,16,512,32,96,32,21,21,32,32,32,32,1,49152,96,9216,96,5,1,1,1,1,1};
  const int off[29] = {S_WDCT,S_BDCT,S_WE,S_BE,S_WL,S_BL,S_WD,S_BDRES,S_WDC,S_BDC,S_WDC1,S_BDC1,
                       S_GD,S_BDN,S_GP,S_BP,S_GDEP,S_BDEP,S_THR,S_WM1,S_BM1,S_WM2,S_BM2,
                       S_ADWW,S_ADWB,S_ACW,S_ACB,S_AG,S_AB2};
  int mode = *flag;
  int gid = blockIdx.x*256 + threadIdx.x;
  int a = -1, loc = 0, base = 0;
  #pragma unroll
  for (int i = 0; i < 29; i++){
    if (a < 0 && gid < base + cnt[i]){ a = i; loc = gid - base; }
    base += cnt[i];
  }
  if (a < 0) return;
  const void* s = ptrs.p[a+1];
  float v = mode ? ((const float*)s)[loc] : bf2f(((const unsigned short*)s)[loc]);
  dst[off[a] + loc] = v;
}

// ---------------- transpose x (B,L,D) -> xt (B*D, L), 4 chunks per batch ----------------
__global__ __launch_bounds__(256) void k_transpose(const void* __restrict__ x, float* __restrict__ xt,
                                                   const int* __restrict__ flag){
  __shared__ float xs[128*DV];
  int mode = *flag;
  int b = blockIdx.x >> 2, ch = blockIdx.x & 3;
  int l0 = ch*128;
  size_t base = (size_t)b*(L_*DV) + (size_t)l0*DV;
  if (mode){
    const float* xp = (const float*)x + base;
    for (int i = threadIdx.x; i < 128*DV; i += 256) xs[i] = xp[i];
  } else {
    const unsigned short* xp = (const unsigned short*)x + base;
    for (int i = threadIdx.x; i < 128*DV; i += 256) xs[i] = bf2f(xp[i]);
  }
  __syncthreads();
  for (int i = threadIdx.x; i < 128*DV; i += 256){
    int d = i >> 7, l = i & 127;
    xt[((size_t)b*DV + d)*512 + l0 + l] = xs[l*DV + d];
  }
}

// ---------------- DCT matrices (exact integer range reduction) ----------------
__global__ __launch_bounds__(256) void k_dctmats(float* __restrict__ D2, float* __restrict__ D3){
  int i = blockIdx.x*256 + threadIdx.x;
  int kk = i >> 9, m = i & 511;
  const float PIo = 3.14159265358979323846f / 1024.0f;
  int a = ((2*m+1)*kk) & 2047;
  D2[i] = 2.0f * cosf(PIo * (float)a);
  int l = kk, k = m;
  int a2 = ((2*l+1)*k) & 2047;
  float w0 = (k==0) ? 0.5f : 1.0f;
  D3[i] = cosf(PIo * (float)a2) * w0 * (1.0f/512.0f);
}

// ---------------- dvec[m] = sum_k 2cos(pi(2m+1)k/1024) * s_ortho[k] * a_dw_w[k] ----------------
__global__ void k_dvec(const float* __restrict__ S, float* __restrict__ dvec){
  int m = blockIdx.x*256 + threadIdx.x;   // 0..511
  const float PIo = 3.14159265358979323846f / 1024.0f;
  const float rs = 22.627416997969522f;   // sqrt(512)
  float s = 0.f;
  #pragma unroll
  for (int k = 0; k < 5; k++){
    float sk = ((k == 0) ? 0.5f : 0.70710678118654752440f) / rs;
    int a = ((2*m+1)*k) & 2047;
    s += 2.0f * cosf(PIo * (float)a) * sk * S[S_ADWW + k];
  }
  dvec[m] = s;
}

// ---------------- fold M = We@Wl blocks: K-split, 1536 blocks, atomic partials ----------------
__global__ __launch_bounds__(256) void k_foldM(const float* __restrict__ S, float* __restrict__ M){
  const float* We = S + S_WE;  const float* Wl = S + S_WL;
  int gid = blockIdx.x*256 + threadIdx.x;   // 0..49151 = (l,p)
  int l = gid/96, p = gid - l*96;
  int n = l>>4, q = l&15;
  int j0 = blockIdx.y*32;
  float acc = 0.f;
  #pragma unroll 8
  for (int j = j0; j < j0+32; j++) acc += We[q*256+j] * Wl[(size_t)(n*256+j)*96 + p];
  atomicAdd(&M[gid], acc);
}

// ---------------- fold c[p] = bl[p] + sum_J be[J&255]*Wl[J*96+p], 128 blocks ----------------
__global__ __launch_bounds__(256) void k_foldC(const float* __restrict__ S, float* __restrict__ c){
  const float* be = S + S_BE;  const float* Wl = S + S_WL;  const float* bl = S + S_BL;
  int t = threadIdx.x;
  int rp = t >> 7, p = t & 127;
  if (p >= 96) return;
  float acc = 0.f;
  int J0 = blockIdx.x*64;
  for (int j = 0; j < 64; j += 2){
    int J = J0 + j + rp;
    acc += be[J & 255] * Wl[(size_t)J*96 + p];
  }
  if (blockIdx.x == 0 && rp == 0) acc += bl[p];
  atomicAdd(&c[p], acc);
}

// ---------------- fold Tn/tb per n: all operands staged to LDS first ----------------
__global__ __launch_bounds__(256) void k_foldTn(const float* __restrict__ S,
    float* __restrict__ Tn, float* __restrict__ tb){
  __shared__ float WeS[4096];
  __shared__ float WdS[4096];
  __shared__ float wdcS[16];
  __shared__ float beS[256];
  __shared__ float bdresS[16];
  int n = blockIdx.x, tid = threadIdx.x;
  for (int i = tid; i < 4096; i += 256){ WeS[i] = S[S_WE+i]; WdS[i] = S[S_WD+i]; }
  beS[tid & 255] = S[S_BE + (tid & 255)];
  if (tid < 16){ wdcS[tid] = S[S_WDC + n*16 + tid]; bdresS[tid] = S[S_BDRES + tid]; }
  __syncthreads();
  int q2 = tid>>4, q = tid&15;
  float R = 0.f;
  for (int j = 0; j < 256; j++) R += WeS[q2*256+j] * WdS[j*16+q];
  float G = 0.f;
  #pragma unroll
  for (int p = 0; p < 16; p++) G += WeS[q2*256 + q*16 + p] * wdcS[p];
  Tn[n*256 + q2*16 + q] = R + G;
  if (tid < 16){
    float rb = bdresS[tid];
    for (int j = 0; j < 256; j++) rb += beS[j] * WdS[j*16+tid];
    float gb = S[S_BDC + n];
    #pragma unroll
    for (int p = 0; p < 16; p++) gb += beS[tid*16+p] * wdcS[p];
    tb[n*16+tid] = rb + gb;
  }
}

// ---------------- tiled f32 GEMM: C[r,col] = sum_m A'[r,m]*Bm[col*512+m] ----------------
// MODE 0: plain.  MODE 1: A' = alpha_d*A+beta_d, epilogue += xt*w_dct+b_dct.
// MODE 3: blockIdx.x<2 -> A' = att*A + (1-att)*A2 ; else A' = xt.
template<int MODE>
__global__ __launch_bounds__(256) void k_gemm(
    const float* __restrict__ A, const float* __restrict__ A2,
    const float* __restrict__ Bm, float* __restrict__ C,
    const float* __restrict__ ab, const float* __restrict__ xt,
    const float* __restrict__ wdct, const float* __restrict__ bdct, int Cstride){
  __shared__ float As[16][68];
  __shared__ float Bs[16][68];
  int tid = threadIdx.x;
  int tx = tid & 15, ty = tid >> 4;
  int rowBase = blockIdx.y * 64;
  int colBase = blockIdx.x * 64;
  int lr = tid >> 2;
  int lk = (tid & 3) << 2;
  float alpha = 1.f, beta = 0.f;
  bool mixA = false;
  if (MODE == 1){ int d = (rowBase + lr) % DV; alpha = ab[2*d]; beta = ab[2*d+1]; }
  if (MODE == 3){ mixA = (blockIdx.x < 2); if (mixA) alpha = ab[rowBase + lr]; }
  float acc[4][4] = {};
  for (int k0 = 0; k0 < 512; k0 += 16){
    float4 av;
    if (MODE == 3 && !mixA) av = *(const float4*)(xt + (size_t)(rowBase+lr)*512 + k0 + lk);
    else                    av = *(const float4*)(A  + (size_t)(rowBase+lr)*512 + k0 + lk);
    if (MODE == 1){ av.x = alpha*av.x+beta; av.y = alpha*av.y+beta; av.z = alpha*av.z+beta; av.w = alpha*av.w+beta; }
    if (MODE == 3 && mixA){
      float4 a2 = *(const float4*)(A2 + (size_t)(rowBase+lr)*512 + k0 + lk);
      float om = 1.0f - alpha;
      av.x = alpha*av.x + om*a2.x; av.y = alpha*av.y + om*a2.y;
      av.z = alpha*av.z + om*a2.z; av.w = alpha*av.w + om*a2.w;
    }
    As[lk+0][lr] = av.x; As[lk+1][lr] = av.y; As[lk+2][lr] = av.z; As[lk+3][lr] = av.w;
    float4 bv = *(const float4*)(Bm + (size_t)(colBase+lr)*512 + k0 + lk);
    Bs[lk+0][lr] = bv.x; Bs[lk+1][lr] = bv.y; Bs[lk+2][lr] = bv.z; Bs[lk+3][lr] = bv.w;
    __syncthreads();
    #pragma unroll
    for (int kk = 0; kk < 16; kk++){
      float4 a4 = *(const float4*)&As[kk][ty*4];
      float4 b4 = *(const float4*)&Bs[kk][tx*4];
      acc[0][0] += a4.x*b4.x; acc[0][1] += a4.x*b4.y; acc[0][2] += a4.x*b4.z; acc[0][3] += a4.x*b4.w;
      acc[1][0] += a4.y*b4.x; acc[1][1] += a4.y*b4.y; acc[1][2] += a4.y*b4.z; acc[1][3] += a4.y*b4.w;
      acc[2][0] += a4.z*b4.x; acc[2][1] += a4.z*b4.y; acc[2][2] += a4.z*b4.z; acc[2][3] += a4.z*b4.w;
      acc[3][0] += a4.w*b4.x; acc[3][1] += a4.w*b4.y; acc[3][2] += a4.w*b4.z; acc[3][3] += a4.w*b4.w;
    }
    __syncthreads();
  }
  #pragma unroll
  for (int i = 0; i < 4; i++){
    int r = rowBase + ty*4 + i;
    #pragma unroll
    for (int j = 0; j < 4; j++){
      int cc = colBase + tx*4 + j;
      float v = acc[i][j];
      if (MODE == 1){
        int d = r % DV;
        v += xt[(size_t)r*512 + cc] * wdct[d] + bdct[d];
      }
      C[(size_t)r*Cstride + cc] = v;
    }
  }
}

// ---------------- energy per row ----------------
__global__ __launch_bounds__(256) void k_energy(const float* __restrict__ z, float* __restrict__ e){
  int tid = threadIdx.x;
  int r = blockIdx.x*4 + (tid>>6);
  int lane = tid & 63;
  const float* p = z + (size_t)r*512;
  float s = 0.f;
  #pragma unroll
  for (int w = 0; w < 8; w++){ float v = p[lane + w*64]; s += v*v; }
  for (int off = 32; off; off >>= 1) s += __shfl_down(s, off);
  if (lane == 0) e[r] = s;
}

// ---------------- median per batch row + norm_e ----------------
__global__ __launch_bounds__(256) void k_med(const float* __restrict__ e, float* __restrict__ norm){
  int b = threadIdx.x;
  float v[DV];
  for (int d = 0; d < DV; d++) v[d] = e[b*DV + d];
  float med = 0.f;
  for (int i = 0; i < DV; i++){
    int rk = 0;
    for (int j = 0; j < DV; j++) rk += (v[j] < v[i]) || (v[j] == v[i] && j < i);
    if (rk == 10) med = v[i];
  }
  float den = med + 1e-6f;
  for (int d = 0; d < DV; d++) norm[b*DV + d] = v[d] / den;
}

// ---------------- distributed rank-count quantile: 16 candidates/block, 16-way scan ----------------
__global__ __launch_bounds__(256) void k_rank(const float* __restrict__ norm,
    const float* __restrict__ thrv, float* __restrict__ stat){
  int tid = threadIdx.x;
  int cand = tid >> 4, part = tid & 15;
  int idx = blockIdx.x*16 + cand;
  float val = norm[idx];
  int cnt = 0;
  int j0 = part*336;
  for (int j = j0; j < j0 + 336; ++j){
    float v = norm[j];
    cnt += (v < val) || (v == val && j < idx);
  }
  __shared__ int sc[16][17];
  sc[cand][part] = cnt;
  __syncthreads();
  if (part == 0){
    int rank = 0;
    #pragma unroll
    for (int i = 0; i < 16; i++) rank += sc[cand][i];
    float q = thrv[0];
    float pos = q * 5375.0f;
    int i0 = (int)floorf(pos);
    int i1 = (i0 + 1 > 5375) ? 5375 : i0 + 1;
    if (rank == i0) stat[200] = val;
    if (rank == i1) stat[201] = val;
  }
}

// ---------------- mask + scale + gelu + BN partials (in-place over zA; no atomics) ----------------
// partial layout: part[(2d)*256 + brow], part[(2d+1)*256 + brow], d = r%21, brow = r/21
__global__ __launch_bounds__(256) void k_maskgelu(float* __restrict__ zA, const float* __restrict__ norm,
    const float* __restrict__ stat, const float* __restrict__ thrv,
    const float* __restrict__ wdct, const float* __restrict__ bdct,
    float* __restrict__ part){
  int r = blockIdx.x, tid = threadIdx.x;
  int d = r % DV, brow = r / DV;
  float q = thrv[0];
  float pos = q * 5375.0f; float f = pos - floorf(pos);
  float thr = stat[200] + (stat[201] - stat[200]) * f;
  float mask = norm[r] > thr ? 1.0f : 0.0f;
  float w = wdct[d], b = bdct[d];
  float s = 0.f, s2 = 0.f;
  for (int i = tid; i < 512; i += 256){
    float v = zA[(size_t)r*512 + i] * mask * w + b;
    float g = gelu_f(v);
    zA[(size_t)r*512 + i] = g;
    s += g; s2 += g*g;
  }
  for (int off = 32; off; off >>= 1){ s += __shfl_down(s, off); s2 += __shfl_down(s2, off); }
  __shared__ float wsum[4][2];
  int wv = tid >> 6;
  if ((tid & 63) == 0){ wsum[wv][0] = s; wsum[wv][1] = s2; }
  __syncthreads();
  if (tid == 0){
    float S  = wsum[0][0]+wsum[1][0]+wsum[2][0]+wsum[3][0];
    float S2 = wsum[0][1]+wsum[1][1]+wsum[2][1]+wsum[3][1];
    part[(2*d)*256 + brow] = S;
    part[(2*d+1)*256 + brow] = S2;
  }
}

// ---------------- BN finalize from partials: grid = nchan blocks ----------------
__global__ __launch_bounds__(256) void k_bnfin2(const float* __restrict__ part, int P,
    const float* __restrict__ g, const float* __restrict__ b, float count, float* __restrict__ ab){
  int c = blockIdx.x, tid = threadIdx.x;
  const float* ps = part + (size_t)(2*c)*P;
  const float* pq = part + (size_t)(2*c+1)*P;
  float s = 0.f, s2 = 0.f;
  for (int i = tid; i < P; i += 256){ s += ps[i]; s2 += pq[i]; }
  for (int off = 32; off; off >>= 1){ s += __shfl_down(s, off); s2 += __shfl_down(s2, off); }
  __shared__ float ws[4][2];
  if ((tid & 63) == 0){ ws[tid>>6][0] = s; ws[tid>>6][1] = s2; }
  __syncthreads();
  if (tid == 0){
    float S1 = ws[0][0]+ws[1][0]+ws[2][0]+ws[3][0];
    float S2 = ws[0][1]+ws[1][1]+ws[2][1]+ws[3][1];
    float mean = S1 / count;
    float var  = S2 / count - mean*mean;
    float al = g[c] * rsqrtf(var + 1e-5f);
    float be = b[c] - mean * al;
    ab[2*c] = al; ab[2*c+1] = be;
  }
}

// ---------------- patch branch: t = zd+res; 4 rows/block, partial-store stats ----------------
__global__ __launch_bounds__(256) void k_patch(const float* __restrict__ xt, const float* __restrict__ Tn,
    const float* __restrict__ tb, float* __restrict__ t, float* __restrict__ part){
  int blk = blockIdx.x, tid = threadIdx.x;
  int n0 = tid >> 4, qq = tid & 15;
  int n1 = n0 + 16;
  float T0[16], T1[16];
  #pragma unroll
  for (int q2 = 0; q2 < 16; q2++){
    T0[q2] = Tn[n0*256 + q2*16 + qq];
    T1[q2] = Tn[n1*256 + q2*16 + qq];
  }
  float tb0 = tb[n0*16 + qq], tb1 = tb[n1*16 + qq];
  float s0 = 0.f, q0 = 0.f, s1 = 0.f, q1 = 0.f;
  #pragma unroll
  for (int rr = 0; rr < 4; rr++){
    int r = blk*4 + rr;
    float x0 = xt[(size_t)r*512 + tid];
    float x1 = xt[(size_t)r*512 + tid + 256];
    float a0 = tb0, a1 = tb1;
    #pragma unroll
    for (int q2 = 0; q2 < 16; q2++){
      a0 += __shfl(x0, q2, 16) * T0[q2];
      a1 += __shfl(x1, q2, 16) * T1[q2];
    }
    t[(size_t)r*512 + tid] = a0;       s0 += a0; q0 += a0*a0;
    t[(size_t)r*512 + tid + 256] = a1; s1 += a1; q1 += a1*a1;
  }
  #pragma unroll
  for (int off = 1; off < 16; off <<= 1){
    s0 += __shfl_xor(s0, off); q0 += __shfl_xor(q0, off);
    s1 += __shfl_xor(s1, off); q1 += __shfl_xor(q1, off);
  }
  if (qq == 0){
    part[(2*n0)*1344 + blk] = s0; part[(2*n0+1)*1344 + blk] = q0;
    part[(2*n1)*1344 + blk] = s1; part[(2*n1+1)*1344 + blk] = q1;
  }
}

// ---------------- z2 = gelu(bn(t)) [in-place]; zc_pre = conv3(z2); 4 rows/block ----------------
__global__ __launch_bounds__(256) void k_z2(float* __restrict__ t, float* __restrict__ zcp,
    const float* __restrict__ abp, const float* __restrict__ wdc1,
    const float* __restrict__ bdc1, float* __restrict__ part){
  int blk = blockIdx.x, tid = threadIdx.x;
  int n0 = tid >> 4, qq = tid & 15;
  int n1 = n0 + 16;
  float al0 = abp[2*n0], be0 = abp[2*n0+1], al1 = abp[2*n1], be1 = abp[2*n1+1];
  float w00 = wdc1[n0*3], w01 = wdc1[n0*3+1], w02 = wdc1[n0*3+2], bb0 = bdc1[n0];
  float w10 = wdc1[n1*3], w11 = wdc1[n1*3+1], w12 = wdc1[n1*3+2], bb1 = bdc1[n1];
  float s0 = 0.f, q0 = 0.f, s1 = 0.f, q1 = 0.f;
  #pragma unroll
  for (int rr = 0; rr < 4; rr++){
    int r = blk*4 + rr;
    float v0 = t[(size_t)r*512 + tid];
    float v1 = t[(size_t)r*512 + tid + 256];
    float z0  = gelu_f(al0*v0 + be0);
    float z1v = gelu_f(al1*v1 + be1);
    float l0 = __shfl_up(z0, 1, 16);    if (qq == 0)  l0 = 0.f;
    float r0 = __shfl_down(z0, 1, 16);  if (qq == 15) r0 = 0.f;
    float l1 = __shfl_up(z1v, 1, 16);   if (qq == 0)  l1 = 0.f;
    float r1 = __shfl_down(z1v, 1, 16); if (qq == 15) r1 = 0.f;
    float cv0 = w00*l0 + w01*z0  + w02*r0 + bb0;
    float cv1 = w10*l1 + w11*z1v + w12*r1 + bb1;
    zcp[(size_t)r*512 + tid] = cv0;       t[(size_t)r*512 + tid] = z0;
    zcp[(size_t)r*512 + tid + 256] = cv1; t[(size_t)r*512 + tid + 256] = z1v;
    s0 += cv0; q0 += cv0*cv0; s1 += cv1; q1 += cv1*cv1;
  }
  #pragma unroll
  for (int off = 1; off < 16; off <<= 1){
    s0 += __shfl_xor(s0, off); q0 += __shfl_xor(q0, off);
    s1 += __shfl_xor(s1, off); q1 += __shfl_xor(q1, off);
  }
  if (qq == 0){
    part[(2*n0)*1344 + blk] = s0; part[(2*n0+1)*1344 + blk] = q0;
    part[(2*n1)*1344 + blk] = s1; part[(2*n1+1)*1344 + blk] = q1;
  }
}

// ---------------- z2f = gelu(bn(zcp)) + z2  (in-place over zcp) ----------------
__global__ __launch_bounds__(256) void k_z2f(float* __restrict__ zcp, const float* __restrict__ z2,
    const float* __restrict__ ab){
  int idx = blockIdx.x*256 + threadIdx.x;
  int n = (idx >> 4) & 31;
  zcp[idx] = gelu_f(ab[2*n]*zcp[idx] + ab[2*n+1]) + z2[idx];
}

// ---------------- attention scalar per row: att[r] = sum_m z1*z2f*dvec ----------------
__global__ __launch_bounds__(256) void k_att(const float* __restrict__ z1, const float* __restrict__ z2f,
    const float* __restrict__ dvec, float* __restrict__ att){
  int tid = threadIdx.x;
  int r = blockIdx.x*4 + (tid >> 6);
  int lane = tid & 63;
  const float* p1 = z1  + (size_t)r*512;
  const float* p2 = z2f + (size_t)r*512;
  float s = 0.f;
  #pragma unroll
  for (int w = 0; w < 8; w++){
    int m = lane + w*64;
    s += p1[m] * p2[m] * dvec[m];
  }
  for (int off = 32; off; off >>= 1) s += __shfl_down(s, off);
  if (lane == 0) att[r] = s;
}

// ---------------- att reduce + BN + gelu + softmax over d (single block) ----------------
__global__ __launch_bounds__(256) void k_attfin(const float* __restrict__ att, const float* __restrict__ S,
                                                float* __restrict__ att1){
  __shared__ float ws[4][2];
  int tid = threadIdx.x;
  float s = 0.f, s2 = 0.f;
  for (int i = tid; i < NROW; i += 256){ float a = att[i]; s += a; s2 += a*a; }
  for (int off = 32; off; off >>= 1){ s += __shfl_down(s, off); s2 += __shfl_down(s2, off); }
  if ((tid & 63) == 0){ ws[tid>>6][0] = s; ws[tid>>6][1] = s2; }
  __syncthreads();
  float S1 = ws[0][0]+ws[1][0]+ws[2][0]+ws[3][0];
  float S2 = ws[0][1]+ws[1][1]+ws[2][1]+ws[3][1];
  float mean = S1 / 5376.0f;
  float var  = S2 / 5376.0f - mean*mean;
  float al = S[S_AG] * rsqrtf(var + 1e-5f);
  float bb = S[S_AB2];
  float cw = S[S_ACW], cb2 = S[S_ACB];
  int b = tid;
  float v[DV]; float mx = -1e30f;
  for (int d = 0; d < DV; d++){
    float a = att[b*DV + d];
    a = gelu_f(al*(a - mean) + bb);
    a = a*cw + cb2;
    v[d] = a; mx = fmaxf(mx, a);
  }
  float ss = 0.f;
  for (int d = 0; d < DV; d++){ v[d] = expf(v[d] - mx); ss += v[d]; }
  float inv = 1.0f / ss;
  for (int d = 0; d < DV; d++) att1[b*DV + d] = v[d] * inv;
}

// ---------------- build BcatT (256x512): rows 0..95 Wm1^T, 128..223 M^T, rest 0 ----------------
__global__ __launch_bounds__(256) void k_bcat(const float* __restrict__ Wm1, const float* __restrict__ M,
                                              float* __restrict__ BcatT){
  int i = blockIdx.x*256 + threadIdx.x;   // 131072
  int c = i >> 9, m = i & 511;
  float v = 0.f;
  if (c < 96) v = Wm1[m*96 + c];
  else if (c >= 128 && c < 224) v = M[m*96 + (c - 128)];
  BcatT[i] = v;
}

// ---------------- out = Zres + c + gelu(H + bm1) @ Wm2 + bm2, 16 rows/block ----------------
__global__ __launch_bounds__(256) void k_out(const float* __restrict__ Hcat, const float* __restrict__ c,
    const float* __restrict__ S, void* __restrict__ outv, const int* __restrict__ flag){
  const float* bm1 = S + S_BM1;
  const float* Wm2 = S + S_WM2;
  const float* bm2 = S + S_BM2;
  __shared__ float W2s[96*96];
  __shared__ float Hs[16][100];
  int blk = blockIdx.x, tid = threadIdx.x;
  int r0 = blk*16;
  for (int i = tid; i < 96*96; i += 256) W2s[i] = Wm2[i];
  for (int i = tid; i < 16*96; i += 256){
    int rr = i / 96, col = i - rr*96;
    Hs[rr][col] = gelu_f(Hcat[(size_t)(r0+rr)*256 + col] + bm1[col]);
  }
  __syncthreads();
  int rr = tid >> 4, c0 = (tid & 15)*6;
  float acc[6] = {};
  for (int k = 0; k < 96; k++){
    float h = Hs[rr][k];
    #pragma unroll
    for (int j = 0; j < 6; j++) acc[j] += h * W2s[k*96 + c0 + j];
  }
  int r = r0 + rr;
  int b = r / DV, d = r - b*DV;
  int mode = *flag;
  #pragma unroll
  for (int j = 0; j < 6; j++){
    int p = c0 + j;
    float val = Hcat[(size_t)r*256 + 128 + p] + c[p] + acc[j] + bm2[p];
    size_t oi = ((size_t)b*96 + p)*DV + d;
    if (mode) ((float*)outv)[oi] = val;
    else ((__hip_bfloat16*)outv)[oi] = __float2bfloat16(val);
  }
}

extern "C" void kernel_launch(void* const* d_in, const int* in_sizes, int n_in,
                              void* d_out, int out_size, void* d_ws, size_t ws_size,
                              hipStream_t stream) {
  float* w = (float*)d_ws;
  float* xt   = w + OFF_XT;
  float* zA   = w + OFF_ZA;
  float* z1   = w + OFF_Z1;
  float* zcp  = w + OFF_ZCP;
  float* D2   = w + OFF_D2;
  float* D3   = w + OFF_D3;
  float* Mb   = w + OFF_M;
  float* Tn   = w + OFF_TN;
  float* tb   = w + OFF_TB;
  float* cb   = w + OFF_C;
  float* en   = w + OFF_EN;
  float* nrm  = w + OFF_NORM;
  float* att  = w + OFF_ATT;
  float* att1 = w + OFF_ATT1;
  float* dvec = w + OFF_ATT1;     // alias: dvec dead before att1 is written
  float* stat = w + OFF_STAT;
  float* abd  = w + OFF_ABD;
  float* abp  = w + OFF_ABP;
  float* abdep= w + OFF_ABDEP;
  int*   flag = (int*)(w + OFF_FLAG);
  float* S    = w + OFF_STG;
  float* Hcat = zA;               // 5376x256, alias (zA dead after z2f)
  float* BcatT= zA + 1500000;     // 256x512, alias
  float* partA = D2;              // scratch partials: dct stats (42x256) then patch stats (64x1344)
  float* partB = D3;              // depth stats partials (64x1344); D3 dead after gemm<1>

  Ptrs ptrs;
  for (int i = 0; i < 30; i++) ptrs.p[i] = d_in[i];

  k_init<<<193, 256, 0, stream>>>((const unsigned*)d_in[13], stat, cb, Mb, flag);
  k_stage<<<3338, 256, 0, stream>>>(ptrs, S, flag);
  k_transpose<<<1024, 256, 0, stream>>>(d_in[0], xt, flag);
  k_dctmats<<<1024, 256, 0, stream>>>(D2, D3);
  k_dvec<<<2, 256, 0, stream>>>(S, dvec);
  k_foldM<<<dim3(192, 8), 256, 0, stream>>>(S, Mb);
  k_foldC<<<128, 256, 0, stream>>>(S, cb);
  k_foldTn<<<32, 256, 0, stream>>>(S, Tn, tb);

  k_gemm<0><<<dim3(8,84), 256, 0, stream>>>(xt, nullptr, D2, zA, nullptr, nullptr, nullptr, nullptr, 512);
  k_energy<<<NROW/4, 256, 0, stream>>>(zA, en);
  k_med<<<1, 256, 0, stream>>>(en, nrm);
  k_rank<<<336, 256, 0, stream>>>(nrm, S+S_THR, stat);
  k_maskgelu<<<NROW, 256, 0, stream>>>(zA, nrm, stat, S+S_THR, S+S_WDCT, S+S_BDCT, partA);
  k_bnfin2<<<DV, 256, 0, stream>>>(partA, 256, S+S_GD, S+S_BDN, 131072.0f, abd);
  k_gemm<1><<<dim3(8,84), 256, 0, stream>>>(zA, nullptr, D3, z1, abd, xt, S+S_WDCT, S+S_BDCT, 512);

  k_patch<<<NROW/4, 256, 0, stream>>>(xt, Tn, tb, zA, partA);
  k_bnfin2<<<NP, 256, 0, stream>>>(partA, 1344, S+S_GP, S+S_BP, 86016.0f, abp);
  k_z2<<<NROW/4, 256, 0, stream>>>(zA, zcp, abp, S+S_WDC1, S+S_BDC1, partB);
  k_bnfin2<<<NP, 256, 0, stream>>>(partB, 1344, S+S_GDEP, S+S_BDEP, 86016.0f, abdep);
  k_z2f<<<NROW*2, 256, 0, stream>>>(zcp, zA, abdep);

  k_att<<<NROW/4, 256, 0, stream>>>(z1, zcp, dvec, att);
  k_attfin<<<1, 256, 0, stream>>>(att, S, att1);

  k_bcat<<<512, 256, 0, stream>>>(S+S_WM1, Mb, BcatT);
  k_gemm<3><<<dim3(4,84), 256, 0, stream>>>(z1, zcp, BcatT, Hcat, att1, xt, nullptr, nullptr, 256);
  k_out<<<NROW/16, 256, 0, stream>>>(Hcat, cb, S, d_out, flag);
}

// Round 8
// 348.717 us; speedup vs baseline: 1.6722x; 1.1347x over previous
//
#include <hip/hip_runtime.h>
#include <hip/hip_bf16.h>

#define B_    256
#define L_    512
#define DV    21
#define NROW  5376       // B_*DV
#define NP    32
#define PP    16
#define PRED_ 96

// ---------------- workspace layout (float indices) ----------------
static const size_t OFF_XT    = 0;          // 5376x512 f32
static const size_t OFF_ZA    = 2752512;    // z_dct -> z -> t -> z2 -> Hcat/BcatTh (aliased over time)
static const size_t OFF_Z1    = 5505024;
static const size_t OFF_ZCP   = 8257536;    // zc_pre -> z2f (in-place)
static const size_t OFF_D2    = 11010048;   // 512x512 f32 ; dead after k_gemm<0> -> stat partials (partA)
static const size_t OFF_D3    = 11272192;   // D3h bf16 (512x512 shorts); dead after gemm_mf<1> -> partB
static const size_t OFF_M     = 11534336;   // 512x96 folded linres
static const size_t OFF_TN    = 11583488;   // 32x16x16
static const size_t OFF_TB    = 11591680;   // 32x16
static const size_t OFF_C     = 11592192;   // 96 (pad 128)
static const size_t OFF_EN    = 11592320;   // 5376
static const size_t OFF_NORM  = 11597696;
static const size_t OFF_ATT   = 11603072;
static const size_t OFF_ATT1  = 11608448;   // aliases dvec (512) before k_attfin writes att1
static const size_t OFF_STAT  = 11613824;   // [200],[201]=quantile order stats
static const size_t OFF_ABD   = 11614080;
static const size_t OFF_ABP   = 11614144;
static const size_t OFF_ABDEP = 11614208;
static const size_t OFF_FLAG  = 11614272;   // int mode flag (1=f32 inputs, 0=bf16)
static const size_t OFF_STG   = 11614336;   // staged f32 weights (854480)
// aliases inside OFF_ZA region (live only after z2f):
//   Hcat   = OFF_ZA                 (5376 x 256 f32)
//   BcatTh = OFF_ZA + 1500000       (256 x 512 bf16)

// staged-weight offsets (relative to OFF_STG)
static const int S_WDCT=0, S_BDCT=24, S_WE=48, S_BE=4144, S_WL=4400, S_BL=790832,
  S_WD=790928, S_BDRES=795024, S_WDC=795040, S_BDC=795552, S_WDC1=795584, S_BDC1=795680,
  S_GD=795712, S_BDN=795736, S_GP=795760, S_BP=795792, S_GDEP=795824, S_BDEP=795856,
  S_THR=795888, S_WM1=795892, S_BM1=845044, S_WM2=845140, S_BM2=854356,
  S_ADWW=854452, S_ADWB=854460, S_ACW=854464, S_ACB=854468, S_AG=854472, S_AB2=854476;

struct Ptrs { const void* p[30]; };

typedef __attribute__((ext_vector_type(8))) short bf16x8;
typedef __attribute__((ext_vector_type(4))) float f32x4;

__device__ __forceinline__ float bf2f(unsigned short h){
  unsigned u = ((unsigned)h) << 16;
  return __uint_as_float(u);
}
__device__ __forceinline__ short f2b(float f){   // RNE f32 -> bf16
  unsigned u = __float_as_uint(f);
  u = (u + 0x7FFFu + ((u >> 16) & 1u)) >> 16;
  return (short)u;
}
__device__ __forceinline__ float gelu_f(float x){ return 0.5f*x*(1.0f+erff(x*0.70710678118654752440f)); }

// ---------------- init: zero stats/c/M + detect input dtype ----------------
__global__ void k_init(const unsigned* __restrict__ gones, float* __restrict__ stat,
                       float* __restrict__ c, float* __restrict__ M, int* __restrict__ flag){
  if (blockIdx.x == 0){
    stat[threadIdx.x] = 0.0f;
    if (threadIdx.x < 128) c[threadIdx.x] = 0.0f;
    if (threadIdx.x == 0) *flag = (gones[0] == 0x3F800000u) ? 1 : 0;
  } else {
    M[(blockIdx.x-1)*256 + threadIdx.x] = 0.0f;
  }
}

// ---------------- stage all weights (inputs 1..29) to f32 ----------------
__global__ __launch_bounds__(256) void k_stage(Ptrs ptrs, float* __restrict__ dst, const int* __restrict__ flag){
  const int cnt[29] = {21,21,4096,256,786432,96,4096,16,512,32,96,32,21,21,32,32,32,32,1,49152,96,9216,96,5,1,1,1,1,1};
  const int off[29] = {S_WDCT,S_BDCT,S_WE,S_BE,S_WL,S_BL,S_WD,S_BDRES,S_WDC,S_BDC,S_WDC1,S_BDC1,
                       S_GD,S_BDN,S_GP,S_BP,S_GDEP,S_BDEP,S_THR,S_WM1,S_BM1,S_WM2,S_BM2,
                       S_ADWW,S_ADWB,S_ACW,S_ACB,S_AG,S_AB2};
  int mode = *flag;
  int gid = blockIdx.x*256 + threadIdx.x;
  int a = -1, loc = 0, base = 0;
  #pragma unroll
  for (int i = 0; i < 29; i++){
    if (a < 0 && gid < base + cnt[i]){ a = i; loc = gid - base; }
    base += cnt[i];
  }
  if (a < 0) return;
  const void* s = ptrs.p[a+1];
  float v = mode ? ((const float*)s)[loc] : bf2f(((const unsigned short*)s)[loc]);
  dst[off[a] + loc] = v;
}

// ---------------- transpose x (B,L,D) -> xt (B*D, L), 4 chunks per batch ----------------
__global__ __launch_bounds__(256) void k_transpose(const void* __restrict__ x, float* __restrict__ xt,
                                                   const int* __restrict__ flag){
  __shared__ float xs[128*DV];
  int mode = *flag;
  int b = blockIdx.x >> 2, ch = blockIdx.x & 3;
  int l0 = ch*128;
  size_t base = (size_t)b*(L_*DV) + (size_t)l0*DV;
  if (mode){
    const float* xp = (const float*)x + base;
    for (int i = threadIdx.x; i < 128*DV; i += 256) xs[i] = xp[i];
  } else {
    const unsigned short* xp = (const unsigned short*)x + base;
    for (int i = threadIdx.x; i < 128*DV; i += 256) xs[i] = bf2f(xp[i]);
  }
  __syncthreads();
  for (int i = threadIdx.x; i < 128*DV; i += 256){
    int d = i >> 7, l = i & 127;
    xt[((size_t)b*DV + d)*512 + l0 + l] = xs[l*DV + d];
  }
}

// ---------------- DCT matrices: D2 f32, D3h bf16 ----------------
__global__ __launch_bounds__(256) void k_dctmats(float* __restrict__ D2, unsigned short* __restrict__ D3h){
  int i = blockIdx.x*256 + threadIdx.x;
  int kk = i >> 9, m = i & 511;
  const float PIo = 3.14159265358979323846f / 1024.0f;
  int a = ((2*m+1)*kk) & 2047;
  D2[i] = 2.0f * cosf(PIo * (float)a);
  int l = kk, k = m;
  int a2 = ((2*l+1)*k) & 2047;
  float w0 = (k==0) ? 0.5f : 1.0f;
  D3h[i] = (unsigned short)f2b(cosf(PIo * (float)a2) * w0 * (1.0f/512.0f));
}

// ---------------- dvec[m] = sum_k 2cos(pi(2m+1)k/1024) * s_ortho[k] * a_dw_w[k] ----------------
__global__ void k_dvec(const float* __restrict__ S, float* __restrict__ dvec){
  int m = blockIdx.x*256 + threadIdx.x;
  const float PIo = 3.14159265358979323846f / 1024.0f;
  const float rs = 22.627416997969522f;
  float s = 0.f;
  #pragma unroll
  for (int k = 0; k < 5; k++){
    float sk = ((k == 0) ? 0.5f : 0.70710678118654752440f) / rs;
    int a = ((2*m+1)*k) & 2047;
    s += 2.0f * cosf(PIo * (float)a) * sk * S[S_ADWW + k];
  }
  dvec[m] = s;
}

// ---------------- fold M = We@Wl blocks: K-split, atomic partials ----------------
__global__ __launch_bounds__(256) void k_foldM(const float* __restrict__ S, float* __restrict__ M){
  const float* We = S + S_WE;  const float* Wl = S + S_WL;
  int gid = blockIdx.x*256 + threadIdx.x;
  int l = gid/96, p = gid - l*96;
  int n = l>>4, q = l&15;
  int j0 = blockIdx.y*32;
  float acc = 0.f;
  #pragma unroll 8
  for (int j = j0; j < j0+32; j++) acc += We[q*256+j] * Wl[(size_t)(n*256+j)*96 + p];
  atomicAdd(&M[gid], acc);
}

// ---------------- fold c[p] ----------------
__global__ __launch_bounds__(256) void k_foldC(const float* __restrict__ S, float* __restrict__ c){
  const float* be = S + S_BE;  const float* Wl = S + S_WL;  const float* bl = S + S_BL;
  int t = threadIdx.x;
  int rp = t >> 7, p = t & 127;
  if (p >= 96) return;
  float acc = 0.f;
  int J0 = blockIdx.x*64;
  for (int j = 0; j < 64; j += 2){
    int J = J0 + j + rp;
    acc += be[J & 255] * Wl[(size_t)J*96 + p];
  }
  if (blockIdx.x == 0 && rp == 0) acc += bl[p];
  atomicAdd(&c[p], acc);
}

// ---------------- fold Tn/tb ----------------
__global__ __launch_bounds__(256) void k_foldTn(const float* __restrict__ S,
    float* __restrict__ Tn, float* __restrict__ tb){
  __shared__ float WeS[4096];
  __shared__ float WdS[4096];
  __shared__ float wdcS[16];
  __shared__ float beS[256];
  __shared__ float bdresS[16];
  int n = blockIdx.x, tid = threadIdx.x;
  for (int i = tid; i < 4096; i += 256){ WeS[i] = S[S_WE+i]; WdS[i] = S[S_WD+i]; }
  beS[tid & 255] = S[S_BE + (tid & 255)];
  if (tid < 16){ wdcS[tid] = S[S_WDC + n*16 + tid]; bdresS[tid] = S[S_BDRES + tid]; }
  __syncthreads();
  int q2 = tid>>4, q = tid&15;
  float R = 0.f;
  for (int j = 0; j < 256; j++) R += WeS[q2*256+j] * WdS[j*16+q];
  float G = 0.f;
  #pragma unroll
  for (int p = 0; p < 16; p++) G += WeS[q2*256 + q*16 + p] * wdcS[p];
  Tn[n*256 + q2*16 + q] = R + G;
  if (tid < 16){
    float rb = bdresS[tid];
    for (int j = 0; j < 256; j++) rb += beS[j] * WdS[j*16+tid];
    float gb = S[S_BDC + n];
    #pragma unroll
    for (int p = 0; p < 16; p++) gb += beS[tid*16+p] * wdcS[p];
    tb[n*16+tid] = rb + gb;
  }
}

// ---------------- f32 GEMM (DCT only; accuracy-critical mask path) ----------------
__global__ __launch_bounds__(256) void k_gemm0(
    const float* __restrict__ A, const float* __restrict__ Bm, float* __restrict__ C){
  __shared__ float As[16][68];
  __shared__ float Bs[16][68];
  int tid = threadIdx.x;
  int tx = tid & 15, ty = tid >> 4;
  int rowBase = blockIdx.y * 64;
  int colBase = blockIdx.x * 64;
  int lr = tid >> 2;
  int lk = (tid & 3) << 2;
  float acc[4][4] = {};
  for (int k0 = 0; k0 < 512; k0 += 16){
    float4 av = *(const float4*)(A + (size_t)(rowBase+lr)*512 + k0 + lk);
    As[lk+0][lr] = av.x; As[lk+1][lr] = av.y; As[lk+2][lr] = av.z; As[lk+3][lr] = av.w;
    float4 bv = *(const float4*)(Bm + (size_t)(colBase+lr)*512 + k0 + lk);
    Bs[lk+0][lr] = bv.x; Bs[lk+1][lr] = bv.y; Bs[lk+2][lr] = bv.z; Bs[lk+3][lr] = bv.w;
    __syncthreads();
    #pragma unroll
    for (int kk = 0; kk < 16; kk++){
      float4 a4 = *(const float4*)&As[kk][ty*4];
      float4 b4 = *(const float4*)&Bs[kk][tx*4];
      acc[0][0] += a4.x*b4.x; acc[0][1] += a4.x*b4.y; acc[0][2] += a4.x*b4.z; acc[0][3] += a4.x*b4.w;
      acc[1][0] += a4.y*b4.x; acc[1][1] += a4.y*b4.y; acc[1][2] += a4.y*b4.z; acc[1][3] += a4.y*b4.w;
      acc[2][0] += a4.z*b4.x; acc[2][1] += a4.z*b4.y; acc[2][2] += a4.z*b4.z; acc[2][3] += a4.z*b4.w;
      acc[3][0] += a4.w*b4.x; acc[3][1] += a4.w*b4.y; acc[3][2] += a4.w*b4.z; acc[3][3] += a4.w*b4.w;
    }
    __syncthreads();
  }
  #pragma unroll
  for (int i = 0; i < 4; i++){
    int r = rowBase + ty*4 + i;
    #pragma unroll
    for (int j = 0; j < 4; j++){
      int cc = colBase + tx*4 + j;
      C[(size_t)r*512 + cc] = acc[i][j];
    }
  }
}

// ---------------- MFMA bf16 GEMM: C[r][cc] = sum_k A'[r][k]*Bg[cc][k] ----------------
// MODE 1: A' = alpha_d*A+beta_d (bf16), epilogue += xt*wdct+bdct.
// MODE 3: blockIdx.x<2 -> A' = att*A + (1-att)*A2 ; else A' = xt.
// Tile 64x64, 4 waves, K-step 32, mfma_f32_16x16x32_bf16.
template<int MODE>
__global__ __launch_bounds__(256) void k_gemm_mf(
    const float* __restrict__ A, const float* __restrict__ A2,
    const unsigned short* __restrict__ Bg,
    float* __restrict__ C, const float* __restrict__ ab, const float* __restrict__ xt,
    const float* __restrict__ wdct, const float* __restrict__ bdct, int Cstride){
  __shared__ short Ah[64*40];   // row-major [row][k], stride 40 shorts (pad 8)
  __shared__ short Bh[64*40];   // [col][k]
  int tid = threadIdx.x;
  int rowBase = blockIdx.y*64, colBase = blockIdx.x*64;
  int srow = tid>>2, seg = tid&3;            // staging: 64 rows x 4 k-segments of 8
  int r = rowBase + srow;
  float alpha = 1.f, beta = 0.f;
  bool useXt = false;
  if (MODE == 1){ int d = r % DV; alpha = ab[2*d]; beta = ab[2*d+1]; }
  if (MODE == 3){ if (blockIdx.x < 2) alpha = ab[r]; else useXt = true; }
  int wave = tid>>6, lane = tid&63;
  int m = lane&15, quad = lane>>4;
  f32x4 acc[4] = {};
  const float* Ap = (MODE == 3 && useXt) ? xt : A;
  for (int k0 = 0; k0 < 512; k0 += 32){
    float4 a0 = *(const float4*)(Ap + (size_t)r*512 + k0 + seg*8);
    float4 a1 = *(const float4*)(Ap + (size_t)r*512 + k0 + seg*8 + 4);
    if (MODE == 1){
      a0.x = alpha*a0.x+beta; a0.y = alpha*a0.y+beta; a0.z = alpha*a0.z+beta; a0.w = alpha*a0.w+beta;
      a1.x = alpha*a1.x+beta; a1.y = alpha*a1.y+beta; a1.z = alpha*a1.z+beta; a1.w = alpha*a1.w+beta;
    }
    if (MODE == 3 && !useXt){
      float4 c0 = *(const float4*)(A2 + (size_t)r*512 + k0 + seg*8);
      float4 c1 = *(const float4*)(A2 + (size_t)r*512 + k0 + seg*8 + 4);
      float om = 1.0f - alpha;
      a0.x = alpha*a0.x + om*c0.x; a0.y = alpha*a0.y + om*c0.y;
      a0.z = alpha*a0.z + om*c0.z; a0.w = alpha*a0.w + om*c0.w;
      a1.x = alpha*a1.x + om*c1.x; a1.y = alpha*a1.y + om*c1.y;
      a1.z = alpha*a1.z + om*c1.z; a1.w = alpha*a1.w + om*c1.w;
    }
    bf16x8 av;
    av[0]=f2b(a0.x); av[1]=f2b(a0.y); av[2]=f2b(a0.z); av[3]=f2b(a0.w);
    av[4]=f2b(a1.x); av[5]=f2b(a1.y); av[6]=f2b(a1.z); av[7]=f2b(a1.w);
    *(bf16x8*)(Ah + srow*40 + seg*8) = av;
    bf16x8 bv = *(const bf16x8*)(Bg + (size_t)(colBase+srow)*512 + k0 + seg*8);
    *(bf16x8*)(Bh + srow*40 + seg*8) = bv;
    __syncthreads();
    bf16x8 af = *(bf16x8*)(Ah + (wave*16 + m)*40 + quad*8);
    #pragma unroll
    for (int t = 0; t < 4; t++){
      bf16x8 bf = *(bf16x8*)(Bh + (t*16 + m)*40 + quad*8);
      acc[t] = __builtin_amdgcn_mfma_f32_16x16x32_bf16(af, bf, acc[t], 0, 0, 0);
    }
    __syncthreads();
  }
  #pragma unroll
  for (int t = 0; t < 4; t++){
    #pragma unroll
    for (int i = 0; i < 4; i++){
      int rr = rowBase + wave*16 + quad*4 + i;
      int cc = colBase + t*16 + m;
      float v = acc[t][i];
      if (MODE == 1){
        int d = rr % DV;
        v += xt[(size_t)rr*512 + cc]*wdct[d] + bdct[d];
      }
      C[(size_t)rr*Cstride + cc] = v;
    }
  }
}

// ---------------- energy per row ----------------
__global__ __launch_bounds__(256) void k_energy(const float* __restrict__ z, float* __restrict__ e){
  int tid = threadIdx.x;
  int r = blockIdx.x*4 + (tid>>6);
  int lane = tid & 63;
  const float* p = z + (size_t)r*512;
  float s = 0.f;
  #pragma unroll
  for (int w = 0; w < 8; w++){ float v = p[lane + w*64]; s += v*v; }
  for (int off = 32; off; off >>= 1) s += __shfl_down(s, off);
  if (lane == 0) e[r] = s;
}

// ---------------- median per batch row + norm_e ----------------
__global__ __launch_bounds__(256) void k_med(const float* __restrict__ e, float* __restrict__ norm){
  int b = threadIdx.x;
  float v[DV];
  for (int d = 0; d < DV; d++) v[d] = e[b*DV + d];
  float med = 0.f;
  for (int i = 0; i < DV; i++){
    int rk = 0;
    for (int j = 0; j < DV; j++) rk += (v[j] < v[i]) || (v[j] == v[i] && j < i);
    if (rk == 10) med = v[i];
  }
  float den = med + 1e-6f;
  for (int d = 0; d < DV; d++) norm[b*DV + d] = v[d] / den;
}

// ---------------- distributed rank-count quantile ----------------
__global__ __launch_bounds__(256) void k_rank(const float* __restrict__ norm,
    const float* __restrict__ thrv, float* __restrict__ stat){
  int tid = threadIdx.x;
  int cand = tid >> 4, part = tid & 15;
  int idx = blockIdx.x*16 + cand;
  float val = norm[idx];
  int cnt = 0;
  int j0 = part*336;
  for (int j = j0; j < j0 + 336; ++j){
    float v = norm[j];
    cnt += (v < val) || (v == val && j < idx);
  }
  __shared__ int sc[16][17];
  sc[cand][part] = cnt;
  __syncthreads();
  if (part == 0){
    int rank = 0;
    #pragma unroll
    for (int i = 0; i < 16; i++) rank += sc[cand][i];
    float q = thrv[0];
    float pos = q * 5375.0f;
    int i0 = (int)floorf(pos);
    int i1 = (i0 + 1 > 5375) ? 5375 : i0 + 1;
    if (rank == i0) stat[200] = val;
    if (rank == i1) stat[201] = val;
  }
}

// ---------------- mask + scale + gelu + BN partials ----------------
__global__ __launch_bounds__(256) void k_maskgelu(float* __restrict__ zA, const float* __restrict__ norm,
    const float* __restrict__ stat, const float* __restrict__ thrv,
    const float* __restrict__ wdct, const float* __restrict__ bdct,
    float* __restrict__ part){
  int r = blockIdx.x, tid = threadIdx.x;
  int d = r % DV, brow = r / DV;
  float q = thrv[0];
  float pos = q * 5375.0f; float f = pos - floorf(pos);
  float thr = stat[200] + (stat[201] - stat[200]) * f;
  float mask = norm[r] > thr ? 1.0f : 0.0f;
  float w = wdct[d], b = bdct[d];
  float s = 0.f, s2 = 0.f;
  for (int i = tid; i < 512; i += 256){
    float v = zA[(size_t)r*512 + i] * mask * w + b;
    float g = gelu_f(v);
    zA[(size_t)r*512 + i] = g;
    s += g; s2 += g*g;
  }
  for (int off = 32; off; off >>= 1){ s += __shfl_down(s, off); s2 += __shfl_down(s2, off); }
  __shared__ float wsum[4][2];
  int wv = tid >> 6;
  if ((tid & 63) == 0){ wsum[wv][0] = s; wsum[wv][1] = s2; }
  __syncthreads();
  if (tid == 0){
    float S  = wsum[0][0]+wsum[1][0]+wsum[2][0]+wsum[3][0];
    float S2 = wsum[0][1]+wsum[1][1]+wsum[2][1]+wsum[3][1];
    part[(2*d)*256 + brow] = S;
    part[(2*d+1)*256 + brow] = S2;
  }
}

// ---------------- BN finalize from partials ----------------
__global__ __launch_bounds__(256) void k_bnfin2(const float* __restrict__ part, int P,
    const float* __restrict__ g, const float* __restrict__ b, float count, float* __restrict__ ab){
  int c = blockIdx.x, tid = threadIdx.x;
  const float* ps = part + (size_t)(2*c)*P;
  const float* pq = part + (size_t)(2*c+1)*P;
  float s = 0.f, s2 = 0.f;
  for (int i = tid; i < P; i += 256){ s += ps[i]; s2 += pq[i]; }
  for (int off = 32; off; off >>= 1){ s += __shfl_down(s, off); s2 += __shfl_down(s2, off); }
  __shared__ float ws[4][2];
  if ((tid & 63) == 0){ ws[tid>>6][0] = s; ws[tid>>6][1] = s2; }
  __syncthreads();
  if (tid == 0){
    float S1 = ws[0][0]+ws[1][0]+ws[2][0]+ws[3][0];
    float S2 = ws[0][1]+ws[1][1]+ws[2][1]+ws[3][1];
    float mean = S1 / count;
    float var  = S2 / count - mean*mean;
    float al = g[c] * rsqrtf(var + 1e-5f);
    float be = b[c] - mean * al;
    ab[2*c] = al; ab[2*c+1] = be;
  }
}

// ---------------- patch branch: 4 rows/block, shuffle matvec, partial stats ----------------
__global__ __launch_bounds__(256) void k_patch(const float* __restrict__ xt, const float* __restrict__ Tn,
    const float* __restrict__ tb, float* __restrict__ t, float* __restrict__ part){
  int blk = blockIdx.x, tid = threadIdx.x;
  int n0 = tid >> 4, qq = tid & 15;
  int n1 = n0 + 16;
  float T0[16], T1[16];
  #pragma unroll
  for (int q2 = 0; q2 < 16; q2++){
    T0[q2] = Tn[n0*256 + q2*16 + qq];
    T1[q2] = Tn[n1*256 + q2*16 + qq];
  }
  float tb0 = tb[n0*16 + qq], tb1 = tb[n1*16 + qq];
  float s0 = 0.f, q0 = 0.f, s1 = 0.f, q1 = 0.f;
  #pragma unroll
  for (int rr = 0; rr < 4; rr++){
    int r = blk*4 + rr;
    float x0 = xt[(size_t)r*512 + tid];
    float x1 = xt[(size_t)r*512 + tid + 256];
    float a0 = tb0, a1 = tb1;
    #pragma unroll
    for (int q2 = 0; q2 < 16; q2++){
      a0 += __shfl(x0, q2, 16) * T0[q2];
      a1 += __shfl(x1, q2, 16) * T1[q2];
    }
    t[(size_t)r*512 + tid] = a0;       s0 += a0; q0 += a0*a0;
    t[(size_t)r*512 + tid + 256] = a1; s1 += a1; q1 += a1*a1;
  }
  #pragma unroll
  for (int off = 1; off < 16; off <<= 1){
    s0 += __shfl_xor(s0, off); q0 += __shfl_xor(q0, off);
    s1 += __shfl_xor(s1, off); q1 += __shfl_xor(q1, off);
  }
  if (qq == 0){
    part[(2*n0)*1344 + blk] = s0; part[(2*n0+1)*1344 + blk] = q0;
    part[(2*n1)*1344 + blk] = s1; part[(2*n1+1)*1344 + blk] = q1;
  }
}

// ---------------- z2 = gelu(bn(t)); zc_pre = conv3(z2); 4 rows/block ----------------
__global__ __launch_bounds__(256) void k_z2(float* __restrict__ t, float* __restrict__ zcp,
    const float* __restrict__ abp, const float* __restrict__ wdc1,
    const float* __restrict__ bdc1, float* __restrict__ part){
  int blk = blockIdx.x, tid = threadIdx.x;
  int n0 = tid >> 4, qq = tid & 15;
  int n1 = n0 + 16;
  float al0 = abp[2*n0], be0 = abp[2*n0+1], al1 = abp[2*n1], be1 = abp[2*n1+1];
  float w00 = wdc1[n0*3], w01 = wdc1[n0*3+1], w02 = wdc1[n0*3+2], bb0 = bdc1[n0];
  float w10 = wdc1[n1*3], w11 = wdc1[n1*3+1], w12 = wdc1[n1*3+2], bb1 = bdc1[n1];
  float s0 = 0.f, q0 = 0.f, s1 = 0.f, q1 = 0.f;
  #pragma unroll
  for (int rr = 0; rr < 4; rr++){
    int r = blk*4 + rr;
    float v0 = t[(size_t)r*512 + tid];
    float v1 = t[(size_t)r*512 + tid + 256];
    float z0  = gelu_f(al0*v0 + be0);
    float z1v = gelu_f(al1*v1 + be1);
    float l0 = __shfl_up(z0, 1, 16);    if (qq == 0)  l0 = 0.f;
    float r0 = __shfl_down(z0, 1, 16);  if (qq == 15) r0 = 0.f;
    float l1 = __shfl_up(z1v, 1, 16);   if (qq == 0)  l1 = 0.f;
    float r1 = __shfl_down(z1v, 1, 16); if (qq == 15) r1 = 0.f;
    float cv0 = w00*l0 + w01*z0  + w02*r0 + bb0;
    float cv1 = w10*l1 + w11*z1v + w12*r1 + bb1;
    zcp[(size_t)r*512 + tid] = cv0;       t[(size_t)r*512 + tid] = z0;
    zcp[(size_t)r*512 + tid + 256] = cv1; t[(size_t)r*512 + tid + 256] = z1v;
    s0 += cv0; q0 += cv0*cv0; s1 += cv1; q1 += cv1*cv1;
  }
  #pragma unroll
  for (int off = 1; off < 16; off <<= 1){
    s0 += __shfl_xor(s0, off); q0 += __shfl_xor(q0, off);
    s1 += __shfl_xor(s1, off); q1 += __shfl_xor(q1, off);
  }
  if (qq == 0){
    part[(2*n0)*1344 + blk] = s0; part[(2*n0+1)*1344 + blk] = q0;
    part[(2*n1)*1344 + blk] = s1; part[(2*n1+1)*1344 + blk] = q1;
  }
}

// ---------------- z2f (in-place over zcp) fused with att dot product ----------------
__global__ __launch_bounds__(256) void k_z2fatt(float* __restrict__ zcp, const float* __restrict__ z2,
    const float* __restrict__ ab, const float* __restrict__ z1,
    const float* __restrict__ dvec, float* __restrict__ att){
  int r = blockIdx.x, tid = threadIdx.x;
  size_t base = (size_t)r*512;
  float s = 0.f;
  #pragma unroll
  for (int h = 0; h < 2; h++){
    int idx = tid + h*256;
    int n = (idx >> 4) & 31;
    float v = gelu_f(ab[2*n]*zcp[base+idx] + ab[2*n+1]) + z2[base+idx];
    zcp[base+idx] = v;
    s += z1[base+idx] * v * dvec[idx];
  }
  for (int off = 32; off; off >>= 1) s += __shfl_down(s, off);
  __shared__ float ws[4];
  if ((tid & 63) == 0) ws[tid>>6] = s;
  __syncthreads();
  if (tid == 0) att[r] = ws[0]+ws[1]+ws[2]+ws[3];
}

// ---------------- att reduce + BN + gelu + softmax over d (single block) ----------------
__global__ __launch_bounds__(256) void k_attfin(const float* __restrict__ att, const float* __restrict__ S,
                                                float* __restrict__ att1){
  __shared__ float ws[4][2];
  int tid = threadIdx.x;
  float s = 0.f, s2 = 0.f;
  for (int i = tid; i < NROW; i += 256){ float a = att[i]; s += a; s2 += a*a; }
  for (int off = 32; off; off >>= 1){ s += __shfl_down(s, off); s2 += __shfl_down(s2, off); }
  if ((tid & 63) == 0){ ws[tid>>6][0] = s; ws[tid>>6][1] = s2; }
  __syncthreads();
  float S1 = ws[0][0]+ws[1][0]+ws[2][0]+ws[3][0];
  float S2 = ws[0][1]+ws[1][1]+ws[2][1]+ws[3][1];
  float mean = S1 / 5376.0f;
  float var  = S2 / 5376.0f - mean*mean;
  float al = S[S_AG] * rsqrtf(var + 1e-5f);
  float bb = S[S_AB2];
  float cw = S[S_ACW], cb2 = S[S_ACB];
  int b = tid;
  float v[DV]; float mx = -1e30f;
  for (int d = 0; d < DV; d++){
    float a = att[b*DV + d];
    a = gelu_f(al*(a - mean) + bb);
    a = a*cw + cb2;
    v[d] = a; mx = fmaxf(mx, a);
  }
  float ss = 0.f;
  for (int d = 0; d < DV; d++){ v[d] = expf(v[d] - mx); ss += v[d]; }
  float inv = 1.0f / ss;
  for (int d = 0; d < DV; d++) att1[b*DV + d] = v[d] * inv;
}

// ---------------- build BcatTh bf16 (256x512): rows 0..95 Wm1^T, 128..223 M^T, rest 0 ----------------
__global__ __launch_bounds__(256) void k_bcat(const float* __restrict__ Wm1, const float* __restrict__ M,
                                              unsigned short* __restrict__ Bt){
  int i = blockIdx.x*256 + threadIdx.x;   // 131072
  int c = i >> 9, m = i & 511;
  float v = 0.f;
  if (c < 96) v = Wm1[m*96 + c];
  else if (c >= 128 && c < 224) v = M[m*96 + (c - 128)];
  Bt[i] = (unsigned short)f2b(v);
}

// ---------------- out = Zres + c + gelu(H + bm1) @ Wm2 + bm2, 16 rows/block ----------------
__global__ __launch_bounds__(256) void k_out(const float* __restrict__ Hcat, const float* __restrict__ c,
    const float* __restrict__ S, void* __restrict__ outv, const int* __restrict__ flag){
  const float* bm1 = S + S_BM1;
  const float* Wm2 = S + S_WM2;
  const float* bm2 = S + S_BM2;
  __shared__ float W2s[96*96];
  __shared__ float Hs[16][100];
  int blk = blockIdx.x, tid = threadIdx.x;
  int r0 = blk*16;
  for (int i = tid; i < 96*96; i += 256) W2s[i] = Wm2[i];
  for (int i = tid; i < 16*96; i += 256){
    int rr = i / 96, col = i - rr*96;
    Hs[rr][col] = gelu_f(Hcat[(size_t)(r0+rr)*256 + col] + bm1[col]);
  }
  __syncthreads();
  int rr = tid >> 4, c0 = (tid & 15)*6;
  float acc[6] = {};
  for (int k = 0; k < 96; k++){
    float h = Hs[rr][k];
    #pragma unroll
    for (int j = 0; j < 6; j++) acc[j] += h * W2s[k*96 + c0 + j];
  }
  int r = r0 + rr;
  int b = r / DV, d = r - b*DV;
  int mode = *flag;
  #pragma unroll
  for (int j = 0; j < 6; j++){
    int p = c0 + j;
    float val = Hcat[(size_t)r*256 + 128 + p] + c[p] + acc[j] + bm2[p];
    size_t oi = ((size_t)b*96 + p)*DV + d;
    if (mode) ((float*)outv)[oi] = val;
    else ((__hip_bfloat16*)outv)[oi] = __float2bfloat16(val);
  }
}

extern "C" void kernel_launch(void* const* d_in, const int* in_sizes, int n_in,
                              void* d_out, int out_size, void* d_ws, size_t ws_size,
                              hipStream_t stream) {
  float* w = (float*)d_ws;
  float* xt   = w + OFF_XT;
  float* zA   = w + OFF_ZA;
  float* z1   = w + OFF_Z1;
  float* zcp  = w + OFF_ZCP;
  float* D2   = w + OFF_D2;
  unsigned short* D3h = (unsigned short*)(w + OFF_D3);
  float* Mb   = w + OFF_M;
  float* Tn   = w + OFF_TN;
  float* tb   = w + OFF_TB;
  float* cb   = w + OFF_C;
  float* en   = w + OFF_EN;
  float* nrm  = w + OFF_NORM;
  float* att  = w + OFF_ATT;
  float* att1 = w + OFF_ATT1;
  float* dvec = w + OFF_ATT1;     // alias: dvec dead before att1 is written
  float* stat = w + OFF_STAT;
  float* abd  = w + OFF_ABD;
  float* abp  = w + OFF_ABP;
  float* abdep= w + OFF_ABDEP;
  int*   flag = (int*)(w + OFF_FLAG);
  float* S    = w + OFF_STG;
  float* Hcat = zA;                                   // 5376x256 f32
  unsigned short* BcatTh = (unsigned short*)(zA + 1500000);  // 256x512 bf16
  float* partA = D2;              // partials: dct stats (42x256), patch stats (64x1344); D2 dead post-gemm0
  float* partB = w + OFF_D3;      // depth stats partials (64x1344); D3h dead post-gemm_mf<1>

  Ptrs ptrs;
  for (int i = 0; i < 30; i++) ptrs.p[i] = d_in[i];

  k_init<<<193, 256, 0, stream>>>((const unsigned*)d_in[13], stat, cb, Mb, flag);
  k_stage<<<3338, 256, 0, stream>>>(ptrs, S, flag);
  k_transpose<<<1024, 256, 0, stream>>>(d_in[0], xt, flag);
  k_dctmats<<<1024, 256, 0, stream>>>(D2, D3h);
  k_dvec<<<2, 256, 0, stream>>>(S, dvec);
  k_foldM<<<dim3(192, 8), 256, 0, stream>>>(S, Mb);
  k_foldC<<<128, 256, 0, stream>>>(S, cb);
  k_foldTn<<<32, 256, 0, stream>>>(S, Tn, tb);

  k_gemm0<<<dim3(8,84), 256, 0, stream>>>(xt, D2, zA);
  k_energy<<<NROW/4, 256, 0, stream>>>(zA, en);
  k_med<<<1, 256, 0, stream>>>(en, nrm);
  k_rank<<<336, 256, 0, stream>>>(nrm, S+S_THR, stat);
  k_maskgelu<<<NROW, 256, 0, stream>>>(zA, nrm, stat, S+S_THR, S+S_WDCT, S+S_BDCT, partA);
  k_bnfin2<<<DV, 256, 0, stream>>>(partA, 256, S+S_GD, S+S_BDN, 131072.0f, abd);
  k_gemm_mf<1><<<dim3(8,84), 256, 0, stream>>>(zA, nullptr, D3h, z1, abd, xt, S+S_WDCT, S+S_BDCT, 512);

  k_patch<<<NROW/4, 256, 0, stream>>>(xt, Tn, tb, zA, partA);
  k_bnfin2<<<NP, 256, 0, stream>>>(partA, 1344, S+S_GP, S+S_BP, 86016.0f, abp);
  k_z2<<<NROW/4, 256, 0, stream>>>(zA, zcp, abp, S+S_WDC1, S+S_BDC1, partB);
  k_bnfin2<<<NP, 256, 0, stream>>>(partB, 1344, S+S_GDEP, S+S_BDEP, 86016.0f, abdep);
  k_z2fatt<<<NROW, 256, 0, stream>>>(zcp, zA, abdep, z1, dvec, att);
  k_attfin<<<1, 256, 0, stream>>>(att, S, att1);

  k_bcat<<<512, 256, 0, stream>>>(S+S_WM1, Mb, BcatTh);
  k_gemm_mf<3><<<dim3(4,84), 256, 0, stream>>>(z1, zcp, BcatTh, Hcat, att1, xt, nullptr, nullptr, 256);
  k_out<<<NROW/16, 256, 0, stream>>>(Hcat, cb, S, d_out, flag);
}

// Round 9
// 318.863 us; speedup vs baseline: 1.8288x; 1.0936x over previous
//
#include <hip/hip_runtime.h>
#include <hip/hip_bf16.h>

#define B_    256
#define L_    512
#define DV    21
#define NROW  5376       // B_*DV
#define NP    32
#define PP    16
#define PRED_ 96

// ---------------- workspace layout (float indices) ----------------
static const size_t OFF_XT    = 0;          // 5376x512 f32
static const size_t OFF_ZA    = 2752512;    // z_dct -> z -> t -> z2 -> Hcat/BcatTh (aliased over time)
static const size_t OFF_Z1    = 5505024;
static const size_t OFF_ZCP   = 8257536;    // zc_pre -> z2f (in-place)
static const size_t OFF_D2    = 11010048;   // D2hi bf16 (131072 f) + D2lo bf16 (131072 f); dead after gemm0 -> partA
static const size_t OFF_D3    = 11272192;   // D3h bf16 (131072 f); +131072: e_part (10752 f) then partB (86016 f)
static const size_t OFF_M     = 11534336;   // 512x96 folded linres
static const size_t OFF_TN    = 11583488;   // 32x16x16
static const size_t OFF_TB    = 11591680;   // 32x16
static const size_t OFF_C     = 11592192;   // 96 (pad 128)
static const size_t OFF_EN    = 11592320;   // 5376
static const size_t OFF_NORM  = 11597696;
static const size_t OFF_ATT   = 11603072;
static const size_t OFF_ATT1  = 11608448;   // aliases dvec (512) before k_attfin writes att1
static const size_t OFF_STAT  = 11613824;   // [200],[201]=quantile order stats
static const size_t OFF_ABD   = 11614080;
static const size_t OFF_ABP   = 11614144;
static const size_t OFF_ABDEP = 11614208;
static const size_t OFF_FLAG  = 11614272;   // int mode flag (1=f32 inputs, 0=bf16)
static const size_t OFF_STG   = 11614336;   // staged f32 weights (854480)
// aliases inside OFF_ZA region (live only after z2f):
//   Hcat   = OFF_ZA                 (5376 x 256 f32)
//   BcatTh = OFF_ZA + 1500000       (256 x 512 bf16)

// staged-weight offsets (relative to OFF_STG)
static const int S_WDCT=0, S_BDCT=24, S_WE=48, S_BE=4144, S_WL=4400, S_BL=790832,
  S_WD=790928, S_BDRES=795024, S_WDC=795040, S_BDC=795552, S_WDC1=795584, S_BDC1=795680,
  S_GD=795712, S_BDN=795736, S_GP=795760, S_BP=795792, S_GDEP=795824, S_BDEP=795856,
  S_THR=795888, S_WM1=795892, S_BM1=845044, S_WM2=845140, S_BM2=854356,
  S_ADWW=854452, S_ADWB=854460, S_ACW=854464, S_ACB=854468, S_AG=854472, S_AB2=854476;

struct Ptrs { const void* p[30]; };

typedef __attribute__((ext_vector_type(8))) short bf16x8;
typedef __attribute__((ext_vector_type(4))) float f32x4;

__device__ __forceinline__ float bf2f(unsigned short h){
  unsigned u = ((unsigned)h) << 16;
  return __uint_as_float(u);
}
__device__ __forceinline__ short f2b(float f){   // RNE f32 -> bf16
  unsigned u = __float_as_uint(f);
  u = (u + 0x7FFFu + ((u >> 16) & 1u)) >> 16;
  return (short)u;
}
__device__ __forceinline__ float gelu_f(float x){ return 0.5f*x*(1.0f+erff(x*0.70710678118654752440f)); }

// ---------------- init: zero stats/c/M + detect input dtype ----------------
__global__ void k_init(const unsigned* __restrict__ gones, float* __restrict__ stat,
                       float* __restrict__ c, float* __restrict__ M, int* __restrict__ flag){
  if (blockIdx.x == 0){
    stat[threadIdx.x] = 0.0f;
    if (threadIdx.x < 128) c[threadIdx.x] = 0.0f;
    if (threadIdx.x == 0) *flag = (gones[0] == 0x3F800000u) ? 1 : 0;
  } else {
    M[(blockIdx.x-1)*256 + threadIdx.x] = 0.0f;
  }
}

// ---------------- stage all weights (inputs 1..29) to f32 ----------------
__global__ __launch_bounds__(256) void k_stage(Ptrs ptrs, float* __restrict__ dst, const int* __restrict__ flag){
  const int cnt[29] = {21,21,4096,256,786432,96,4096,16,512,32,96,32,21,21,32,32,32,32,1,49152,96,9216,96,5,1,1,1,1,1};
  const int off[29] = {S_WDCT,S_BDCT,S_WE,S_BE,S_WL,S_BL,S_WD,S_BDRES,S_WDC,S_BDC,S_WDC1,S_BDC1,
                       S_GD,S_BDN,S_GP,S_BP,S_GDEP,S_BDEP,S_THR,S_WM1,S_BM1,S_WM2,S_BM2,
                       S_ADWW,S_ADWB,S_ACW,S_ACB,S_AG,S_AB2};
  int mode = *flag;
  int gid = blockIdx.x*256 + threadIdx.x;
  int a = -1, loc = 0, base = 0;
  #pragma unroll
  for (int i = 0; i < 29; i++){
    if (a < 0 && gid < base + cnt[i]){ a = i; loc = gid - base; }
    base += cnt[i];
  }
  if (a < 0) return;
  const void* s = ptrs.p[a+1];
  float v = mode ? ((const float*)s)[loc] : bf2f(((const unsigned short*)s)[loc]);
  dst[off[a] + loc] = v;
}

// ---------------- transpose x (B,L,D) -> xt (B*D, L), 4 chunks per batch ----------------
__global__ __launch_bounds__(256) void k_transpose(const void* __restrict__ x, float* __restrict__ xt,
                                                   const int* __restrict__ flag){
  __shared__ float xs[128*DV];
  int mode = *flag;
  int b = blockIdx.x >> 2, ch = blockIdx.x & 3;
  int l0 = ch*128;
  size_t base = (size_t)b*(L_*DV) + (size_t)l0*DV;
  if (mode){
    const float* xp = (const float*)x + base;
    for (int i = threadIdx.x; i < 128*DV; i += 256) xs[i] = xp[i];
  } else {
    const unsigned short* xp = (const unsigned short*)x + base;
    for (int i = threadIdx.x; i < 128*DV; i += 256) xs[i] = bf2f(xp[i]);
  }
  __syncthreads();
  for (int i = threadIdx.x; i < 128*DV; i += 256){
    int d = i >> 7, l = i & 127;
    xt[((size_t)b*DV + d)*512 + l0 + l] = xs[l*DV + d];
  }
}

// ---------------- DCT matrices: D2 split bf16 (hi/lo), D3h bf16; + dvec fold ----------------
__global__ __launch_bounds__(256) void k_dctmats(unsigned short* __restrict__ D2h,
    unsigned short* __restrict__ D2l, unsigned short* __restrict__ D3h,
    const float* __restrict__ S, float* __restrict__ dvec){
  int i = blockIdx.x*256 + threadIdx.x;
  int kk = i >> 9, m = i & 511;
  const float PIo = 3.14159265358979323846f / 1024.0f;
  int a = ((2*m+1)*kk) & 2047;
  float v = 2.0f * cosf(PIo * (float)a);
  short hi = f2b(v);
  float lo = v - bf2f((unsigned short)hi);
  D2h[i] = (unsigned short)hi;
  D2l[i] = (unsigned short)f2b(lo);
  int l = kk, k = m;
  int a2 = ((2*l+1)*k) & 2047;
  float w0 = (k==0) ? 0.5f : 1.0f;
  D3h[i] = (unsigned short)f2b(cosf(PIo * (float)a2) * w0 * (1.0f/512.0f));
  if (i < 512){
    const float rs = 22.627416997969522f;
    float s = 0.f;
    #pragma unroll
    for (int k5 = 0; k5 < 5; k5++){
      float sk = ((k5 == 0) ? 0.5f : 0.70710678118654752440f) / rs;
      int a5 = ((2*i+1)*k5) & 2047;
      s += 2.0f * cosf(PIo * (float)a5) * sk * S[S_ADWW + k5];
    }
    dvec[i] = s;
  }
}

// ---------------- fold M = We@Wl blocks: K-split, atomic partials ----------------
__global__ __launch_bounds__(256) void k_foldM(const float* __restrict__ S, float* __restrict__ M){
  const float* We = S + S_WE;  const float* Wl = S + S_WL;
  int gid = blockIdx.x*256 + threadIdx.x;
  int l = gid/96, p = gid - l*96;
  int n = l>>4, q = l&15;
  int j0 = blockIdx.y*32;
  float acc = 0.f;
  #pragma unroll 8
  for (int j = j0; j < j0+32; j++) acc += We[q*256+j] * Wl[(size_t)(n*256+j)*96 + p];
  atomicAdd(&M[gid], acc);
}

// ---------------- fold c[p] ----------------
__global__ __launch_bounds__(256) void k_foldC(const float* __restrict__ S, float* __restrict__ c){
  const float* be = S + S_BE;  const float* Wl = S + S_WL;  const float* bl = S + S_BL;
  int t = threadIdx.x;
  int rp = t >> 7, p = t & 127;
  if (p >= 96) return;
  float acc = 0.f;
  int J0 = blockIdx.x*64;
  for (int j = 0; j < 64; j += 2){
    int J = J0 + j + rp;
    acc += be[J & 255] * Wl[(size_t)J*96 + p];
  }
  if (blockIdx.x == 0 && rp == 0) acc += bl[p];
  atomicAdd(&c[p], acc);
}

// ---------------- fold Tn/tb ----------------
__global__ __launch_bounds__(256) void k_foldTn(const float* __restrict__ S,
    float* __restrict__ Tn, float* __restrict__ tb){
  __shared__ float WeS[4096];
  __shared__ float WdS[4096];
  __shared__ float wdcS[16];
  __shared__ float beS[256];
  __shared__ float bdresS[16];
  int n = blockIdx.x, tid = threadIdx.x;
  for (int i = tid; i < 4096; i += 256){ WeS[i] = S[S_WE+i]; WdS[i] = S[S_WD+i]; }
  beS[tid & 255] = S[S_BE + (tid & 255)];
  if (tid < 16){ wdcS[tid] = S[S_WDC + n*16 + tid]; bdresS[tid] = S[S_BDRES + tid]; }
  __syncthreads();
  int q2 = tid>>4, q = tid&15;
  float R = 0.f;
  for (int j = 0; j < 256; j++) R += WeS[q2*256+j] * WdS[j*16+q];
  float G = 0.f;
  #pragma unroll
  for (int p = 0; p < 16; p++) G += WeS[q2*256 + q*16 + p] * wdcS[p];
  Tn[n*256 + q2*16 + q] = R + G;
  if (tid < 16){
    float rb = bdresS[tid];
    for (int j = 0; j < 256; j++) rb += beS[j] * WdS[j*16+tid];
    float gb = S[S_BDC + n];
    #pragma unroll
    for (int p = 0; p < 16; p++) gb += beS[tid*16+p] * wdcS[p];
    tb[n*16+tid] = rb + gb;
  }
}

// ---------------- DCT GEMM via split-bf16 MFMA (f32-accurate): C = xt @ D2^T ----------------
// a = hi+lo exact split; acc += hi*hi + hi*lo + lo*hi + lo*lo (all f32-accum MFMA).
// Epilogue: per-row sum-of-squares partials (energy) -> e_part[r*8 + bx].
__global__ __launch_bounds__(256) void k_gemm0(
    const float* __restrict__ A, const unsigned short* __restrict__ Bh16,
    const unsigned short* __restrict__ Bl16, float* __restrict__ C,
    float* __restrict__ e_part){
  __shared__ short Ahi[64*40];
  __shared__ short Alo[64*40];
  __shared__ short Bhi[64*40];
  __shared__ short Blo[64*40];
  int tid = threadIdx.x;
  int rowBase = blockIdx.y*64, colBase = blockIdx.x*64;
  int srow = tid>>2, seg = tid&3;
  int r = rowBase + srow;
  int wave = tid>>6, lane = tid&63;
  int m = lane&15, quad = lane>>4;
  f32x4 acc[4] = {};
  for (int k0 = 0; k0 < 512; k0 += 32){
    float4 a0 = *(const float4*)(A + (size_t)r*512 + k0 + seg*8);
    float4 a1 = *(const float4*)(A + (size_t)r*512 + k0 + seg*8 + 4);
    bf16x8 ah, al;
    {
      float av[8] = {a0.x,a0.y,a0.z,a0.w,a1.x,a1.y,a1.z,a1.w};
      #pragma unroll
      for (int j = 0; j < 8; j++){
        short h = f2b(av[j]);
        ah[j] = h;
        al[j] = f2b(av[j] - bf2f((unsigned short)h));
      }
    }
    *(bf16x8*)(Ahi + srow*40 + seg*8) = ah;
    *(bf16x8*)(Alo + srow*40 + seg*8) = al;
    *(bf16x8*)(Bhi + srow*40 + seg*8) = *(const bf16x8*)(Bh16 + (size_t)(colBase+srow)*512 + k0 + seg*8);
    *(bf16x8*)(Blo + srow*40 + seg*8) = *(const bf16x8*)(Bl16 + (size_t)(colBase+srow)*512 + k0 + seg*8);
    __syncthreads();
    bf16x8 afh = *(bf16x8*)(Ahi + (wave*16 + m)*40 + quad*8);
    bf16x8 afl = *(bf16x8*)(Alo + (wave*16 + m)*40 + quad*8);
    #pragma unroll
    for (int t = 0; t < 4; t++){
      bf16x8 bfh = *(bf16x8*)(Bhi + (t*16 + m)*40 + quad*8);
      bf16x8 bfl = *(bf16x8*)(Blo + (t*16 + m)*40 + quad*8);
      acc[t] = __builtin_amdgcn_mfma_f32_16x16x32_bf16(afh, bfh, acc[t], 0, 0, 0);
      acc[t] = __builtin_amdgcn_mfma_f32_16x16x32_bf16(afh, bfl, acc[t], 0, 0, 0);
      acc[t] = __builtin_amdgcn_mfma_f32_16x16x32_bf16(afl, bfh, acc[t], 0, 0, 0);
      acc[t] = __builtin_amdgcn_mfma_f32_16x16x32_bf16(afl, bfl, acc[t], 0, 0, 0);
    }
    __syncthreads();
  }
  float es[4] = {};
  #pragma unroll
  for (int t = 0; t < 4; t++){
    #pragma unroll
    for (int i = 0; i < 4; i++){
      int rr = rowBase + wave*16 + quad*4 + i;
      int cc = colBase + t*16 + m;
      float v = acc[t][i];
      C[(size_t)rr*512 + cc] = v;
      es[i] += v*v;
    }
  }
  #pragma unroll
  for (int off = 1; off < 16; off <<= 1){
    #pragma unroll
    for (int i = 0; i < 4; i++) es[i] += __shfl_xor(es[i], off);
  }
  if (m == 0){
    #pragma unroll
    for (int i = 0; i < 4; i++){
      int rr = rowBase + wave*16 + quad*4 + i;
      e_part[rr*8 + blockIdx.x] = es[i];
    }
  }
}

// ---------------- reduce energy partials: e[r] = sum of 8 ----------------
__global__ __launch_bounds__(256) void k_ered(const float* __restrict__ e_part, float* __restrict__ e){
  int r = blockIdx.x*256 + threadIdx.x;
  float s = 0.f;
  #pragma unroll
  for (int j = 0; j < 8; j++) s += e_part[r*8 + j];
  e[r] = s;
}

// ---------------- MFMA bf16 GEMM: C[r][cc] = sum_k A'[r][k]*Bg[cc][k] ----------------
// MODE 1: A' = alpha_d*A+beta_d (bf16), epilogue += xt*wdct+bdct.
// MODE 3: blockIdx.x<2 -> A' = att*A + (1-att)*A2 ; else A' = xt.
template<int MODE>
__global__ __launch_bounds__(256) void k_gemm_mf(
    const float* __restrict__ A, const float* __restrict__ A2,
    const unsigned short* __restrict__ Bg,
    float* __restrict__ C, const float* __restrict__ ab, const float* __restrict__ xt,
    const float* __restrict__ wdct, const float* __restrict__ bdct, int Cstride){
  __shared__ short Ah[64*40];
  __shared__ short Bh[64*40];
  int tid = threadIdx.x;
  int rowBase = blockIdx.y*64, colBase = blockIdx.x*64;
  int srow = tid>>2, seg = tid&3;
  int r = rowBase + srow;
  float alpha = 1.f, beta = 0.f;
  bool useXt = false;
  if (MODE == 1){ int d = r % DV; alpha = ab[2*d]; beta = ab[2*d+1]; }
  if (MODE == 3){ if (blockIdx.x < 2) alpha = ab[r]; else useXt = true; }
  int wave = tid>>6, lane = tid&63;
  int m = lane&15, quad = lane>>4;
  f32x4 acc[4] = {};
  const float* Ap = (MODE == 3 && useXt) ? xt : A;
  for (int k0 = 0; k0 < 512; k0 += 32){
    float4 a0 = *(const float4*)(Ap + (size_t)r*512 + k0 + seg*8);
    float4 a1 = *(const float4*)(Ap + (size_t)r*512 + k0 + seg*8 + 4);
    if (MODE == 1){
      a0.x = alpha*a0.x+beta; a0.y = alpha*a0.y+beta; a0.z = alpha*a0.z+beta; a0.w = alpha*a0.w+beta;
      a1.x = alpha*a1.x+beta; a1.y = alpha*a1.y+beta; a1.z = alpha*a1.z+beta; a1.w = alpha*a1.w+beta;
    }
    if (MODE == 3 && !useXt){
      float4 c0 = *(const float4*)(A2 + (size_t)r*512 + k0 + seg*8);
      float4 c1 = *(const float4*)(A2 + (size_t)r*512 + k0 + seg*8 + 4);
      float om = 1.0f - alpha;
      a0.x = alpha*a0.x + om*c0.x; a0.y = alpha*a0.y + om*c0.y;
      a0.z = alpha*a0.z + om*c0.z; a0.w = alpha*a0.w + om*c0.w;
      a1.x = alpha*a1.x + om*c1.x; a1.y = alpha*a1.y + om*c1.y;
      a1.z = alpha*a1.z + om*c1.z; a1.w = alpha*a1.w + om*c1.w;
    }
    bf16x8 av;
    av[0]=f2b(a0.x); av[1]=f2b(a0.y); av[2]=f2b(a0.z); av[3]=f2b(a0.w);
    av[4]=f2b(a1.x); av[5]=f2b(a1.y); av[6]=f2b(a1.z); av[7]=f2b(a1.w);
    *(bf16x8*)(Ah + srow*40 + seg*8) = av;
    bf16x8 bv = *(const bf16x8*)(Bg + (size_t)(colBase+srow)*512 + k0 + seg*8);
    *(bf16x8*)(Bh + srow*40 + seg*8) = bv;
    __syncthreads();
    bf16x8 af = *(bf16x8*)(Ah + (wave*16 + m)*40 + quad*8);
    #pragma unroll
    for (int t = 0; t < 4; t++){
      bf16x8 bf = *(bf16x8*)(Bh + (t*16 + m)*40 + quad*8);
      acc[t] = __builtin_amdgcn_mfma_f32_16x16x32_bf16(af, bf, acc[t], 0, 0, 0);
    }
    __syncthreads();
  }
  #pragma unroll
  for (int t = 0; t < 4; t++){
    #pragma unroll
    for (int i = 0; i < 4; i++){
      int rr = rowBase + wave*16 + quad*4 + i;
      int cc = colBase + t*16 + m;
      float v = acc[t][i];
      if (MODE == 1){
        int d = rr % DV;
        v += xt[(size_t)rr*512 + cc]*wdct[d] + bdct[d];
      }
      C[(size_t)rr*Cstride + cc] = v;
    }
  }
}

// ---------------- median per batch row + norm_e ----------------
__global__ __launch_bounds__(256) void k_med(const float* __restrict__ e, float* __restrict__ norm){
  int b = threadIdx.x;
  float v[DV];
  for (int d = 0; d < DV; d++) v[d] = e[b*DV + d];
  float med = 0.f;
  for (int i = 0; i < DV; i++){
    int rk = 0;
    for (int j = 0; j < DV; j++) rk += (v[j] < v[i]) || (v[j] == v[i] && j < i);
    if (rk == 10) med = v[i];
  }
  float den = med + 1e-6f;
  for (int d = 0; d < DV; d++) norm[b*DV + d] = v[d] / den;
}

// ---------------- distributed rank-count quantile ----------------
__global__ __launch_bounds__(256) void k_rank(const float* __restrict__ norm,
    const float* __restrict__ thrv, float* __restrict__ stat){
  int tid = threadIdx.x;
  int cand = tid >> 4, part = tid & 15;
  int idx = blockIdx.x*16 + cand;
  float val = norm[idx];
  int cnt = 0;
  int j0 = part*336;
  for (int j = j0; j < j0 + 336; ++j){
    float v = norm[j];
    cnt += (v < val) || (v == val && j < idx);
  }
  __shared__ int sc[16][17];
  sc[cand][part] = cnt;
  __syncthreads();
  if (part == 0){
    int rank = 0;
    #pragma unroll
    for (int i = 0; i < 16; i++) rank += sc[cand][i];
    float q = thrv[0];
    float pos = q * 5375.0f;
    int i0 = (int)floorf(pos);
    int i1 = (i0 + 1 > 5375) ? 5375 : i0 + 1;
    if (rank == i0) stat[200] = val;
    if (rank == i1) stat[201] = val;
  }
}

// ---------------- mask + scale + gelu + BN partials ----------------
__global__ __launch_bounds__(256) void k_maskgelu(float* __restrict__ zA, const float* __restrict__ norm,
    const float* __restrict__ stat, const float* __restrict__ thrv,
    const float* __restrict__ wdct, const float* __restrict__ bdct,
    float* __restrict__ part){
  int r = blockIdx.x, tid = threadIdx.x;
  int d = r % DV, brow = r / DV;
  float q = thrv[0];
  float pos = q * 5375.0f; float f = pos - floorf(pos);
  float thr = stat[200] + (stat[201] - stat[200]) * f;
  float mask = norm[r] > thr ? 1.0f : 0.0f;
  float w = wdct[d], b = bdct[d];
  float s = 0.f, s2 = 0.f;
  for (int i = tid; i < 512; i += 256){
    float v = zA[(size_t)r*512 + i] * mask * w + b;
    float g = gelu_f(v);
    zA[(size_t)r*512 + i] = g;
    s += g; s2 += g*g;
  }
  for (int off = 32; off; off >>= 1){ s += __shfl_down(s, off); s2 += __shfl_down(s2, off); }
  __shared__ float wsum[4][2];
  int wv = tid >> 6;
  if ((tid & 63) == 0){ wsum[wv][0] = s; wsum[wv][1] = s2; }
  __syncthreads();
  if (tid == 0){
    float S  = wsum[0][0]+wsum[1][0]+wsum[2][0]+wsum[3][0];
    float S2 = wsum[0][1]+wsum[1][1]+wsum[2][1]+wsum[3][1];
    part[(2*d)*256 + brow] = S;
    part[(2*d+1)*256 + brow] = S2;
  }
}

// ---------------- BN finalize from partials ----------------
__global__ __launch_bounds__(256) void k_bnfin2(const float* __restrict__ part, int P,
    const float* __restrict__ g, const float* __restrict__ b, float count, float* __restrict__ ab){
  int c = blockIdx.x, tid = threadIdx.x;
  const float* ps = part + (size_t)(2*c)*P;
  const float* pq = part + (size_t)(2*c+1)*P;
  float s = 0.f, s2 = 0.f;
  for (int i = tid; i < P; i += 256){ s += ps[i]; s2 += pq[i]; }
  for (int off = 32; off; off >>= 1){ s += __shfl_down(s, off); s2 += __shfl_down(s2, off); }
  __shared__ float ws[4][2];
  if ((tid & 63) == 0){ ws[tid>>6][0] = s; ws[tid>>6][1] = s2; }
  __syncthreads();
  if (tid == 0){
    float S1 = ws[0][0]+ws[1][0]+ws[2][0]+ws[3][0];
    float S2 = ws[0][1]+ws[1][1]+ws[2][1]+ws[3][1];
    float mean = S1 / count;
    float var  = S2 / count - mean*mean;
    float al = g[c] * rsqrtf(var + 1e-5f);
    float be = b[c] - mean * al;
    ab[2*c] = al; ab[2*c+1] = be;
  }
}

// ---------------- patch branch: 4 rows/block, shuffle matvec, partial stats ----------------
__global__ __launch_bounds__(256) void k_patch(const float* __restrict__ xt, const float* __restrict__ Tn,
    const float* __restrict__ tb, float* __restrict__ t, float* __restrict__ part){
  int blk = blockIdx.x, tid = threadIdx.x;
  int n0 = tid >> 4, qq = tid & 15;
  int n1 = n0 + 16;
  float T0[16], T1[16];
  #pragma unroll
  for (int q2 = 0; q2 < 16; q2++){
    T0[q2] = Tn[n0*256 + q2*16 + qq];
    T1[q2] = Tn[n1*256 + q2*16 + qq];
  }
  float tb0 = tb[n0*16 + qq], tb1 = tb[n1*16 + qq];
  float s0 = 0.f, q0 = 0.f, s1 = 0.f, q1 = 0.f;
  #pragma unroll
  for (int rr = 0; rr < 4; rr++){
    int r = blk*4 + rr;
    float x0 = xt[(size_t)r*512 + tid];
    float x1 = xt[(size_t)r*512 + tid + 256];
    float a0 = tb0, a1 = tb1;
    #pragma unroll
    for (int q2 = 0; q2 < 16; q2++){
      a0 += __shfl(x0, q2, 16) * T0[q2];
      a1 += __shfl(x1, q2, 16) * T1[q2];
    }
    t[(size_t)r*512 + tid] = a0;       s0 += a0; q0 += a0*a0;
    t[(size_t)r*512 + tid + 256] = a1; s1 += a1; q1 += a1*a1;
  }
  #pragma unroll
  for (int off = 1; off < 16; off <<= 1){
    s0 += __shfl_xor(s0, off); q0 += __shfl_xor(q0, off);
    s1 += __shfl_xor(s1, off); q1 += __shfl_xor(q1, off);
  }
  if (qq == 0){
    part[(2*n0)*1344 + blk] = s0; part[(2*n0+1)*1344 + blk] = q0;
    part[(2*n1)*1344 + blk] = s1; part[(2*n1+1)*1344 + blk] = q1;
  }
}

// ---------------- z2 = gelu(bn(t)); zc_pre = conv3(z2); 4 rows/block ----------------
__global__ __launch_bounds__(256) void k_z2(float* __restrict__ t, float* __restrict__ zcp,
    const float* __restrict__ abp, const float* __restrict__ wdc1,
    const float* __restrict__ bdc1, float* __restrict__ part){
  int blk = blockIdx.x, tid = threadIdx.x;
  int n0 = tid >> 4, qq = tid & 15;
  int n1 = n0 + 16;
  float al0 = abp[2*n0], be0 = abp[2*n0+1], al1 = abp[2*n1], be1 = abp[2*n1+1];
  float w00 = wdc1[n0*3], w01 = wdc1[n0*3+1], w02 = wdc1[n0*3+2], bb0 = bdc1[n0];
  float w10 = wdc1[n1*3], w11 = wdc1[n1*3+1], w12 = wdc1[n1*3+2], bb1 = bdc1[n1];
  float s0 = 0.f, q0 = 0.f, s1 = 0.f, q1 = 0.f;
  #pragma unroll
  for (int rr = 0; rr < 4; rr++){
    int r = blk*4 + rr;
    float v0 = t[(size_t)r*512 + tid];
    float v1 = t[(size_t)r*512 + tid + 256];
    float z0  = gelu_f(al0*v0 + be0);
    float z1v = gelu_f(al1*v1 + be1);
    float l0 = __shfl_up(z0, 1, 16);    if (qq == 0)  l0 = 0.f;
    float r0 = __shfl_down(z0, 1, 16);  if (qq == 15) r0 = 0.f;
    float l1 = __shfl_up(z1v, 1, 16);   if (qq == 0)  l1 = 0.f;
    float r1 = __shfl_down(z1v, 1, 16); if (qq == 15) r1 = 0.f;
    float cv0 = w00*l0 + w01*z0  + w02*r0 + bb0;
    float cv1 = w10*l1 + w11*z1v + w12*r1 + bb1;
    zcp[(size_t)r*512 + tid] = cv0;       t[(size_t)r*512 + tid] = z0;
    zcp[(size_t)r*512 + tid + 256] = cv1; t[(size_t)r*512 + tid + 256] = z1v;
    s0 += cv0; q0 += cv0*cv0; s1 += cv1; q1 += cv1*cv1;
  }
  #pragma unroll
  for (int off = 1; off < 16; off <<= 1){
    s0 += __shfl_xor(s0, off); q0 += __shfl_xor(q0, off);
    s1 += __shfl_xor(s1, off); q1 += __shfl_xor(q1, off);
  }
  if (qq == 0){
    part[(2*n0)*1344 + blk] = s0; part[(2*n0+1)*1344 + blk] = q0;
    part[(2*n1)*1344 + blk] = s1; part[(2*n1+1)*1344 + blk] = q1;
  }
}

// ---------------- z2f (in-place over zcp) fused with att dot product ----------------
__global__ __launch_bounds__(256) void k_z2fatt(float* __restrict__ zcp, const float* __restrict__ z2,
    const float* __restrict__ ab, const float* __restrict__ z1,
    const float* __restrict__ dvec, float* __restrict__ att){
  int r = blockIdx.x, tid = threadIdx.x;
  size_t base = (size_t)r*512;
  float s = 0.f;
  #pragma unroll
  for (int h = 0; h < 2; h++){
    int idx = tid + h*256;
    int n = (idx >> 4) & 31;
    float v = gelu_f(ab[2*n]*zcp[base+idx] + ab[2*n+1]) + z2[base+idx];
    zcp[base+idx] = v;
    s += z1[base+idx] * v * dvec[idx];
  }
  for (int off = 32; off; off >>= 1) s += __shfl_down(s, off);
  __shared__ float ws[4];
  if ((tid & 63) == 0) ws[tid>>6] = s;
  __syncthreads();
  if (tid == 0) att[r] = ws[0]+ws[1]+ws[2]+ws[3];
}

// ---------------- att reduce + BN + gelu + softmax over d (single block) ----------------
__global__ __launch_bounds__(256) void k_attfin(const float* __restrict__ att, const float* __restrict__ S,
                                                float* __restrict__ att1){
  __shared__ float ws[4][2];
  int tid = threadIdx.x;
  float s = 0.f, s2 = 0.f;
  for (int i = tid; i < NROW; i += 256){ float a = att[i]; s += a; s2 += a*a; }
  for (int off = 32; off; off >>= 1){ s += __shfl_down(s, off); s2 += __shfl_down(s2, off); }
  if ((tid & 63) == 0){ ws[tid>>6][0] = s; ws[tid>>6][1] = s2; }
  __syncthreads();
  float S1 = ws[0][0]+ws[1][0]+ws[2][0]+ws[3][0];
  float S2 = ws[0][1]+ws[1][1]+ws[2][1]+ws[3][1];
  float mean = S1 / 5376.0f;
  float var  = S2 / 5376.0f - mean*mean;
  float al = S[S_AG] * rsqrtf(var + 1e-5f);
  float bb = S[S_AB2];
  float cw = S[S_ACW], cb2 = S[S_ACB];
  int b = tid;
  float v[DV]; float mx = -1e30f;
  for (int d = 0; d < DV; d++){
    float a = att[b*DV + d];
    a = gelu_f(al*(a - mean) + bb);
    a = a*cw + cb2;
    v[d] = a; mx = fmaxf(mx, a);
  }
  float ss = 0.f;
  for (int d = 0; d < DV; d++){ v[d] = expf(v[d] - mx); ss += v[d]; }
  float inv = 1.0f / ss;
  for (int d = 0; d < DV; d++) att1[b*DV + d] = v[d] * inv;
}

// ---------------- build BcatTh bf16 (256x512): rows 0..95 Wm1^T, 128..223 M^T, rest 0 ----------------
__global__ __launch_bounds__(256) void k_bcat(const float* __restrict__ Wm1, const float* __restrict__ M,
                                              unsigned short* __restrict__ Bt){
  int i = blockIdx.x*256 + threadIdx.x;   // 131072
  int c = i >> 9, m = i & 511;
  float v = 0.f;
  if (c < 96) v = Wm1[m*96 + c];
  else if (c >= 128 && c < 224) v = M[m*96 + (c - 128)];
  Bt[i] = (unsigned short)f2b(v);
}

// ---------------- out = Zres + c + gelu(H + bm1) @ Wm2 + bm2, 16 rows/block ----------------
__global__ __launch_bounds__(256) void k_out(const float* __restrict__ Hcat, const float* __restrict__ c,
    const float* __restrict__ S, void* __restrict__ outv, const int* __restrict__ flag){
  const float* bm1 = S + S_BM1;
  const float* Wm2 = S + S_WM2;
  const float* bm2 = S + S_BM2;
  __shared__ float W2s[96*96];
  __shared__ float Hs[16][100];
  int blk = blockIdx.x, tid = threadIdx.x;
  int r0 = blk*16;
  for (int i = tid; i < 96*96; i += 256) W2s[i] = Wm2[i];
  for (int i = tid; i < 16*96; i += 256){
    int rr = i / 96, col = i - rr*96;
    Hs[rr][col] = gelu_f(Hcat[(size_t)(r0+rr)*256 + col] + bm1[col]);
  }
  __syncthreads();
  int rr = tid >> 4, c0 = (tid & 15)*6;
  float acc[6] = {};
  for (int k = 0; k < 96; k++){
    float h = Hs[rr][k];
    #pragma unroll
    for (int j = 0; j < 6; j++) acc[j] += h * W2s[k*96 + c0 + j];
  }
  int r = r0 + rr;
  int b = r / DV, d = r - b*DV;
  int mode = *flag;
  #pragma unroll
  for (int j = 0; j < 6; j++){
    int p = c0 + j;
    float val = Hcat[(size_t)r*256 + 128 + p] + c[p] + acc[j] + bm2[p];
    size_t oi = ((size_t)b*96 + p)*DV + d;
    if (mode) ((float*)outv)[oi] = val;
    else ((__hip_bfloat16*)outv)[oi] = __float2bfloat16(val);
  }
}

extern "C" void kernel_launch(void* const* d_in, const int* in_sizes, int n_in,
                              void* d_out, int out_size, void* d_ws, size_t ws_size,
                              hipStream_t stream) {
  float* w = (float*)d_ws;
  float* xt   = w + OFF_XT;
  float* zA   = w + OFF_ZA;
  float* z1   = w + OFF_Z1;
  float* zcp  = w + OFF_ZCP;
  unsigned short* D2h = (unsigned short*)(w + OFF_D2);
  unsigned short* D2l = (unsigned short*)(w + OFF_D2 + 131072);
  unsigned short* D3h = (unsigned short*)(w + OFF_D3);
  float* Mb   = w + OFF_M;
  float* Tn   = w + OFF_TN;
  float* tb   = w + OFF_TB;
  float* cb   = w + OFF_C;
  float* en   = w + OFF_EN;
  float* nrm  = w + OFF_NORM;
  float* att  = w + OFF_ATT;
  float* att1 = w + OFF_ATT1;
  float* dvec = w + OFF_ATT1;     // alias: dvec dead before att1 is written
  float* stat = w + OFF_STAT;
  float* abd  = w + OFF_ABD;
  float* abp  = w + OFF_ABP;
  float* abdep= w + OFF_ABDEP;
  int*   flag = (int*)(w + OFF_FLAG);
  float* S    = w + OFF_STG;
  float* Hcat = zA;                                          // 5376x256 f32
  unsigned short* BcatTh = (unsigned short*)(zA + 1500000);  // 256x512 bf16
  float* partA  = w + OFF_D2;            // dct BN partials (42x256), patch partials (64x1344); D2hi/lo dead post-gemm0
  float* e_part = w + OFF_D3 + 131072;   // 5376x8 energy partials (D3h untouched)
  float* partB  = w + OFF_D3 + 131072;   // depth partials (64x1344); e_part dead by then

  Ptrs ptrs;
  for (int i = 0; i < 30; i++) ptrs.p[i] = d_in[i];

  k_init<<<193, 256, 0, stream>>>((const unsigned*)d_in[13], stat, cb, Mb, flag);
  k_stage<<<3338, 256, 0, stream>>>(ptrs, S, flag);
  k_transpose<<<1024, 256, 0, stream>>>(d_in[0], xt, flag);
  k_dctmats<<<1024, 256, 0, stream>>>(D2h, D2l, D3h, S, dvec);
  k_foldM<<<dim3(192, 8), 256, 0, stream>>>(S, Mb);
  k_foldC<<<128, 256, 0, stream>>>(S, cb);
  k_foldTn<<<32, 256, 0, stream>>>(S, Tn, tb);

  k_gemm0<<<dim3(8,84), 256, 0, stream>>>(xt, D2h, D2l, zA, e_part);
  k_ered<<<21, 256, 0, stream>>>(e_part, en);
  k_med<<<1, 256, 0, stream>>>(en, nrm);
  k_rank<<<336, 256, 0, stream>>>(nrm, S+S_THR, stat);
  k_maskgelu<<<NROW, 256, 0, stream>>>(zA, nrm, stat, S+S_THR, S+S_WDCT, S+S_BDCT, partA);
  k_bnfin2<<<DV, 256, 0, stream>>>(partA, 256, S+S_GD, S+S_BDN, 131072.0f, abd);
  k_gemm_mf<1><<<dim3(8,84), 256, 0, stream>>>(zA, nullptr, D3h, z1, abd, xt, S+S_WDCT, S+S_BDCT, 512);

  k_patch<<<NROW/4, 256, 0, stream>>>(xt, Tn, tb, zA, partA);
  k_bnfin2<<<NP, 256, 0, stream>>>(partA, 1344, S+S_GP, S+S_BP, 86016.0f, abp);
  k_z2<<<NROW/4, 256, 0, stream>>>(zA, zcp, abp, S+S_WDC1, S+S_BDC1, partB);
  k_bnfin2<<<NP, 256, 0, stream>>>(partB, 1344, S+S_GDEP, S+S_BDEP, 86016.0f, abdep);
  k_z2fatt<<<NROW, 256, 0, stream>>>(zcp, zA, abdep, z1, dvec, att);
  k_attfin<<<1, 256, 0, stream>>>(att, S, att1);

  k_bcat<<<512, 256, 0, stream>>>(S+S_WM1, Mb, BcatTh);
  k_gemm_mf<3><<<dim3(4,84), 256, 0, stream>>>(z1, zcp, BcatTh, Hcat, att1, xt, nullptr, nullptr, 256);
  k_out<<<NROW/16, 256, 0, stream>>>(Hcat, cb, S, d_out, flag);
}

// Round 10
// 287.050 us; speedup vs baseline: 2.0315x; 1.1108x over previous
//
#include <hip/hip_runtime.h>
#include <hip/hip_bf16.h>

#define B_    256
#define L_    512
#define DV    21
#define NROW  5376       // B_*DV
#define NP    32
#define PP    16
#define PRED_ 96

// ---------------- workspace layout (float indices) ----------------
static const size_t OFF_XT    = 0;          // 5376x512 f32
static const size_t OFF_ZA    = 2752512;    // z_dct -> z (DCT chain); later Hcat alias
static const size_t OFF_Z1    = 5505024;
static const size_t OFF_ZCP   = 8257536;    // zc_pre -> z2f (in-place)
static const size_t OFF_D2    = 11010048;   // D2hi bf16 (131072 f) + D2lo bf16 (131072 f)
static const size_t OFF_D3    = 11272192;   // D3h bf16 (131072 f)
static const size_t OFF_M     = 11534336;   // 512x96 folded linres
static const size_t OFF_TN    = 11583488;   // 32x16x16
static const size_t OFF_TB    = 11591680;   // 32x16
static const size_t OFF_C     = 11592192;   // 96 (pad 128)
static const size_t OFF_EN    = 11592320;   // 5376
static const size_t OFF_NORM  = 11597696;
static const size_t OFF_ATT   = 11603072;
static const size_t OFF_ATT1  = 11608448;   // aliases dvec (512) before k_attfin writes att1
static const size_t OFF_STAT  = 11613824;   // [200],[201]=quantile order stats
static const size_t OFF_ABD   = 11614080;
static const size_t OFF_ABP   = 11614144;
static const size_t OFF_ABDEP = 11614208;
static const size_t OFF_FLAG  = 11614272;   // int mode flag (1=f32 inputs, 0=bf16)
static const size_t OFF_STG   = 11614336;   // staged f32 weights (854480) -> ends 12468816
static const size_t OFF_T     = 12468816;   // t / z2 buffer (2752512)
static const size_t OFF_PARTP = 15221328;   // patch stats partials 64x1344
static const size_t OFF_PARTD = 15307344;   // depth stats partials 64x1344
static const size_t OFF_EPART = 15393360;   // energy partials 5376x8
static const size_t OFF_PARTM = 15436368;   // maskgelu BN partials 42x256
static const size_t OFF_BCAT  = 15447120;   // BcatTh bf16 256x512 (65536 floats)
// total ~15.51M floats = 62 MB
// Hcat alias = OFF_ZA (zA dead after gemm_mf1)

// staged-weight offsets (relative to OFF_STG)
static const int S_WDCT=0, S_BDCT=24, S_WE=48, S_BE=4144, S_WL=4400, S_BL=790832,
  S_WD=790928, S_BDRES=795024, S_WDC=795040, S_BDC=795552, S_WDC1=795584, S_BDC1=795680,
  S_GD=795712, S_BDN=795736, S_GP=795760, S_BP=795792, S_GDEP=795824, S_BDEP=795856,
  S_THR=795888, S_WM1=795892, S_BM1=845044, S_WM2=845140, S_BM2=854356,
  S_ADWW=854452, S_ADWB=854460, S_ACW=854464, S_ACB=854468, S_AG=854472, S_AB2=854476;

struct Ptrs { const void* p[30]; };

typedef __attribute__((ext_vector_type(8))) short bf16x8;
typedef __attribute__((ext_vector_type(4))) float f32x4;

__device__ __forceinline__ float bf2f(unsigned short h){
  unsigned u = ((unsigned)h) << 16;
  return __uint_as_float(u);
}
__device__ __forceinline__ short f2b(float f){   // RNE f32 -> bf16
  unsigned u = __float_as_uint(f);
  u = (u + 0x7FFFu + ((u >> 16) & 1u)) >> 16;
  return (short)u;
}
__device__ __forceinline__ float gelu_f(float x){ return 0.5f*x*(1.0f+erff(x*0.70710678118654752440f)); }

// ================= setup: stage + transpose + dctmats/dvec + zero-init =================
__global__ __launch_bounds__(256) void k_setup(Ptrs ptrs, float* __restrict__ W,
    float* __restrict__ xt, unsigned short* __restrict__ D2h, unsigned short* __restrict__ D2l,
    unsigned short* __restrict__ D3h, float* __restrict__ dvec){
  int b = blockIdx.x, tid = threadIdx.x;
  int mode = (((const unsigned*)ptrs.p[13])[0] == 0x3F800000u) ? 1 : 0;
  float* S = W + OFF_STG;
  if (b < 3338){
    // ---- stage weights to f32 ----
    const int cnt[29] = {21,21,4096,256,786432,96,4096,16,512,32,96,32,21,21,32,32,32,32,1,49152,96,9216,96,5,1,1,1,1,1};
    const int off[29] = {S_WDCT,S_BDCT,S_WE,S_BE,S_WL,S_BL,S_WD,S_BDRES,S_WDC,S_BDC,S_WDC1,S_BDC1,
                         S_GD,S_BDN,S_GP,S_BP,S_GDEP,S_BDEP,S_THR,S_WM1,S_BM1,S_WM2,S_BM2,
                         S_ADWW,S_ADWB,S_ACW,S_ACB,S_AG,S_AB2};
    int gid = b*256 + tid;
    int a = -1, loc = 0, base = 0;
    #pragma unroll
    for (int i = 0; i < 29; i++){
      if (a < 0 && gid < base + cnt[i]){ a = i; loc = gid - base; }
      base += cnt[i];
    }
    if (a < 0) return;
    const void* s = ptrs.p[a+1];
    S[off[a] + loc] = mode ? ((const float*)s)[loc] : bf2f(((const unsigned short*)s)[loc]);
  } else if (b < 4362){
    // ---- transpose x ----
    __shared__ float xs[128*DV];
    int b2 = b - 3338;
    int bb = b2 >> 2, ch = b2 & 3;
    int l0 = ch*128;
    size_t base = (size_t)bb*(L_*DV) + (size_t)l0*DV;
    if (mode){
      const float* xp = (const float*)ptrs.p[0] + base;
      for (int i = tid; i < 128*DV; i += 256) xs[i] = xp[i];
    } else {
      const unsigned short* xp = (const unsigned short*)ptrs.p[0] + base;
      for (int i = tid; i < 128*DV; i += 256) xs[i] = bf2f(xp[i]);
    }
    __syncthreads();
    for (int i = tid; i < 128*DV; i += 256){
      int d = i >> 7, l = i & 127;
      xt[((size_t)bb*DV + d)*512 + l0 + l] = xs[l*DV + d];
    }
  } else if (b < 5386){
    // ---- DCT matrices + dvec ----
    int i = (b - 4362)*256 + tid;
    int kk = i >> 9, m = i & 511;
    const float PIo = 3.14159265358979323846f / 1024.0f;
    int a = ((2*m+1)*kk) & 2047;
    float v = 2.0f * cosf(PIo * (float)a);
    short hi = f2b(v);
    D2h[i] = (unsigned short)hi;
    D2l[i] = (unsigned short)f2b(v - bf2f((unsigned short)hi));
    int a2 = ((2*kk+1)*m) & 2047;
    float w0 = (m==0) ? 0.5f : 1.0f;
    D3h[i] = (unsigned short)f2b(cosf(PIo * (float)a2) * w0 * (1.0f/512.0f));
    if (i < 512){
      const float rs = 22.627416997969522f;
      const void* aw = ptrs.p[24];
      float s = 0.f;
      #pragma unroll
      for (int k5 = 0; k5 < 5; k5++){
        float awk = mode ? ((const float*)aw)[k5] : bf2f(((const unsigned short*)aw)[k5]);
        float sk = ((k5 == 0) ? 0.5f : 0.70710678118654752440f) / rs;
        int a5 = ((2*i+1)*k5) & 2047;
        s += 2.0f * cosf(PIo * (float)a5) * sk * awk;
      }
      dvec[i] = s;
    }
  } else {
    // ---- zero init ----
    int bz = b - 5386;
    if (bz == 0){
      W[OFF_STAT + tid] = 0.0f;
      if (tid < 128) W[OFF_C + tid] = 0.0f;
      if (tid == 0) *(int*)(W + OFF_FLAG) = mode;
    } else {
      W[OFF_M + (size_t)(bz-1)*256 + tid] = 0.0f;
    }
  }
}

// ================= fold: M / c / Tn+tb =================
__global__ __launch_bounds__(256) void k_fold(const float* __restrict__ S,
    float* __restrict__ M, float* __restrict__ c, float* __restrict__ Tn, float* __restrict__ tb){
  int b = blockIdx.x, tid = threadIdx.x;
  if (b < 1536){
    const float* We = S + S_WE;  const float* Wl = S + S_WL;
    int y = b / 192, xb = b - y*192;
    int gid = xb*256 + tid;
    int l = gid/96, p = gid - l*96;
    int n = l>>4, q = l&15;
    int j0 = y*32;
    float acc = 0.f;
    #pragma unroll 8
    for (int j = j0; j < j0+32; j++) acc += We[q*256+j] * Wl[(size_t)(n*256+j)*96 + p];
    atomicAdd(&M[gid], acc);
  } else if (b < 1664){
    const float* be = S + S_BE;  const float* Wl = S + S_WL;  const float* bl = S + S_BL;
    int blkC = b - 1536;
    int rp = tid >> 7, p = tid & 127;
    if (p >= 96) return;
    float acc = 0.f;
    int J0 = blkC*64;
    for (int j = 0; j < 64; j += 2){
      int J = J0 + j + rp;
      acc += be[J & 255] * Wl[(size_t)J*96 + p];
    }
    if (blkC == 0 && rp == 0) acc += bl[p];
    atomicAdd(&c[p], acc);
  } else {
    __shared__ float WeS[4096];
    __shared__ float WdS[4096];
    __shared__ float wdcS[16];
    __shared__ float beS[256];
    __shared__ float bdresS[16];
    int n = b - 1664;
    for (int i = tid; i < 4096; i += 256){ WeS[i] = S[S_WE+i]; WdS[i] = S[S_WD+i]; }
    beS[tid & 255] = S[S_BE + (tid & 255)];
    if (tid < 16){ wdcS[tid] = S[S_WDC + n*16 + tid]; bdresS[tid] = S[S_BDRES + tid]; }
    __syncthreads();
    int q2 = tid>>4, q = tid&15;
    float R = 0.f;
    for (int j = 0; j < 256; j++) R += WeS[q2*256+j] * WdS[j*16+q];
    float G = 0.f;
    #pragma unroll
    for (int p = 0; p < 16; p++) G += WeS[q2*256 + q*16 + p] * wdcS[p];
    Tn[n*256 + q2*16 + q] = R + G;
    if (tid < 16){
      float rb = bdresS[tid];
      for (int j = 0; j < 256; j++) rb += beS[j] * WdS[j*16+tid];
      float gb = S[S_BDC + n];
      #pragma unroll
      for (int p = 0; p < 16; p++) gb += beS[tid*16+p] * wdcS[p];
      tb[n*16+tid] = rb + gb;
    }
  }
}

// ================= mega: DCT-GEMM (split bf16 MFMA) || patch || bcat =================
__global__ __launch_bounds__(256) void k_mega(
    const float* __restrict__ xt, const unsigned short* __restrict__ Bh16,
    const unsigned short* __restrict__ Bl16, float* __restrict__ C,
    float* __restrict__ e_part, const int* __restrict__ flag,
    const float* __restrict__ Tn, const float* __restrict__ tb,
    float* __restrict__ t, float* __restrict__ partP,
    const float* __restrict__ S, const float* __restrict__ M, unsigned short* __restrict__ Bt){
  int b = blockIdx.x, tid = threadIdx.x;
  if (b < 672){
    // ---- gemm0: C = xt @ D2^T via split bf16 MFMA; energy partials ----
    __shared__ short Ahi[64*40];
    __shared__ short Alo[64*40];
    __shared__ short Bhi[64*40];
    __shared__ short Blo[64*40];
    int mode = *flag;                    // 0: bf16 inputs -> A-lo == 0, skip
    int bx = b & 7, by = b >> 3;
    int rowBase = by*64, colBase = bx*64;
    int srow = tid>>2, seg = tid&3;
    int r = rowBase + srow;
    int wave = tid>>6, lane = tid&63;
    int m = lane&15, quad = lane>>4;
    f32x4 acc[4] = {};
    for (int k0 = 0; k0 < 512; k0 += 32){
      float4 a0 = *(const float4*)(xt + (size_t)r*512 + k0 + seg*8);
      float4 a1 = *(const float4*)(xt + (size_t)r*512 + k0 + seg*8 + 4);
      bf16x8 ah;
      float av[8] = {a0.x,a0.y,a0.z,a0.w,a1.x,a1.y,a1.z,a1.w};
      #pragma unroll
      for (int j = 0; j < 8; j++) ah[j] = f2b(av[j]);
      *(bf16x8*)(Ahi + srow*40 + seg*8) = ah;
      if (mode){
        bf16x8 al;
        #pragma unroll
        for (int j = 0; j < 8; j++) al[j] = f2b(av[j] - bf2f((unsigned short)ah[j]));
        *(bf16x8*)(Alo + srow*40 + seg*8) = al;
      }
      *(bf16x8*)(Bhi + srow*40 + seg*8) = *(const bf16x8*)(Bh16 + (size_t)(colBase+srow)*512 + k0 + seg*8);
      *(bf16x8*)(Blo + srow*40 + seg*8) = *(const bf16x8*)(Bl16 + (size_t)(colBase+srow)*512 + k0 + seg*8);
      __syncthreads();
      bf16x8 afh = *(bf16x8*)(Ahi + (wave*16 + m)*40 + quad*8);
      #pragma unroll
      for (int tt = 0; tt < 4; tt++){
        bf16x8 bfh = *(bf16x8*)(Bhi + (tt*16 + m)*40 + quad*8);
        bf16x8 bfl = *(bf16x8*)(Blo + (tt*16 + m)*40 + quad*8);
        acc[tt] = __builtin_amdgcn_mfma_f32_16x16x32_bf16(afh, bfh, acc[tt], 0, 0, 0);
        acc[tt] = __builtin_amdgcn_mfma_f32_16x16x32_bf16(afh, bfl, acc[tt], 0, 0, 0);
      }
      if (mode){
        bf16x8 afl = *(bf16x8*)(Alo + (wave*16 + m)*40 + quad*8);
        #pragma unroll
        for (int tt = 0; tt < 4; tt++){
          bf16x8 bfh = *(bf16x8*)(Bhi + (tt*16 + m)*40 + quad*8);
          bf16x8 bfl = *(bf16x8*)(Blo + (tt*16 + m)*40 + quad*8);
          acc[tt] = __builtin_amdgcn_mfma_f32_16x16x32_bf16(afl, bfh, acc[tt], 0, 0, 0);
          acc[tt] = __builtin_amdgcn_mfma_f32_16x16x32_bf16(afl, bfl, acc[tt], 0, 0, 0);
        }
      }
      __syncthreads();
    }
    float es[4] = {};
    #pragma unroll
    for (int tt = 0; tt < 4; tt++){
      #pragma unroll
      for (int i = 0; i < 4; i++){
        int rr = rowBase + wave*16 + quad*4 + i;
        int cc = colBase + tt*16 + m;
        float v = acc[tt][i];
        C[(size_t)rr*512 + cc] = v;
        es[i] += v*v;
      }
    }
    #pragma unroll
    for (int off = 1; off < 16; off <<= 1){
      #pragma unroll
      for (int i = 0; i < 4; i++) es[i] += __shfl_xor(es[i], off);
    }
    if (m == 0){
      #pragma unroll
      for (int i = 0; i < 4; i++){
        int rr = rowBase + wave*16 + quad*4 + i;
        e_part[rr*8 + bx] = es[i];
      }
    }
  } else if (b < 2016){
    // ---- patch branch ----
    int blk = b - 672;
    int n0 = tid >> 4, qq = tid & 15;
    int n1 = n0 + 16;
    float T0[16], T1[16];
    #pragma unroll
    for (int q2 = 0; q2 < 16; q2++){
      T0[q2] = Tn[n0*256 + q2*16 + qq];
      T1[q2] = Tn[n1*256 + q2*16 + qq];
    }
    float tb0 = tb[n0*16 + qq], tb1 = tb[n1*16 + qq];
    float s0 = 0.f, q0 = 0.f, s1 = 0.f, q1 = 0.f;
    #pragma unroll
    for (int rr = 0; rr < 4; rr++){
      int r = blk*4 + rr;
      float x0 = xt[(size_t)r*512 + tid];
      float x1 = xt[(size_t)r*512 + tid + 256];
      float a0 = tb0, a1 = tb1;
      #pragma unroll
      for (int q2 = 0; q2 < 16; q2++){
        a0 += __shfl(x0, q2, 16) * T0[q2];
        a1 += __shfl(x1, q2, 16) * T1[q2];
      }
      t[(size_t)r*512 + tid] = a0;       s0 += a0; q0 += a0*a0;
      t[(size_t)r*512 + tid + 256] = a1; s1 += a1; q1 += a1*a1;
    }
    #pragma unroll
    for (int off = 1; off < 16; off <<= 1){
      s0 += __shfl_xor(s0, off); q0 += __shfl_xor(q0, off);
      s1 += __shfl_xor(s1, off); q1 += __shfl_xor(q1, off);
    }
    if (qq == 0){
      partP[(2*n0)*1344 + blk] = s0; partP[(2*n0+1)*1344 + blk] = q0;
      partP[(2*n1)*1344 + blk] = s1; partP[(2*n1+1)*1344 + blk] = q1;
    }
  } else {
    // ---- bcat: BcatTh bf16 (256x512) ----
    int i = (b - 2016)*256 + tid;
    int cc = i >> 9, m = i & 511;
    float v = 0.f;
    if (cc < 96) v = S[S_WM1 + m*96 + cc];
    else if (cc >= 128 && cc < 224) v = M[m*96 + (cc - 128)];
    Bt[i] = (unsigned short)f2b(v);
  }
}

// ---------------- shared device: BN finalize from partials ----------------
__device__ __forceinline__ void dev_bnfin(const float* part, int P, const float* g,
    const float* bb, float count, float* ab, int c, int tid){
  const float* ps = part + (size_t)(2*c)*P;
  const float* pq = part + (size_t)(2*c+1)*P;
  float s = 0.f, s2 = 0.f;
  for (int i = tid; i < P; i += 256){ s += ps[i]; s2 += pq[i]; }
  for (int off = 32; off; off >>= 1){ s += __shfl_down(s, off); s2 += __shfl_down(s2, off); }
  __shared__ float ws[4][2];
  if ((tid & 63) == 0){ ws[tid>>6][0] = s; ws[tid>>6][1] = s2; }
  __syncthreads();
  if (tid == 0){
    float S1 = ws[0][0]+ws[1][0]+ws[2][0]+ws[3][0];
    float S2 = ws[0][1]+ws[1][1]+ws[2][1]+ws[3][1];
    float mean = S1 / count;
    float var  = S2 / count - mean*mean;
    float al = g[c] * rsqrtf(var + 1e-5f);
    float be = bb[c] - mean * al;
    ab[2*c] = al; ab[2*c+1] = be;
  }
}

// ================= mid1: block0 = energy-reduce + median ; blocks 1..32 = patch BN fin =================
__global__ __launch_bounds__(256) void k_mid1(const float* __restrict__ e_part,
    float* __restrict__ en, float* __restrict__ norm,
    const float* __restrict__ partP, const float* __restrict__ S, float* __restrict__ abp){
  int b = blockIdx.x, tid = threadIdx.x;
  if (b == 0){
    for (int r = tid; r < NROW; r += 256){
      float s = 0.f;
      #pragma unroll
      for (int j = 0; j < 8; j++) s += e_part[r*8 + j];
      en[r] = s;
    }
    __syncthreads();
    int bb = tid;
    float v[DV];
    for (int d = 0; d < DV; d++) v[d] = en[bb*DV + d];
    float med = 0.f;
    for (int i = 0; i < DV; i++){
      int rk = 0;
      for (int j = 0; j < DV; j++) rk += (v[j] < v[i]) || (v[j] == v[i] && j < i);
      if (rk == 10) med = v[i];
    }
    float den = med + 1e-6f;
    for (int d = 0; d < DV; d++) norm[bb*DV + d] = v[d] / den;
  } else {
    dev_bnfin(partP, 1344, S + S_GP, S + S_BP, 86016.0f, abp, b - 1, tid);
  }
}

// ================= mid2: blocks 0..335 = rank ; 336..1679 = z2/conv3 =================
__global__ __launch_bounds__(256) void k_mid2(const float* __restrict__ norm,
    const float* __restrict__ S, float* __restrict__ stat,
    float* __restrict__ t, float* __restrict__ zcp,
    const float* __restrict__ abp, float* __restrict__ partD){
  int b = blockIdx.x, tid = threadIdx.x;
  if (b < 336){
    int cand = tid >> 4, part = tid & 15;
    int idx = b*16 + cand;
    float val = norm[idx];
    int cnt = 0;
    int j0 = part*336;
    for (int j = j0; j < j0 + 336; ++j){
      float v = norm[j];
      cnt += (v < val) || (v == val && j < idx);
    }
    __shared__ int sc[16][17];
    sc[cand][part] = cnt;
    __syncthreads();
    if (part == 0){
      int rank = 0;
      #pragma unroll
      for (int i = 0; i < 16; i++) rank += sc[cand][i];
      float q = S[S_THR];
      float pos = q * 5375.0f;
      int i0 = (int)floorf(pos);
      int i1 = (i0 + 1 > 5375) ? 5375 : i0 + 1;
      if (rank == i0) stat[200] = val;
      if (rank == i1) stat[201] = val;
    }
  } else {
    int blk = b - 336;
    const float* wdc1 = S + S_WDC1;
    const float* bdc1 = S + S_BDC1;
    int n0 = tid >> 4, qq = tid & 15;
    int n1 = n0 + 16;
    float al0 = abp[2*n0], be0 = abp[2*n0+1], al1 = abp[2*n1], be1 = abp[2*n1+1];
    float w00 = wdc1[n0*3], w01 = wdc1[n0*3+1], w02 = wdc1[n0*3+2], bb0 = bdc1[n0];
    float w10 = wdc1[n1*3], w11 = wdc1[n1*3+1], w12 = wdc1[n1*3+2], bb1 = bdc1[n1];
    float s0 = 0.f, q0 = 0.f, s1 = 0.f, q1 = 0.f;
    #pragma unroll
    for (int rr = 0; rr < 4; rr++){
      int r = blk*4 + rr;
      float v0 = t[(size_t)r*512 + tid];
      float v1 = t[(size_t)r*512 + tid + 256];
      float z0  = gelu_f(al0*v0 + be0);
      float z1v = gelu_f(al1*v1 + be1);
      float l0 = __shfl_up(z0, 1, 16);    if (qq == 0)  l0 = 0.f;
      float r0 = __shfl_down(z0, 1, 16);  if (qq == 15) r0 = 0.f;
      float l1 = __shfl_up(z1v, 1, 16);   if (qq == 0)  l1 = 0.f;
      float r1 = __shfl_down(z1v, 1, 16); if (qq == 15) r1 = 0.f;
      float cv0 = w00*l0 + w01*z0  + w02*r0 + bb0;
      float cv1 = w10*l1 + w11*z1v + w12*r1 + bb1;
      zcp[(size_t)r*512 + tid] = cv0;       t[(size_t)r*512 + tid] = z0;
      zcp[(size_t)r*512 + tid + 256] = cv1; t[(size_t)r*512 + tid + 256] = z1v;
      s0 += cv0; q0 += cv0*cv0; s1 += cv1; q1 += cv1*cv1;
    }
    #pragma unroll
    for (int off = 1; off < 16; off <<= 1){
      s0 += __shfl_xor(s0, off); q0 += __shfl_xor(q0, off);
      s1 += __shfl_xor(s1, off); q1 += __shfl_xor(q1, off);
    }
    if (qq == 0){
      partD[(2*n0)*1344 + blk] = s0; partD[(2*n0+1)*1344 + blk] = q0;
      partD[(2*n1)*1344 + blk] = s1; partD[(2*n1+1)*1344 + blk] = q1;
    }
  }
}

// ================= mid3: blocks 0..5375 = maskgelu ; 5376..5407 = depth BN fin =================
__global__ __launch_bounds__(256) void k_mid3(float* __restrict__ zA, const float* __restrict__ norm,
    const float* __restrict__ stat, const float* __restrict__ S,
    float* __restrict__ partM, const float* __restrict__ partD, float* __restrict__ abdep){
  int b = blockIdx.x, tid = threadIdx.x;
  if (b < NROW){
    int r = b;
    int d = r % DV, brow = r / DV;
    float q = S[S_THR];
    float pos = q * 5375.0f; float f = pos - floorf(pos);
    float thr = stat[200] + (stat[201] - stat[200]) * f;
    float mask = norm[r] > thr ? 1.0f : 0.0f;
    float w = S[S_WDCT + d], bb = S[S_BDCT + d];
    float s = 0.f, s2 = 0.f;
    for (int i = tid; i < 512; i += 256){
      float v = zA[(size_t)r*512 + i] * mask * w + bb;
      float g = gelu_f(v);
      zA[(size_t)r*512 + i] = g;
      s += g; s2 += g*g;
    }
    for (int off = 32; off; off >>= 1){ s += __shfl_down(s, off); s2 += __shfl_down(s2, off); }
    __shared__ float wsum[4][2];
    int wv = tid >> 6;
    if ((tid & 63) == 0){ wsum[wv][0] = s; wsum[wv][1] = s2; }
    __syncthreads();
    if (tid == 0){
      float SS  = wsum[0][0]+wsum[1][0]+wsum[2][0]+wsum[3][0];
      float SS2 = wsum[0][1]+wsum[1][1]+wsum[2][1]+wsum[3][1];
      partM[(2*d)*256 + brow] = SS;
      partM[(2*d+1)*256 + brow] = SS2;
    }
  } else {
    dev_bnfin(partD, 1344, S + S_GDEP, S + S_BDEP, 86016.0f, abdep, b - NROW, tid);
  }
}

// ================= mid4: dct BN finalize =================
__global__ __launch_bounds__(256) void k_mid4(const float* __restrict__ partM,
    const float* __restrict__ S, float* __restrict__ abd){
  dev_bnfin(partM, 256, S + S_GD, S + S_BDN, 131072.0f, abd, blockIdx.x, threadIdx.x);
}

// ================= MFMA bf16 GEMM (idct / mlp) =================
template<int MODE>
__global__ __launch_bounds__(256) void k_gemm_mf(
    const float* __restrict__ A, const float* __restrict__ A2,
    const unsigned short* __restrict__ Bg,
    float* __restrict__ C, const float* __restrict__ ab, const float* __restrict__ xt,
    const float* __restrict__ wdct, const float* __restrict__ bdct, int Cstride){
  __shared__ short Ah[64*40];
  __shared__ short Bh[64*40];
  int tid = threadIdx.x;
  int rowBase = blockIdx.y*64, colBase = blockIdx.x*64;
  int srow = tid>>2, seg = tid&3;
  int r = rowBase + srow;
  float alpha = 1.f, beta = 0.f;
  bool useXt = false;
  if (MODE == 1){ int d = r % DV; alpha = ab[2*d]; beta = ab[2*d+1]; }
  if (MODE == 3){ if (blockIdx.x < 2) alpha = ab[r]; else useXt = true; }
  int wave = tid>>6, lane = tid&63;
  int m = lane&15, quad = lane>>4;
  f32x4 acc[4] = {};
  const float* Ap = (MODE == 3 && useXt) ? xt : A;
  for (int k0 = 0; k0 < 512; k0 += 32){
    float4 a0 = *(const float4*)(Ap + (size_t)r*512 + k0 + seg*8);
    float4 a1 = *(const float4*)(Ap + (size_t)r*512 + k0 + seg*8 + 4);
    if (MODE == 1){
      a0.x = alpha*a0.x+beta; a0.y = alpha*a0.y+beta; a0.z = alpha*a0.z+beta; a0.w = alpha*a0.w+beta;
      a1.x = alpha*a1.x+beta; a1.y = alpha*a1.y+beta; a1.z = alpha*a1.z+beta; a1.w = alpha*a1.w+beta;
    }
    if (MODE == 3 && !useXt){
      float4 c0 = *(const float4*)(A2 + (size_t)r*512 + k0 + seg*8);
      float4 c1 = *(const float4*)(A2 + (size_t)r*512 + k0 + seg*8 + 4);
      float om = 1.0f - alpha;
      a0.x = alpha*a0.x + om*c0.x; a0.y = alpha*a0.y + om*c0.y;
      a0.z = alpha*a0.z + om*c0.z; a0.w = alpha*a0.w + om*c0.w;
      a1.x = alpha*a1.x + om*c1.x; a1.y = alpha*a1.y + om*c1.y;
      a1.z = alpha*a1.z + om*c1.z; a1.w = alpha*a1.w + om*c1.w;
    }
    bf16x8 av;
    av[0]=f2b(a0.x); av[1]=f2b(a0.y); av[2]=f2b(a0.z); av[3]=f2b(a0.w);
    av[4]=f2b(a1.x); av[5]=f2b(a1.y); av[6]=f2b(a1.z); av[7]=f2b(a1.w);
    *(bf16x8*)(Ah + srow*40 + seg*8) = av;
    bf16x8 bv = *(const bf16x8*)(Bg + (size_t)(colBase+srow)*512 + k0 + seg*8);
    *(bf16x8*)(Bh + srow*40 + seg*8) = bv;
    __syncthreads();
    bf16x8 af = *(bf16x8*)(Ah + (wave*16 + m)*40 + quad*8);
    #pragma unroll
    for (int t = 0; t < 4; t++){
      bf16x8 bf = *(bf16x8*)(Bh + (t*16 + m)*40 + quad*8);
      acc[t] = __builtin_amdgcn_mfma_f32_16x16x32_bf16(af, bf, acc[t], 0, 0, 0);
    }
    __syncthreads();
  }
  #pragma unroll
  for (int t = 0; t < 4; t++){
    #pragma unroll
    for (int i = 0; i < 4; i++){
      int rr = rowBase + wave*16 + quad*4 + i;
      int cc = colBase + t*16 + m;
      float v = acc[t][i];
      if (MODE == 1){
        int d = rr % DV;
        v += xt[(size_t)rr*512 + cc]*wdct[d] + bdct[d];
      }
      C[(size_t)rr*Cstride + cc] = v;
    }
  }
}

// ================= z2f (in-place over zcp) fused with att dot product =================
__global__ __launch_bounds__(256) void k_z2fatt(float* __restrict__ zcp, const float* __restrict__ z2,
    const float* __restrict__ ab, const float* __restrict__ z1,
    const float* __restrict__ dvec, float* __restrict__ att){
  int r = blockIdx.x, tid = threadIdx.x;
  size_t base = (size_t)r*512;
  float s = 0.f;
  #pragma unroll
  for (int h = 0; h < 2; h++){
    int idx = tid + h*256;
    int n = (idx >> 4) & 31;
    float v = gelu_f(ab[2*n]*zcp[base+idx] + ab[2*n+1]) + z2[base+idx];
    zcp[base+idx] = v;
    s += z1[base+idx] * v * dvec[idx];
  }
  for (int off = 32; off; off >>= 1) s += __shfl_down(s, off);
  __shared__ float ws[4];
  if ((tid & 63) == 0) ws[tid>>6] = s;
  __syncthreads();
  if (tid == 0) att[r] = ws[0]+ws[1]+ws[2]+ws[3];
}

// ================= att reduce + BN + gelu + softmax =================
__global__ __launch_bounds__(256) void k_attfin(const float* __restrict__ att, const float* __restrict__ S,
                                                float* __restrict__ att1){
  __shared__ float ws[4][2];
  int tid = threadIdx.x;
  float s = 0.f, s2 = 0.f;
  for (int i = tid; i < NROW; i += 256){ float a = att[i]; s += a; s2 += a*a; }
  for (int off = 32; off; off >>= 1){ s += __shfl_down(s, off); s2 += __shfl_down(s2, off); }
  if ((tid & 63) == 0){ ws[tid>>6][0] = s; ws[tid>>6][1] = s2; }
  __syncthreads();
  float S1 = ws[0][0]+ws[1][0]+ws[2][0]+ws[3][0];
  float S2 = ws[0][1]+ws[1][1]+ws[2][1]+ws[3][1];
  float mean = S1 / 5376.0f;
  float var  = S2 / 5376.0f - mean*mean;
  float al = S[S_AG] * rsqrtf(var + 1e-5f);
  float bb = S[S_AB2];
  float cw = S[S_ACW], cb2 = S[S_ACB];
  int b = tid;
  float v[DV]; float mx = -1e30f;
  for (int d = 0; d < DV; d++){
    float a = att[b*DV + d];
    a = gelu_f(al*(a - mean) + bb);
    a = a*cw + cb2;
    v[d] = a; mx = fmaxf(mx, a);
  }
  float ss = 0.f;
  for (int d = 0; d < DV; d++){ v[d] = expf(v[d] - mx); ss += v[d]; }
  float inv = 1.0f / ss;
  for (int d = 0; d < DV; d++) att1[b*DV + d] = v[d] * inv;
}

// ================= out epilogue =================
__global__ __launch_bounds__(256) void k_out(const float* __restrict__ Hcat, const float* __restrict__ c,
    const float* __restrict__ S, void* __restrict__ outv, const int* __restrict__ flag){
  const float* bm1 = S + S_BM1;
  const float* Wm2 = S + S_WM2;
  const float* bm2 = S + S_BM2;
  __shared__ float W2s[96*96];
  __shared__ float Hs[16][100];
  int blk = blockIdx.x, tid = threadIdx.x;
  int r0 = blk*16;
  for (int i = tid; i < 96*96; i += 256) W2s[i] = Wm2[i];
  for (int i = tid; i < 16*96; i += 256){
    int rr = i / 96, col = i - rr*96;
    Hs[rr][col] = gelu_f(Hcat[(size_t)(r0+rr)*256 + col] + bm1[col]);
  }
  __syncthreads();
  int rr = tid >> 4, c0 = (tid & 15)*6;
  float acc[6] = {};
  for (int k = 0; k < 96; k++){
    float h = Hs[rr][k];
    #pragma unroll
    for (int j = 0; j < 6; j++) acc[j] += h * W2s[k*96 + c0 + j];
  }
  int r = r0 + rr;
  int b = r / DV, d = r - b*DV;
  int mode = *flag;
  #pragma unroll
  for (int j = 0; j < 6; j++){
    int p = c0 + j;
    float val = Hcat[(size_t)r*256 + 128 + p] + c[p] + acc[j] + bm2[p];
    size_t oi = ((size_t)b*96 + p)*DV + d;
    if (mode) ((float*)outv)[oi] = val;
    else ((__hip_bfloat16*)outv)[oi] = __float2bfloat16(val);
  }
}

extern "C" void kernel_launch(void* const* d_in, const int* in_sizes, int n_in,
                              void* d_out, int out_size, void* d_ws, size_t ws_size,
                              hipStream_t stream) {
  float* w = (float*)d_ws;
  float* xt   = w + OFF_XT;
  float* zA   = w + OFF_ZA;
  float* z1   = w + OFF_Z1;
  float* zcp  = w + OFF_ZCP;
  unsigned short* D2h = (unsigned short*)(w + OFF_D2);
  unsigned short* D2l = (unsigned short*)(w + OFF_D2 + 131072);
  unsigned short* D3h = (unsigned short*)(w + OFF_D3);
  float* Mb   = w + OFF_M;
  float* Tn   = w + OFF_TN;
  float* tb   = w + OFF_TB;
  float* cb   = w + OFF_C;
  float* en   = w + OFF_EN;
  float* nrm  = w + OFF_NORM;
  float* att  = w + OFF_ATT;
  float* att1 = w + OFF_ATT1;
  float* dvec = w + OFF_ATT1;
  float* stat = w + OFF_STAT;
  float* abd  = w + OFF_ABD;
  float* abp  = w + OFF_ABP;
  float* abdep= w + OFF_ABDEP;
  int*   flag = (int*)(w + OFF_FLAG);
  float* S    = w + OFF_STG;
  float* tbuf = w + OFF_T;
  float* partP = w + OFF_PARTP;
  float* partD = w + OFF_PARTD;
  float* e_part= w + OFF_EPART;
  float* partM = w + OFF_PARTM;
  unsigned short* BcatTh = (unsigned short*)(w + OFF_BCAT);
  float* Hcat = zA;

  Ptrs ptrs;
  for (int i = 0; i < 30; i++) ptrs.p[i] = d_in[i];

  k_setup<<<5579, 256, 0, stream>>>(ptrs, w, xt, D2h, D2l, D3h, dvec);
  k_fold<<<1696, 256, 0, stream>>>(S, Mb, cb, Tn, tb);
  k_mega<<<2528, 256, 0, stream>>>(xt, D2h, D2l, zA, e_part, flag, Tn, tb, tbuf, partP, S, Mb, BcatTh);
  k_mid1<<<33, 256, 0, stream>>>(e_part, en, nrm, partP, S, abp);
  k_mid2<<<1680, 256, 0, stream>>>(nrm, S, stat, tbuf, zcp, abp, partD);
  k_mid3<<<NROW + NP, 256, 0, stream>>>(zA, nrm, stat, S, partM, partD, abdep);
  k_mid4<<<DV, 256, 0, stream>>>(partM, S, abd);
  k_gemm_mf<1><<<dim3(8,84), 256, 0, stream>>>(zA, nullptr, D3h, z1, abd, xt, S+S_WDCT, S+S_BDCT, 512);
  k_z2fatt<<<NROW, 256, 0, stream>>>(zcp, tbuf, abdep, z1, dvec, att);
  k_attfin<<<1, 256, 0, stream>>>(att, S, att1);
  k_gemm_mf<3><<<dim3(4,84), 256, 0, stream>>>(z1, zcp, BcatTh, Hcat, att1, xt, nullptr, nullptr, 256);
  k_out<<<NROW/16, 256, 0, stream>>>(Hcat, cb, S, d_out, flag);
}

// Round 11
// 282.206 us; speedup vs baseline: 2.0663x; 1.0172x over previous
//
#include <hip/hip_runtime.h>
#include <hip/hip_bf16.h>

#define B_    256
#define L_    512
#define DV    21
#define NROW  5376       // B_*DV
#define NP    32
#define PP    16
#define PRED_ 96

// ---------------- workspace layout (float indices) ----------------
static const size_t OFF_XT    = 0;          // 5376x512 f32
static const size_t OFF_ZA    = 2752512;    // z_dct -> z (DCT chain)
static const size_t OFF_Z1    = 5505024;
static const size_t OFF_ZCP   = 8257536;    // zc_pre -> z2f (in-place)
static const size_t OFF_D2    = 11010048;   // D2hi bf16 (131072 f) + D2lo bf16 (131072 f)
static const size_t OFF_D3    = 11272192;   // D3h bf16 (131072 f)
static const size_t OFF_M     = 11534336;   // (unused now; spare)
static const size_t OFF_TN    = 11583488;   // 32x16x16
static const size_t OFF_TB    = 11591680;   // 32x16
static const size_t OFF_C     = 11592192;   // 96 (pad 128)
static const size_t OFF_EN    = 11592320;   // 5376
static const size_t OFF_NORM  = 11597696;
static const size_t OFF_ATT   = 11603072;
static const size_t OFF_ATT1  = 11608448;   // dvec (512)
static const size_t OFF_STAT  = 11613824;   // [200],[201]=quantile order stats
static const size_t OFF_ABP   = 11614144;
static const size_t OFF_ABDEP = 11614208;
static const size_t OFF_FLAG  = 11614272;   // int mode flag (1=f32 inputs, 0=bf16)
static const size_t OFF_STG   = 11614336;   // staged f32 weights (854480) -> ends 12468816
static const size_t OFF_T     = 12468816;   // t / z2 buffer (2752512)
static const size_t OFF_PARTP = 15221328;   // patch stats partials 64x1344
static const size_t OFF_PARTD = 15307344;   // depth stats partials 64x1344
static const size_t OFF_EPART = 15393360;   // energy partials 5376x8
static const size_t OFF_PARTM = 15436368;   // maskgelu BN partials 42x256
static const size_t OFF_BCAT  = 15447120;   // BcatTh bf16 256x512 (65536 floats)
static const size_t OFF_PM    = 15512656;   // foldM partials 8x49152
static const size_t OFF_PC    = 15905872;   // foldC partials 256x96
// total ~15.93M floats = 63.7 MB (ws = 256 MiB)

// staged-weight offsets (relative to OFF_STG)
static const int S_WDCT=0, S_BDCT=24, S_WE=48, S_BE=4144, S_WL=4400, S_BL=790832,
  S_WD=790928, S_BDRES=795024, S_WDC=795040, S_BDC=795552, S_WDC1=795584, S_BDC1=795680,
  S_GD=795712, S_BDN=795736, S_GP=795760, S_BP=795792, S_GDEP=795824, S_BDEP=795856,
  S_THR=795888, S_WM1=795892, S_BM1=845044, S_WM2=845140, S_BM2=854356,
  S_ADWW=854452, S_ADWB=854460, S_ACW=854464, S_ACB=854468, S_AG=854472, S_AB2=854476;

struct Ptrs { const void* p[30]; };

typedef __attribute__((ext_vector_type(8))) short bf16x8;
typedef __attribute__((ext_vector_type(4))) short bf16x4;
typedef __attribute__((ext_vector_type(4))) float f32x4;

__device__ __forceinline__ float bf2f(unsigned short h){
  unsigned u = ((unsigned)h) << 16;
  return __uint_as_float(u);
}
__device__ __forceinline__ short f2b(float f){   // RNE f32 -> bf16
  unsigned u = __float_as_uint(f);
  u = (u + 0x7FFFu + ((u >> 16) & 1u)) >> 16;
  return (short)u;
}
__device__ __forceinline__ float gelu_f(float x){ return 0.5f*x*(1.0f+erff(x*0.70710678118654752440f)); }

#define RD(P,I) (mode ? ((const float*)(P))[(I)] : bf2f(((const unsigned short*)(P))[(I)]))

// ================= setup: stage + transpose + dctmats/dvec + zero + folds (partials) =================
__global__ __launch_bounds__(256) void k_setup(Ptrs ptrs, float* __restrict__ W,
    float* __restrict__ xt, unsigned short* __restrict__ D2h, unsigned short* __restrict__ D2l,
    unsigned short* __restrict__ D3h, float* __restrict__ dvec,
    float* __restrict__ PM, float* __restrict__ PC,
    float* __restrict__ Tn, float* __restrict__ tb){
  int b = blockIdx.x, tid = threadIdx.x;
  int mode = (((const unsigned*)ptrs.p[13])[0] == 0x3F800000u) ? 1 : 0;
  float* S = W + OFF_STG;
  if (b < 3338){
    // ---- stage weights to f32 ----
    const int cnt[29] = {21,21,4096,256,786432,96,4096,16,512,32,96,32,21,21,32,32,32,32,1,49152,96,9216,96,5,1,1,1,1,1};
    const int off[29] = {S_WDCT,S_BDCT,S_WE,S_BE,S_WL,S_BL,S_WD,S_BDRES,S_WDC,S_BDC,S_WDC1,S_BDC1,
                         S_GD,S_BDN,S_GP,S_BP,S_GDEP,S_BDEP,S_THR,S_WM1,S_BM1,S_WM2,S_BM2,
                         S_ADWW,S_ADWB,S_ACW,S_ACB,S_AG,S_AB2};
    int gid = b*256 + tid;
    int a = -1, loc = 0, base = 0;
    #pragma unroll
    for (int i = 0; i < 29; i++){
      if (a < 0 && gid < base + cnt[i]){ a = i; loc = gid - base; }
      base += cnt[i];
    }
    if (a < 0) return;
    S[off[a] + loc] = RD(ptrs.p[a+1], loc);
  } else if (b < 4362){
    // ---- transpose x ----
    __shared__ float xs[128*DV];
    int b2 = b - 3338;
    int bb = b2 >> 2, ch = b2 & 3;
    int l0 = ch*128;
    size_t base = (size_t)bb*(L_*DV) + (size_t)l0*DV;
    for (int i = tid; i < 128*DV; i += 256) xs[i] = RD(ptrs.p[0], base + i);
    __syncthreads();
    for (int i = tid; i < 128*DV; i += 256){
      int d = i >> 7, l = i & 127;
      xt[((size_t)bb*DV + d)*512 + l0 + l] = xs[l*DV + d];
    }
  } else if (b < 5386){
    // ---- DCT matrices + dvec ----
    int i = (b - 4362)*256 + tid;
    int kk = i >> 9, m = i & 511;
    const float PIo = 3.14159265358979323846f / 1024.0f;
    int a = ((2*m+1)*kk) & 2047;
    float v = 2.0f * cosf(PIo * (float)a);
    short hi = f2b(v);
    D2h[i] = (unsigned short)hi;
    D2l[i] = (unsigned short)f2b(v - bf2f((unsigned short)hi));
    int a2 = ((2*kk+1)*m) & 2047;
    float w0 = (m==0) ? 0.5f : 1.0f;
    D3h[i] = (unsigned short)f2b(cosf(PIo * (float)a2) * w0 * (1.0f/512.0f));
    if (i < 512){
      const float rs = 22.627416997969522f;
      float s = 0.f;
      #pragma unroll
      for (int k5 = 0; k5 < 5; k5++){
        float awk = RD(ptrs.p[24], k5);
        float sk = ((k5 == 0) ? 0.5f : 0.70710678118654752440f) / rs;
        int a5 = ((2*i+1)*k5) & 2047;
        s += 2.0f * cosf(PIo * (float)a5) * sk * awk;
      }
      dvec[i] = s;
    }
  } else if (b == 5386){
    // ---- zero stat + flag ----
    W[OFF_STAT + tid] = 0.0f;
    if (tid == 0) *(int*)(W + OFF_FLAG) = mode;
  } else if (b < 6923){
    // ---- foldM partials: PM[y*49152 + gid] ----
    int bb2 = b - 5387;
    int y = bb2 / 192, xb = bb2 - y*192;
    int gid = xb*256 + tid;
    int l = gid/96, p = gid - l*96;
    int n = l>>4, q = l&15;
    int j0 = y*32;
    float acc = 0.f;
    #pragma unroll 8
    for (int j = j0; j < j0+32; j++)
      acc += RD(ptrs.p[3], q*256+j) * RD(ptrs.p[5], (size_t)(n*256+j)*96 + p);
    PM[(size_t)y*49152 + gid] = acc;
  } else if (b < 7051){
    // ---- foldC partials: PC[(blk*2+rp)*96 + p] ----
    int blkC = b - 6923;
    int rp = tid >> 7, p = tid & 127;
    if (p >= 96) return;
    float acc = 0.f;
    int J0 = blkC*64;
    for (int j = 0; j < 64; j += 2){
      int J = J0 + j + rp;
      acc += RD(ptrs.p[4], J & 255) * RD(ptrs.p[5], (size_t)J*96 + p);
    }
    if (blkC == 0 && rp == 0) acc += RD(ptrs.p[6], p);
    PC[(blkC*2 + rp)*96 + p] = acc;
  } else {
    // ---- foldTn ----
    __shared__ float WeS[4096];
    __shared__ float WdS[4096];
    __shared__ float wdcS[16];
    __shared__ float beS[256];
    __shared__ float bdresS[16];
    int n = b - 7051;
    for (int i = tid; i < 4096; i += 256){ WeS[i] = RD(ptrs.p[3], i); WdS[i] = RD(ptrs.p[7], i); }
    beS[tid] = RD(ptrs.p[4], tid);
    if (tid < 16){ wdcS[tid] = RD(ptrs.p[9], n*16 + tid); bdresS[tid] = RD(ptrs.p[8], tid); }
    __syncthreads();
    int q2 = tid>>4, q = tid&15;
    float R = 0.f;
    for (int j = 0; j < 256; j++) R += WeS[q2*256+j] * WdS[j*16+q];
    float G = 0.f;
    #pragma unroll
    for (int p = 0; p < 16; p++) G += WeS[q2*256 + q*16 + p] * wdcS[p];
    Tn[n*256 + q2*16 + q] = R + G;
    if (tid < 16){
      float rb = bdresS[tid];
      for (int j = 0; j < 256; j++) rb += beS[j] * WdS[j*16+tid];
      float gb = RD(ptrs.p[10], n);
      #pragma unroll
      for (int p = 0; p < 16; p++) gb += beS[tid*16+p] * wdcS[p];
      tb[n*16+tid] = rb + gb;
    }
  }
}

// ================= mega: DCT-GEMM || patch || bcat(+M reduce) || c reduce =================
__global__ __launch_bounds__(256) void k_mega(
    const float* __restrict__ xt, const unsigned short* __restrict__ Bh16,
    const unsigned short* __restrict__ Bl16, float* __restrict__ C,
    float* __restrict__ e_part, const int* __restrict__ flag,
    const float* __restrict__ Tn, const float* __restrict__ tb,
    float* __restrict__ t, float* __restrict__ partP,
    const float* __restrict__ S, const float* __restrict__ PM,
    const float* __restrict__ PC, float* __restrict__ cb, unsigned short* __restrict__ Bt){
  int b = blockIdx.x, tid = threadIdx.x;
  if (b < 672){
    __shared__ short Ahi[64*40];
    __shared__ short Alo[64*40];
    __shared__ short Bhi[64*40];
    __shared__ short Blo[64*40];
    int mode = *flag;                    // 0: bf16 inputs -> A-lo == 0, skip
    int bx = b & 7, by = b >> 3;
    int rowBase = by*64, colBase = bx*64;
    int srow = tid>>2, seg = tid&3;
    int r = rowBase + srow;
    int wave = tid>>6, lane = tid&63;
    int m = lane&15, quad = lane>>4;
    f32x4 acc[4] = {};
    for (int k0 = 0; k0 < 512; k0 += 32){
      float4 a0 = *(const float4*)(xt + (size_t)r*512 + k0 + seg*8);
      float4 a1 = *(const float4*)(xt + (size_t)r*512 + k0 + seg*8 + 4);
      bf16x8 ah;
      float av[8] = {a0.x,a0.y,a0.z,a0.w,a1.x,a1.y,a1.z,a1.w};
      #pragma unroll
      for (int j = 0; j < 8; j++) ah[j] = f2b(av[j]);
      *(bf16x8*)(Ahi + srow*40 + seg*8) = ah;
      if (mode){
        bf16x8 al;
        #pragma unroll
        for (int j = 0; j < 8; j++) al[j] = f2b(av[j] - bf2f((unsigned short)ah[j]));
        *(bf16x8*)(Alo + srow*40 + seg*8) = al;
      }
      *(bf16x8*)(Bhi + srow*40 + seg*8) = *(const bf16x8*)(Bh16 + (size_t)(colBase+srow)*512 + k0 + seg*8);
      *(bf16x8*)(Blo + srow*40 + seg*8) = *(const bf16x8*)(Bl16 + (size_t)(colBase+srow)*512 + k0 + seg*8);
      __syncthreads();
      bf16x8 afh = *(bf16x8*)(Ahi + (wave*16 + m)*40 + quad*8);
      #pragma unroll
      for (int tt = 0; tt < 4; tt++){
        bf16x8 bfh = *(bf16x8*)(Bhi + (tt*16 + m)*40 + quad*8);
        bf16x8 bfl = *(bf16x8*)(Blo + (tt*16 + m)*40 + quad*8);
        acc[tt] = __builtin_amdgcn_mfma_f32_16x16x32_bf16(afh, bfh, acc[tt], 0, 0, 0);
        acc[tt] = __builtin_amdgcn_mfma_f32_16x16x32_bf16(afh, bfl, acc[tt], 0, 0, 0);
      }
      if (mode){
        bf16x8 afl = *(bf16x8*)(Alo + (wave*16 + m)*40 + quad*8);
        #pragma unroll
        for (int tt = 0; tt < 4; tt++){
          bf16x8 bfh = *(bf16x8*)(Bhi + (tt*16 + m)*40 + quad*8);
          bf16x8 bfl = *(bf16x8*)(Blo + (tt*16 + m)*40 + quad*8);
          acc[tt] = __builtin_amdgcn_mfma_f32_16x16x32_bf16(afl, bfh, acc[tt], 0, 0, 0);
          acc[tt] = __builtin_amdgcn_mfma_f32_16x16x32_bf16(afl, bfl, acc[tt], 0, 0, 0);
        }
      }
      __syncthreads();
    }
    float es[4] = {};
    #pragma unroll
    for (int tt = 0; tt < 4; tt++){
      #pragma unroll
      for (int i = 0; i < 4; i++){
        int rr = rowBase + wave*16 + quad*4 + i;
        int cc = colBase + tt*16 + m;
        float v = acc[tt][i];
        C[(size_t)rr*512 + cc] = v;
        es[i] += v*v;
      }
    }
    #pragma unroll
    for (int off = 1; off < 16; off <<= 1){
      #pragma unroll
      for (int i = 0; i < 4; i++) es[i] += __shfl_xor(es[i], off);
    }
    if (m == 0){
      #pragma unroll
      for (int i = 0; i < 4; i++){
        int rr = rowBase + wave*16 + quad*4 + i;
        e_part[rr*8 + bx] = es[i];
      }
    }
  } else if (b < 2016){
    // ---- patch branch ----
    int blk = b - 672;
    int n0 = tid >> 4, qq = tid & 15;
    int n1 = n0 + 16;
    float T0[16], T1[16];
    #pragma unroll
    for (int q2 = 0; q2 < 16; q2++){
      T0[q2] = Tn[n0*256 + q2*16 + qq];
      T1[q2] = Tn[n1*256 + q2*16 + qq];
    }
    float tb0 = tb[n0*16 + qq], tb1 = tb[n1*16 + qq];
    float s0 = 0.f, q0 = 0.f, s1 = 0.f, q1 = 0.f;
    #pragma unroll
    for (int rr = 0; rr < 4; rr++){
      int r = blk*4 + rr;
      float x0 = xt[(size_t)r*512 + tid];
      float x1 = xt[(size_t)r*512 + tid + 256];
      float a0 = tb0, a1 = tb1;
      #pragma unroll
      for (int q2 = 0; q2 < 16; q2++){
        a0 += __shfl(x0, q2, 16) * T0[q2];
        a1 += __shfl(x1, q2, 16) * T1[q2];
      }
      t[(size_t)r*512 + tid] = a0;       s0 += a0; q0 += a0*a0;
      t[(size_t)r*512 + tid + 256] = a1; s1 += a1; q1 += a1*a1;
    }
    #pragma unroll
    for (int off = 1; off < 16; off <<= 1){
      s0 += __shfl_xor(s0, off); q0 += __shfl_xor(q0, off);
      s1 += __shfl_xor(s1, off); q1 += __shfl_xor(q1, off);
    }
    if (qq == 0){
      partP[(2*n0)*1344 + blk] = s0; partP[(2*n0+1)*1344 + blk] = q0;
      partP[(2*n1)*1344 + blk] = s1; partP[(2*n1+1)*1344 + blk] = q1;
    }
  } else if (b < 2528){
    // ---- bcat with M reduction ----
    int i = (b - 2016)*256 + tid;
    int cc = i >> 9, mm = i & 511;
    float v = 0.f;
    if (cc < 96) v = S[S_WM1 + mm*96 + cc];
    else if (cc >= 128 && cc < 224){
      int idx = mm*96 + (cc - 128);
      #pragma unroll
      for (int y = 0; y < 8; y++) v += PM[(size_t)y*49152 + idx];
    }
    Bt[i] = (unsigned short)f2b(v);
  } else {
    // ---- c reduce ----
    if (tid < 96){
      float a = 0.f;
      for (int j = 0; j < 256; j++) a += PC[j*96 + tid];
      cb[tid] = a;
    }
  }
}

// ---------------- shared device: BN finalize from partials ----------------
__device__ __forceinline__ void dev_bnfin(const float* part, int P, const float* g,
    const float* bb, float count, float* ab, int c, int tid){
  const float* ps = part + (size_t)(2*c)*P;
  const float* pq = part + (size_t)(2*c+1)*P;
  float s = 0.f, s2 = 0.f;
  for (int i = tid; i < P; i += 256){ s += ps[i]; s2 += pq[i]; }
  for (int off = 32; off; off >>= 1){ s += __shfl_down(s, off); s2 += __shfl_down(s2, off); }
  __shared__ float ws[4][2];
  if ((tid & 63) == 0){ ws[tid>>6][0] = s; ws[tid>>6][1] = s2; }
  __syncthreads();
  if (tid == 0){
    float S1 = ws[0][0]+ws[1][0]+ws[2][0]+ws[3][0];
    float S2 = ws[0][1]+ws[1][1]+ws[2][1]+ws[3][1];
    float mean = S1 / count;
    float var  = S2 / count - mean*mean;
    float al = g[c] * rsqrtf(var + 1e-5f);
    float be = bb[c] - mean * al;
    ab[2*c] = al; ab[2*c+1] = be;
  }
}

// ================= mid1: block0 = energy-reduce + median ; blocks 1..32 = patch BN fin =================
__global__ __launch_bounds__(256) void k_mid1(const float* __restrict__ e_part,
    float* __restrict__ en, float* __restrict__ norm,
    const float* __restrict__ partP, const float* __restrict__ S, float* __restrict__ abp){
  int b = blockIdx.x, tid = threadIdx.x;
  if (b == 0){
    for (int r = tid; r < NROW; r += 256){
      float s = 0.f;
      #pragma unroll
      for (int j = 0; j < 8; j++) s += e_part[r*8 + j];
      en[r] = s;
    }
    __syncthreads();
    int bb = tid;
    float v[DV];
    for (int d = 0; d < DV; d++) v[d] = en[bb*DV + d];
    float med = 0.f;
    for (int i = 0; i < DV; i++){
      int rk = 0;
      for (int j = 0; j < DV; j++) rk += (v[j] < v[i]) || (v[j] == v[i] && j < i);
      if (rk == 10) med = v[i];
    }
    float den = med + 1e-6f;
    for (int d = 0; d < DV; d++) norm[bb*DV + d] = v[d] / den;
  } else {
    dev_bnfin(partP, 1344, S + S_GP, S + S_BP, 86016.0f, abp, b - 1, tid);
  }
}

// ================= mid2: blocks 0..335 = rank ; 336..1679 = z2/conv3 =================
__global__ __launch_bounds__(256) void k_mid2(const float* __restrict__ norm,
    const float* __restrict__ S, float* __restrict__ stat,
    float* __restrict__ t, float* __restrict__ zcp,
    const float* __restrict__ abp, float* __restrict__ partD){
  int b = blockIdx.x, tid = threadIdx.x;
  if (b < 336){
    int cand = tid >> 4, part = tid & 15;
    int idx = b*16 + cand;
    float val = norm[idx];
    int cnt = 0;
    int j0 = part*336;
    for (int j = j0; j < j0 + 336; ++j){
      float v = norm[j];
      cnt += (v < val) || (v == val && j < idx);
    }
    __shared__ int sc[16][17];
    sc[cand][part] = cnt;
    __syncthreads();
    if (part == 0){
      int rank = 0;
      #pragma unroll
      for (int i = 0; i < 16; i++) rank += sc[cand][i];
      float q = S[S_THR];
      float pos = q * 5375.0f;
      int i0 = (int)floorf(pos);
      int i1 = (i0 + 1 > 5375) ? 5375 : i0 + 1;
      if (rank == i0) stat[200] = val;
      if (rank == i1) stat[201] = val;
    }
  } else {
    int blk = b - 336;
    const float* wdc1 = S + S_WDC1;
    const float* bdc1 = S + S_BDC1;
    int n0 = tid >> 4, qq = tid & 15;
    int n1 = n0 + 16;
    float al0 = abp[2*n0], be0 = abp[2*n0+1], al1 = abp[2*n1], be1 = abp[2*n1+1];
    float w00 = wdc1[n0*3], w01 = wdc1[n0*3+1], w02 = wdc1[n0*3+2], bb0 = bdc1[n0];
    float w10 = wdc1[n1*3], w11 = wdc1[n1*3+1], w12 = wdc1[n1*3+2], bb1 = bdc1[n1];
    float s0 = 0.f, q0 = 0.f, s1 = 0.f, q1 = 0.f;
    #pragma unroll
    for (int rr = 0; rr < 4; rr++){
      int r = blk*4 + rr;
      float v0 = t[(size_t)r*512 + tid];
      float v1 = t[(size_t)r*512 + tid + 256];
      float z0  = gelu_f(al0*v0 + be0);
      float z1v = gelu_f(al1*v1 + be1);
      float l0 = __shfl_up(z0, 1, 16);    if (qq == 0)  l0 = 0.f;
      float r0 = __shfl_down(z0, 1, 16);  if (qq == 15) r0 = 0.f;
      float l1 = __shfl_up(z1v, 1, 16);   if (qq == 0)  l1 = 0.f;
      float r1 = __shfl_down(z1v, 1, 16); if (qq == 15) r1 = 0.f;
      float cv0 = w00*l0 + w01*z0  + w02*r0 + bb0;
      float cv1 = w10*l1 + w11*z1v + w12*r1 + bb1;
      zcp[(size_t)r*512 + tid] = cv0;       t[(size_t)r*512 + tid] = z0;
      zcp[(size_t)r*512 + tid + 256] = cv1; t[(size_t)r*512 + tid + 256] = z1v;
      s0 += cv0; q0 += cv0*cv0; s1 += cv1; q1 += cv1*cv1;
    }
    #pragma unroll
    for (int off = 1; off < 16; off <<= 1){
      s0 += __shfl_xor(s0, off); q0 += __shfl_xor(q0, off);
      s1 += __shfl_xor(s1, off); q1 += __shfl_xor(q1, off);
    }
    if (qq == 0){
      partD[(2*n0)*1344 + blk] = s0; partD[(2*n0+1)*1344 + blk] = q0;
      partD[(2*n1)*1344 + blk] = s1; partD[(2*n1+1)*1344 + blk] = q1;
    }
  }
}

// ================= mid3: blocks 0..5375 = maskgelu ; 5376..5407 = depth BN fin =================
__global__ __launch_bounds__(256) void k_mid3(float* __restrict__ zA, const float* __restrict__ norm,
    const float* __restrict__ stat, const float* __restrict__ S,
    float* __restrict__ partM, const float* __restrict__ partD, float* __restrict__ abdep){
  int b = blockIdx.x, tid = threadIdx.x;
  if (b < NROW){
    int r = b;
    int d = r % DV, brow = r / DV;
    float q = S[S_THR];
    float pos = q * 5375.0f; float f = pos - floorf(pos);
    float thr = stat[200] + (stat[201] - stat[200]) * f;
    float mask = norm[r] > thr ? 1.0f : 0.0f;
    float w = S[S_WDCT + d], bb = S[S_BDCT + d];
    float s = 0.f, s2 = 0.f;
    for (int i = tid; i < 512; i += 256){
      float v = zA[(size_t)r*512 + i] * mask * w + bb;
      float g = gelu_f(v);
      zA[(size_t)r*512 + i] = g;
      s += g; s2 += g*g;
    }
    for (int off = 32; off; off >>= 1){ s += __shfl_down(s, off); s2 += __shfl_down(s2, off); }
    __shared__ float wsum[4][2];
    int wv = tid >> 6;
    if ((tid & 63) == 0){ wsum[wv][0] = s; wsum[wv][1] = s2; }
    __syncthreads();
    if (tid == 0){
      float SS  = wsum[0][0]+wsum[1][0]+wsum[2][0]+wsum[3][0];
      float SS2 = wsum[0][1]+wsum[1][1]+wsum[2][1]+wsum[3][1];
      partM[(2*d)*256 + brow] = SS;
      partM[(2*d+1)*256 + brow] = SS2;
    }
  } else {
    dev_bnfin(partD, 1344, S + S_GDEP, S + S_BDEP, 86016.0f, abdep, b - NROW, tid);
  }
}

// ================= gemm1: idct MFMA GEMM with in-block dct-BN finalize =================
__global__ __launch_bounds__(256) void k_gemm1(
    const float* __restrict__ A, const unsigned short* __restrict__ Bg,
    float* __restrict__ C, const float* __restrict__ partM, const float* __restrict__ xt,
    const float* __restrict__ S){
  __shared__ short Ah[64*40];
  __shared__ short Bh[64*40];
  __shared__ float redS[84];
  __shared__ float abdS[42];
  int tid = threadIdx.x;
  // in-block reduction of dct BN partials
  if (tid < 84){
    int s = tid >> 1, h = tid & 1;
    const float* ps = partM + (size_t)s*256 + h*128;
    float a = 0.f;
    #pragma unroll 16
    for (int i = 0; i < 128; i++) a += ps[i];
    redS[tid] = a;
  }
  __syncthreads();
  if (tid < DV){
    float S1 = redS[(2*tid)*2] + redS[(2*tid)*2+1];
    float S2 = redS[(2*tid+1)*2] + redS[(2*tid+1)*2+1];
    float mean = S1 / 131072.0f;
    float var  = S2 / 131072.0f - mean*mean;
    float al = S[S_GD + tid] * rsqrtf(var + 1e-5f);
    abdS[2*tid] = al;
    abdS[2*tid+1] = S[S_BDN + tid] - mean * al;
  }
  __syncthreads();
  int rowBase = blockIdx.y*64, colBase = blockIdx.x*64;
  int srow = tid>>2, seg = tid&3;
  int r = rowBase + srow;
  int d0 = r % DV;
  float alpha = abdS[2*d0], beta = abdS[2*d0+1];
  int wave = tid>>6, lane = tid&63;
  int m = lane&15, quad = lane>>4;
  f32x4 acc[4] = {};
  for (int k0 = 0; k0 < 512; k0 += 32){
    float4 a0 = *(const float4*)(A + (size_t)r*512 + k0 + seg*8);
    float4 a1 = *(const float4*)(A + (size_t)r*512 + k0 + seg*8 + 4);
    a0.x = alpha*a0.x+beta; a0.y = alpha*a0.y+beta; a0.z = alpha*a0.z+beta; a0.w = alpha*a0.w+beta;
    a1.x = alpha*a1.x+beta; a1.y = alpha*a1.y+beta; a1.z = alpha*a1.z+beta; a1.w = alpha*a1.w+beta;
    bf16x8 av;
    av[0]=f2b(a0.x); av[1]=f2b(a0.y); av[2]=f2b(a0.z); av[3]=f2b(a0.w);
    av[4]=f2b(a1.x); av[5]=f2b(a1.y); av[6]=f2b(a1.z); av[7]=f2b(a1.w);
    *(bf16x8*)(Ah + srow*40 + seg*8) = av;
    bf16x8 bv = *(const bf16x8*)(Bg + (size_t)(colBase+srow)*512 + k0 + seg*8);
    *(bf16x8*)(Bh + srow*40 + seg*8) = bv;
    __syncthreads();
    bf16x8 af = *(bf16x8*)(Ah + (wave*16 + m)*40 + quad*8);
    #pragma unroll
    for (int t = 0; t < 4; t++){
      bf16x8 bf = *(bf16x8*)(Bh + (t*16 + m)*40 + quad*8);
      acc[t] = __builtin_amdgcn_mfma_f32_16x16x32_bf16(af, bf, acc[t], 0, 0, 0);
    }
    __syncthreads();
  }
  #pragma unroll
  for (int t = 0; t < 4; t++){
    #pragma unroll
    for (int i = 0; i < 4; i++){
      int rr = rowBase + wave*16 + quad*4 + i;
      int cc = colBase + t*16 + m;
      int d = rr % DV;
      float v = acc[t][i] + xt[(size_t)rr*512 + cc]*S[S_WDCT + d] + S[S_BDCT + d];
      C[(size_t)rr*512 + cc] = v;
    }
  }
}

// ================= z2f (in-place over zcp) fused with att dot product =================
__global__ __launch_bounds__(256) void k_z2fatt(float* __restrict__ zcp, const float* __restrict__ z2,
    const float* __restrict__ ab, const float* __restrict__ z1,
    const float* __restrict__ dvec, float* __restrict__ att){
  int r = blockIdx.x, tid = threadIdx.x;
  size_t base = (size_t)r*512;
  float s = 0.f;
  #pragma unroll
  for (int h = 0; h < 2; h++){
    int idx = tid + h*256;
    int n = (idx >> 4) & 31;
    float v = gelu_f(ab[2*n]*zcp[base+idx] + ab[2*n+1]) + z2[base+idx];
    zcp[base+idx] = v;
    s += z1[base+idx] * v * dvec[idx];
  }
  for (int off = 32; off; off >>= 1) s += __shfl_down(s, off);
  __shared__ float ws[4];
  if ((tid & 63) == 0) ws[tid>>6] = s;
  __syncthreads();
  if (tid == 0) att[r] = ws[0]+ws[1]+ws[2]+ws[3];
}

// ================= gemm_out: attfin + MLP/zres GEMM + Wm2 epilogue -> d_out =================
// 168 blocks x 32 rows x 256 cols. waves 0,1: A'=att1*z1+(1-att1)*zcp (cols 0..127);
// waves 2,3: A'=xt (cols 128..255). Then H epilogue straight to output.
__global__ __launch_bounds__(256) void k_gemm_out(
    const float* __restrict__ z1, const float* __restrict__ zcp, const float* __restrict__ xt,
    const unsigned short* __restrict__ Bg, const float* __restrict__ att,
    const float* __restrict__ cb, const float* __restrict__ S,
    void* __restrict__ outv, const int* __restrict__ flag){
  __shared__ short Amix[32*40];
  __shared__ short Axt[32*40];
  __shared__ short Bst[256*40];
  __shared__ float Hs[32*260];
  __shared__ float W2s[96*96];
  __shared__ float att1S[32];
  __shared__ float asum[2];
  __shared__ float ws[4][2];
  int bb = blockIdx.x, tid = threadIdx.x;
  int r0 = bb*32;
  // Wm2 to LDS (independent)
  for (int i = tid; i < 96*96; i += 256) W2s[i] = S[S_WM2 + i];
  // att global mean/var (identical order in every block -> deterministic)
  {
    float s = 0.f, s2 = 0.f;
    for (int i = tid; i < NROW; i += 256){ float a = att[i]; s += a; s2 += a*a; }
    for (int off = 32; off; off >>= 1){ s += __shfl_down(s, off); s2 += __shfl_down(s2, off); }
    if ((tid & 63) == 0){ ws[tid>>6][0] = s; ws[tid>>6][1] = s2; }
    __syncthreads();
    if (tid == 0){
      asum[0] = ws[0][0]+ws[1][0]+ws[2][0]+ws[3][0];
      asum[1] = ws[0][1]+ws[1][1]+ws[2][1]+ws[3][1];
    }
    __syncthreads();
  }
  if (tid < 32){
    int r = r0 + tid; int b2 = r / DV, d = r - b2*DV;
    float mean = asum[0] / 5376.0f;
    float var  = asum[1] / 5376.0f - mean*mean;
    float al = S[S_AG] * rsqrtf(var + 1e-5f);
    float bbx = S[S_AB2];
    float cw = S[S_ACW], cb2 = S[S_ACB];
    float v[DV]; float mx = -1e30f;
    for (int dd = 0; dd < DV; dd++){
      float a = att[b2*DV + dd];
      a = gelu_f(al*(a - mean) + bbx);
      a = a*cw + cb2;
      v[dd] = a; mx = fmaxf(mx, a);
    }
    float ss = 0.f;
    for (int dd = 0; dd < DV; dd++) ss += expf(v[dd] - mx);
    att1S[tid] = expf(v[d] - mx) / ss;
  }
  __syncthreads();
  // GEMM
  int wave = tid>>6, lane = tid&63;
  int m = lane&15, quad = lane>>4;
  int srow = tid>>3, seg = tid&7;              // A staging: 32 rows x 8 segs of 4
  int r = r0 + srow;
  float a1r = att1S[srow];
  f32x4 acc0[4] = {}, acc1[4] = {};
  for (int k0 = 0; k0 < 512; k0 += 32){
    // A tiles
    {
      float4 zf = *(const float4*)(z1  + (size_t)r*512 + k0 + seg*4);
      float4 cf = *(const float4*)(zcp + (size_t)r*512 + k0 + seg*4);
      float om = 1.0f - a1r;
      bf16x4 mv;
      mv[0] = f2b(a1r*zf.x + om*cf.x); mv[1] = f2b(a1r*zf.y + om*cf.y);
      mv[2] = f2b(a1r*zf.z + om*cf.z); mv[3] = f2b(a1r*zf.w + om*cf.w);
      *(bf16x4*)(Amix + srow*40 + seg*4) = mv;
      float4 xf = *(const float4*)(xt + (size_t)r*512 + k0 + seg*4);
      bf16x4 xv;
      xv[0] = f2b(xf.x); xv[1] = f2b(xf.y); xv[2] = f2b(xf.z); xv[3] = f2b(xf.w);
      *(bf16x4*)(Axt + srow*40 + seg*4) = xv;
    }
    // B tiles: 256 cols x 32 k
    #pragma unroll
    for (int cg = 0; cg < 4; cg++){
      int col = cg*64 + (tid>>2);
      *(bf16x8*)(Bst + col*40 + (tid&3)*8) = *(const bf16x8*)(Bg + (size_t)col*512 + k0 + (tid&3)*8);
    }
    __syncthreads();
    const short* Ast = (wave < 2) ? Amix : Axt;
    bf16x8 af0 = *(bf16x8*)(Ast + (m)*40 + quad*8);
    bf16x8 af1 = *(bf16x8*)(Ast + (16 + m)*40 + quad*8);
    #pragma unroll
    for (int tc = 0; tc < 4; tc++){
      bf16x8 bf = *(bf16x8*)(Bst + (wave*64 + tc*16 + m)*40 + quad*8);
      acc0[tc] = __builtin_amdgcn_mfma_f32_16x16x32_bf16(af0, bf, acc0[tc], 0, 0, 0);
      acc1[tc] = __builtin_amdgcn_mfma_f32_16x16x32_bf16(af1, bf, acc1[tc], 0, 0, 0);
    }
    __syncthreads();
  }
  // H to LDS
  #pragma unroll
  for (int tc = 0; tc < 4; tc++){
    #pragma unroll
    for (int i = 0; i < 4; i++){
      int col = wave*64 + tc*16 + m;
      Hs[(quad*4 + i)*260 + col] = acc0[tc][i];
      Hs[(16 + quad*4 + i)*260 + col] = acc1[tc][i];
    }
  }
  __syncthreads();
  // gelu(H + bm1) for cols < 96 (in place)
  for (int i = tid; i < 32*96; i += 256){
    int rr = i / 96, k = i - rr*96;
    Hs[rr*260 + k] = gelu_f(Hs[rr*260 + k] + S[S_BM1 + k]);
  }
  __syncthreads();
  // out = Zres + c + H1 @ Wm2 + bm2
  int rr = tid >> 3, pg = tid & 7;
  float accv[12] = {};
  for (int k = 0; k < 96; k++){
    float h = Hs[rr*260 + k];
    #pragma unroll
    for (int j = 0; j < 12; j++) accv[j] += h * W2s[k*96 + pg*12 + j];
  }
  int rg = r0 + rr;
  int b2 = rg / DV, d = rg - b2*DV;
  int mode = *flag;
  #pragma unroll
  for (int j = 0; j < 12; j++){
    int p = pg*12 + j;
    float val = Hs[rr*260 + 128 + p] + cb[p] + accv[j] + S[S_BM2 + p];
    size_t oi = ((size_t)b2*96 + p)*DV + d;
    if (mode) ((float*)outv)[oi] = val;
    else ((__hip_bfloat16*)outv)[oi] = __float2bfloat16(val);
  }
}

extern "C" void kernel_launch(void* const* d_in, const int* in_sizes, int n_in,
                              void* d_out, int out_size, void* d_ws, size_t ws_size,
                              hipStream_t stream) {
  float* w = (float*)d_ws;
  float* xt   = w + OFF_XT;
  float* zA   = w + OFF_ZA;
  float* z1   = w + OFF_Z1;
  float* zcp  = w + OFF_ZCP;
  unsigned short* D2h = (unsigned short*)(w + OFF_D2);
  unsigned short* D2l = (unsigned short*)(w + OFF_D2 + 131072);
  unsigned short* D3h = (unsigned short*)(w + OFF_D3);
  float* Tn   = w + OFF_TN;
  float* tb   = w + OFF_TB;
  float* cb   = w + OFF_C;
  float* en   = w + OFF_EN;
  float* nrm  = w + OFF_NORM;
  float* att  = w + OFF_ATT;
  float* dvec = w + OFF_ATT1;
  float* stat = w + OFF_STAT;
  float* abp  = w + OFF_ABP;
  float* abdep= w + OFF_ABDEP;
  int*   flag = (int*)(w + OFF_FLAG);
  float* S    = w + OFF_STG;
  float* tbuf = w + OFF_T;
  float* partP = w + OFF_PARTP;
  float* partD = w + OFF_PARTD;
  float* e_part= w + OFF_EPART;
  float* partM = w + OFF_PARTM;
  unsigned short* BcatTh = (unsigned short*)(w + OFF_BCAT);
  float* PM   = w + OFF_PM;
  float* PC   = w + OFF_PC;

  Ptrs ptrs;
  for (int i = 0; i < 30; i++) ptrs.p[i] = d_in[i];

  k_setup<<<7083, 256, 0, stream>>>(ptrs, w, xt, D2h, D2l, D3h, dvec, PM, PC, Tn, tb);
  k_mega<<<2529, 256, 0, stream>>>(xt, D2h, D2l, zA, e_part, flag, Tn, tb, tbuf, partP, S, PM, PC, cb, BcatTh);
  k_mid1<<<33, 256, 0, stream>>>(e_part, en, nrm, partP, S, abp);
  k_mid2<<<1680, 256, 0, stream>>>(nrm, S, stat, tbuf, zcp, abp, partD);
  k_mid3<<<NROW + NP, 256, 0, stream>>>(zA, nrm, stat, S, partM, partD, abdep);
  k_gemm1<<<dim3(8,84), 256, 0, stream>>>(zA, D3h, z1, partM, xt, S);
  k_z2fatt<<<NROW, 256, 0, stream>>>(zcp, tbuf, abdep, z1, dvec, att);
  k_gemm_out<<<168, 256, 0, stream>>>(z1, zcp, xt, BcatTh, att, cb, S, d_out, flag);
}